// Round 15
// baseline (1802.850 us; speedup 1.0000x reference)
//
#include <hip/hip_runtime.h>
#include <hip/hip_bf16.h>
#include <math.h>

#define RSQ 0.99999500003749969f   // 1/sqrt(1+1e-5)
#define SLOPE 0.01f

typedef __attribute__((ext_vector_type(8))) short short8;
typedef __attribute__((ext_vector_type(4))) float f32x4;

__device__ __forceinline__ float sigmoidf_(float x){ return 1.0f/(1.0f+expf(-x)); }

__device__ __forceinline__ unsigned short f2bf(float f){
    unsigned u = __float_as_uint(f);
    u += 0x7fff + ((u >> 16) & 1);      // RNE
    return (unsigned short)(u >> 16);
}
__device__ __forceinline__ float bf2f(unsigned short s){
    return __uint_as_float(((unsigned)s) << 16);
}

// async global->LDS, 16B per lane
__device__ __forceinline__ void stage16(const unsigned short* g, unsigned short* l) {
    __builtin_amdgcn_global_load_lds(
        (const __attribute__((address_space(1))) unsigned int*)g,
        (__attribute__((address_space(3))) unsigned int*)l, 16, 0, 0);
}

// ---------------- mask: prod_k cos(fW*rng + fB) ----------------
__global__ void mask_partial_kernel(const float* __restrict__ fW, const float* __restrict__ fB,
                                    float* __restrict__ partial)
{
    int p = blockIdx.x*256 + threadIdx.x;   // 0..15902
    if (p >= 15903) return;
    int w = p % 513;
    float r = (float)(w + 1);
    int k0 = blockIdx.y * 32;
    float prod = 1.0f;
    for (int k = k0; k < k0 + 32; ++k) {
        float a = fW[(size_t)k*15903 + p] * r + fB[(size_t)k*15903 + p];
        prod *= cosf(a);
    }
    partial[blockIdx.y*15903 + p] = prod;
}

__global__ void mask_finalize_apply(const float* __restrict__ partial, const float* __restrict__ x,
                                    float* __restrict__ xm)
{
    int p = blockIdx.x*256 + threadIdx.x;
    if (p >= 15903) return;
    float m = 1.0f;
    #pragma unroll
    for (int c = 0; c < 32; ++c) m *= partial[c*15903 + p];
    for (int n = 0; n < 32; ++n)
        xm[(size_t)n*15903 + p] = x[(size_t)n*15903 + p] * m;
}

// ---------------- weight transforms ----------------
__global__ void wtrans9_kernel(const float* __restrict__ w, unsigned short* __restrict__ o,
                               int Cout, int Cin)
{
    int idx = blockIdx.x*256 + threadIdx.x;
    int cc = Cout*Cin;
    if (idx >= 9*cc) return;
    int tap = idx / cc;
    int r = idx - tap*cc;
    int co = r / Cin, ci = r - co*Cin;
    int kh = tap/3, kw = tap - kh*3;
    o[idx] = f2bf(w[((size_t)(co*Cin + ci)*3 + kh)*3 + kw]);
}
__global__ void wtrans1_kernel(const float* __restrict__ w, unsigned short* __restrict__ o, int total)
{
    int idx = blockIdx.x*256 + threadIdx.x;
    if (idx < total) o[idx] = f2bf(w[idx]);
}

// whh (1024,256) fp32 -> MFMA-fragment-contiguous bf16
__global__ void whh_frag_kernel(const float* __restrict__ whh, unsigned short* __restrict__ out)
{
    int tid = blockIdx.x*256 + threadIdx.x;  // 262144 exact
    int e    = tid & 7;
    int lane = (tid >> 3) & 63;
    int kc   = (tid >> 9) & 7;
    int u0   = (tid >> 12) & 15;
    int g    = tid >> 16;
    int j = (g << 8) + (u0 << 4) + (lane & 15);
    int k = (kc << 5) + ((lane >> 4) << 3) + e;
    out[tid] = f2bf(whh[(size_t)j*256 + k]);
}

// ---------------- conv1: Cin=1 direct, fp32 in -> bf16 NHWC (rows 1..31 of [33][515][64]) ----------------
__launch_bounds__(256)
__global__ void conv1_kernel(const float* __restrict__ xm, const float* __restrict__ w1,
                             const float* __restrict__ g, const float* __restrict__ b,
                             unsigned short* __restrict__ O)
{
    __shared__ float wl[576];
    __shared__ float sg[64], sb[64];
    int tid = threadIdx.x;
    if (tid < 64) { sg[tid] = g[tid]*RSQ; sb[tid] = b[tid]; }
    for (int i = tid; i < 576; i += 256) wl[i] = w1[i];
    __syncthreads();
    int px = blockIdx.x*256 + tid;
    int n = blockIdx.z;
    if (px >= 15903) return;
    int h = px / 513, w = px - h*513;
    const float* xp = xm + (size_t)n*15903;
    float v[9];
    #pragma unroll
    for (int dh = 0; dh < 3; ++dh)
      #pragma unroll
      for (int dw = 0; dw < 3; ++dw) {
        int hh = h+dh-1, ww = w+dw-1;
        bool ok = ((unsigned)hh < 31u) && ((unsigned)ww < 513u);
        v[dh*3+dw] = ok ? xp[hh*513 + ww] : 0.f;
      }
    unsigned short* op = O + (((size_t)(n*33 + h + 1))*515 + (w + 1))*64;
    #pragma unroll
    for (int c8 = 0; c8 < 8; ++c8) {
        unsigned tmp[8];
        #pragma unroll
        for (int j = 0; j < 8; ++j) {
            int co = c8*8 + j;
            const float* wr = &wl[co*9];
            float a = 0.f;
            #pragma unroll
            for (int t2 = 0; t2 < 9; ++t2) a += wr[t2]*v[t2];
            a = a*sg[co] + sb[co];
            a = (a >= 0.f) ? a : SLOPE*a;
            tmp[j] = f2bf(a);
        }
        uint4 pk;
        pk.x = tmp[0] | (tmp[1]<<16);
        pk.y = tmp[2] | (tmp[3]<<16);
        pk.z = tmp[4] | (tmp[5]<<16);
        pk.w = tmp[6] | (tmp[7]<<16);
        *(uint4*)(op + c8*8) = pk;
    }
}

// ---------------- LDS-staged implicit-GEMM 3x3 conv (+1x1 shortcut) via MFMA ----------------
template<int CIN, int TPX, int CS, int POOL>
__launch_bounds__(256, 2)
__global__ void conv_lds_kernel(const unsigned short* __restrict__ X,
                                const unsigned short* __restrict__ W9,
                                const unsigned short* __restrict__ Xs,
                                const unsigned short* __restrict__ Ws,
                                unsigned short* __restrict__ O,
                                int Wp, int WT, int WpS,
                                int HO, int HOFF, int WpO, int OOFF, int Cout,
                                const float* __restrict__ g, const float* __restrict__ b)
{
    constexpr int KQ  = CIN/8;
    constexpr int PXT = TPX*16 + 2;
    constexpr int UX  = 3*PXT*KQ;
    constexpr int KQS = (CS > 0) ? CS/8 : 8;
    constexpr int US  = (CS > 0) ? TPX*16*KQS : 0;
    constexpr int UT  = UX + US;
    constexpr int NU  = (UT + 255)/256;
    constexpr int NKC = CIN/32;
    __shared__ uint4 lds4[UT + 8];

    const int tid = threadIdx.x;
    const int lane = tid & 63;
    const int wave = tid >> 6;
    const int cob  = blockIdx.y*64 + wave*16;
    const int n  = blockIdx.z;
    const int wt = blockIdx.x % WT;
    const int h  = blockIdx.x / WT;
    const int w0 = wt*(TPX*16);
    const int l15 = lane & 15;
    const int gq  = lane >> 4;

    uint4 tmp[NU];
    #pragma unroll
    for (int i = 0; i < NU; ++i) {
        int u = tid + i*256;
        if (u < UX) {
            int r   = u / (PXT*KQ);
            int rem = u - r*(PXT*KQ);
            int px  = rem / KQ;
            int kq  = rem - px*KQ;
            tmp[i] = *(const uint4*)(X + (((size_t)(n*33 + h + r))*Wp + w0 + px)*CIN + kq*8);
        } else if (CS > 0 && u < UT) {
            int us = u - UX;
            int px = us / KQS;
            int kq = us - px*KQS;
            tmp[i] = *(const uint4*)(Xs + (((size_t)(n*33 + h + 1))*WpS + w0 + 1 + px)*CS + kq*8);
        }
    }
    #pragma unroll
    for (int i = 0; i < NU; ++i) {
        int u = tid + i*256;
        if (u < UT) {
            int px;
            if (u < UX) { int rem = u % (PXT*KQ); px = rem / KQ; }
            else        { px = (u - UX) / KQS; }
            *(uint4*)((char*)lds4 + ((u*16) ^ ((px & 7) << 4))) = tmp[i];
        }
    }
    __syncthreads();

    f32x4 acc[TPX] = {};
    #pragma unroll
    for (int dh = 0; dh < 3; ++dh) {
        short8 aw[3*NKC];
        #pragma unroll
        for (int dw = 0; dw < 3; ++dw)
            #pragma unroll
            for (int kc = 0; kc < NKC; ++kc)
                aw[dw*NKC + kc] = *(const short8*)(W9 +
                    ((size_t)((dh*3 + dw)*Cout + cob + l15))*CIN + kc*32 + gq*8);
        #pragma unroll
        for (int dw = 0; dw < 3; ++dw) {
            #pragma unroll
            for (int kc = 0; kc < NKC; ++kc) {
                short8 a = aw[dw*NKC + kc];
                #pragma unroll
                for (int t = 0; t < TPX; ++t) {
                    int px = dw + t*16 + l15;
                    int u  = (dh*PXT + px)*KQ + kc*4 + gq;
                    short8 bv = *(const short8*)((const char*)lds4 + ((u*16) ^ ((px & 7) << 4)));
                    acc[t] = __builtin_amdgcn_mfma_f32_16x16x32_bf16(a, bv, acc[t], 0, 0, 0);
                }
            }
        }
    }

    if (CS > 0) {
        #pragma unroll
        for (int kc = 0; kc < KQS/4; ++kc) {
            short8 a = *(const short8*)(Ws + (size_t)(cob + l15)*CS + kc*32 + gq*8);
            #pragma unroll
            for (int t = 0; t < TPX; ++t) {
                int px = t*16 + l15;
                int u  = UX + px*KQS + kc*4 + gq;
                short8 bv = *(const short8*)((const char*)lds4 + ((u*16) ^ ((px & 7) << 4)));
                acc[t] = __builtin_amdgcn_mfma_f32_16x16x32_bf16(a, bv, acc[t], 0, 0, 0);
            }
        }
    }

    int cb = cob + gq*4;
    float s0 = g[cb+0]*RSQ, s1 = g[cb+1]*RSQ, s2 = g[cb+2]*RSQ, s3 = g[cb+3]*RSQ;
    float o0 = b[cb+0], o1 = b[cb+1], o2 = b[cb+2], o3 = b[cb+3];
    #pragma unroll
    for (int t = 0; t < TPX; ++t) {
        float v0 = acc[t][0]*s0 + o0; v0 = (v0 >= 0.f) ? v0 : SLOPE*v0;
        float v1 = acc[t][1]*s1 + o1; v1 = (v1 >= 0.f) ? v1 : SLOPE*v1;
        float v2 = acc[t][2]*s2 + o2; v2 = (v2 >= 0.f) ? v2 : SLOPE*v2;
        float v3 = acc[t][3]*s3 + o3; v3 = (v3 >= 0.f) ? v3 : SLOPE*v3;
        if (POOL) {
            v0 = fmaxf(v0, __shfl_xor(v0, 1)); v0 = fmaxf(v0, __shfl_xor(v0, 2));
            v1 = fmaxf(v1, __shfl_xor(v1, 1)); v1 = fmaxf(v1, __shfl_xor(v1, 2));
            v2 = fmaxf(v2, __shfl_xor(v2, 1)); v2 = fmaxf(v2, __shfl_xor(v2, 2));
            v3 = fmaxf(v3, __shfl_xor(v3, 1)); v3 = fmaxf(v3, __shfl_xor(v3, 2));
            if ((l15 & 3) == 0) {
                int pw = (w0 + t*16 + l15) >> 2;
                uint2 pk;
                pk.x = (unsigned)f2bf(v0) | ((unsigned)f2bf(v1) << 16);
                pk.y = (unsigned)f2bf(v2) | ((unsigned)f2bf(v3) << 16);
                *(uint2*)(O + (((size_t)(n*HO + h + HOFF))*WpO + pw + OOFF)*Cout + cb) = pk;
            }
        } else {
            int w = w0 + t*16 + l15;
            uint2 pk;
            pk.x = (unsigned)f2bf(v0) | ((unsigned)f2bf(v1) << 16);
            pk.y = (unsigned)f2bf(v2) | ((unsigned)f2bf(v3) << 16);
            *(uint2*)(O + (((size_t)(n*HO + h + HOFF))*WpO + w + OOFF)*Cout + cb) = pk;
        }
    }
}

// ---------------- W=8 LDS-staged conv for r3 layers ----------------
template<int CIN, int CS, int POOL>
__launch_bounds__(256, 2)
__global__ void conv_w8_kernel(const unsigned short* __restrict__ X,
                               const unsigned short* __restrict__ W9,
                               const unsigned short* __restrict__ Xs,
                               const unsigned short* __restrict__ Ws,
                               unsigned short* __restrict__ O, int Cout,
                               const float* __restrict__ g, const float* __restrict__ b)
{
    constexpr int KQ  = CIN/8;
    constexpr int UX  = 4*10*KQ;
    constexpr int KQS = (CS > 0) ? CS/8 : 8;
    constexpr int US  = (CS > 0) ? 2*8*KQS : 0;
    constexpr int UT  = UX + US;
    constexpr int NU  = (UT + 255)/256;
    constexpr int NKC = CIN/32;
    __shared__ uint4 lds4[UT + 8];

    const int tid = threadIdx.x;
    const int lane = tid & 63;
    const int wave = tid >> 6;
    const int hp = blockIdx.x;          // 0..15
    const int n  = blockIdx.z;
    const int h0 = hp*2;
    const int l15 = lane & 15;
    const int gq  = lane >> 4;
    const int r = l15 >> 3;
    const int w = l15 & 7;
    const int cwb = blockIdx.y*128 + wave*32;

    uint4 tmp[NU];
    #pragma unroll
    for (int i = 0; i < NU; ++i) {
        int u = tid + i*256;
        if (u < UX) {
            int row = u / (10*KQ);
            int rem = u - row*(10*KQ);
            int px  = rem / KQ;
            int kq  = rem - px*KQ;
            tmp[i] = *(const uint4*)(X + (((size_t)(n*34 + h0 + row))*10 + px)*CIN + kq*8);
        } else if (CS > 0 && u < UT) {
            int us = u - UX;
            int rs = us / (8*KQS);
            int rem = us - rs*(8*KQS);
            int px8 = rem / KQS;
            int kq  = rem - px8*KQS;
            tmp[i] = *(const uint4*)(Xs + (((size_t)(n*34 + h0 + 1 + rs))*10 + px8 + 1)*CS + kq*8);
        }
    }
    #pragma unroll
    for (int i = 0; i < NU; ++i) {
        int u = tid + i*256;
        if (u < UT) {
            int key;
            if (u < UX) { int rem = u % (10*KQ); key = rem / KQ; }
            else        { key = ((u - UX) % (8*KQS)) / KQS; }
            *(uint4*)((char*)lds4 + ((u*16) ^ ((key & 7) << 4))) = tmp[i];
        }
    }
    __syncthreads();

    f32x4 acc0 = {0,0,0,0}, acc1 = {0,0,0,0};
    #pragma unroll
    for (int dh = 0; dh < 3; ++dh) {
        #pragma unroll
        for (int dw = 0; dw < 3; ++dw) {
            short8 a0[NKC], a1[NKC];
            #pragma unroll
            for (int kc = 0; kc < NKC; ++kc) {
                a0[kc] = *(const short8*)(W9 + ((size_t)((dh*3+dw)*Cout + cwb + l15))*CIN + kc*32 + gq*8);
                a1[kc] = *(const short8*)(W9 + ((size_t)((dh*3+dw)*Cout + cwb + 16 + l15))*CIN + kc*32 + gq*8);
            }
            #pragma unroll
            for (int kc = 0; kc < NKC; ++kc) {
                int row_s = r + dh;
                int col = w + dw;
                int u = (row_s*10 + col)*KQ + kc*4 + gq;
                short8 bv = *(const short8*)((const char*)lds4 + ((u*16) ^ ((col & 7) << 4)));
                acc0 = __builtin_amdgcn_mfma_f32_16x16x32_bf16(a0[kc], bv, acc0, 0, 0, 0);
                acc1 = __builtin_amdgcn_mfma_f32_16x16x32_bf16(a1[kc], bv, acc1, 0, 0, 0);
            }
        }
    }

    if (CS > 0) {
        #pragma unroll
        for (int kc = 0; kc < KQS/4; ++kc) {
            short8 a0 = *(const short8*)(Ws + (size_t)(cwb + l15)*CS + kc*32 + gq*8);
            short8 a1 = *(const short8*)(Ws + (size_t)(cwb + 16 + l15)*CS + kc*32 + gq*8);
            int u = UX + (r*8 + w)*KQS + kc*4 + gq;
            short8 bv = *(const short8*)((const char*)lds4 + ((u*16) ^ ((w & 7) << 4)));
            acc0 = __builtin_amdgcn_mfma_f32_16x16x32_bf16(a0, bv, acc0, 0, 0, 0);
            acc1 = __builtin_amdgcn_mfma_f32_16x16x32_bf16(a1, bv, acc1, 0, 0, 0);
        }
    }

    const int hr = h0 + r;
    const bool valid = hr < 31;
#define EPIG8(ACC, G) do { \
    int cb = cwb + (G)*16 + gq*4; \
    float s0 = g[cb+0]*RSQ, s1 = g[cb+1]*RSQ, s2 = g[cb+2]*RSQ, s3 = g[cb+3]*RSQ; \
    float o0 = b[cb+0], o1 = b[cb+1], o2 = b[cb+2], o3 = b[cb+3]; \
    float v0 = ACC[0]*s0 + o0; v0 = (v0 >= 0.f) ? v0 : SLOPE*v0; \
    float v1 = ACC[1]*s1 + o1; v1 = (v1 >= 0.f) ? v1 : SLOPE*v1; \
    float v2 = ACC[2]*s2 + o2; v2 = (v2 >= 0.f) ? v2 : SLOPE*v2; \
    float v3 = ACC[3]*s3 + o3; v3 = (v3 >= 0.f) ? v3 : SLOPE*v3; \
    if (POOL) { \
        v0 = fmaxf(v0, __shfl_xor(v0, 1)); v0 = fmaxf(v0, __shfl_xor(v0, 2)); \
        v1 = fmaxf(v1, __shfl_xor(v1, 1)); v1 = fmaxf(v1, __shfl_xor(v1, 2)); \
        v2 = fmaxf(v2, __shfl_xor(v2, 1)); v2 = fmaxf(v2, __shfl_xor(v2, 2)); \
        v3 = fmaxf(v3, __shfl_xor(v3, 1)); v3 = fmaxf(v3, __shfl_xor(v3, 2)); \
        if (((l15 & 3) == 0) && valid) { \
            uint2 pk; \
            pk.x = (unsigned)f2bf(v0) | ((unsigned)f2bf(v1) << 16); \
            pk.y = (unsigned)f2bf(v2) | ((unsigned)f2bf(v3) << 16); \
            *(uint2*)(O + (((size_t)(n*31 + hr))*2 + (w >> 2))*Cout + cb) = pk; \
        } \
    } else if (valid) { \
        uint2 pk; \
        pk.x = (unsigned)f2bf(v0) | ((unsigned)f2bf(v1) << 16); \
        pk.y = (unsigned)f2bf(v2) | ((unsigned)f2bf(v3) << 16); \
        *(uint2*)(O + (((size_t)(n*34 + hr + 1))*10 + w + 1)*Cout + cb) = pk; \
    } \
} while(0)
    EPIG8(acc0, 0);
    EPIG8(acc1, 1);
#undef EPIG8
}

// ---------------- feats: [n][31][2][256] bf16 NHWC -> [n][31][512] fp32 ----------------
__global__ void feats_kernel(const unsigned short* __restrict__ p4, float* __restrict__ fe)
{
    int idx = blockIdx.x*256 + threadIdx.x;   // 507904
    int cw = idx & 511;
    int nh = idx >> 9;
    int c = cw >> 1, w = cw & 1;
    fe[idx] = bf2f(p4[((size_t)nh*2 + w)*256 + c]);
}

// ---------------- tiled SGEMM: C[M,N] = A[M,K] @ B[N,K]^T + bias(+bias2) ----------------
#define GM 32
#define GN 64
#define GK 32
template<int XPOSE>
__launch_bounds__(256)
__global__ void gemm_bias_kernel(const float* __restrict__ A, const float* __restrict__ B,
                                 const float* __restrict__ bias, const float* __restrict__ bias2,
                                 float* __restrict__ C, int M, int N, int K)
{
    __shared__ float As[GM][GK+1];
    __shared__ float Bs[GN][GK+1];
    int m0 = blockIdx.x*GM, n0 = blockIdx.y*GN;
    int tid = threadIdx.x;
    int mi = tid >> 4;
    int ni = (tid & 15) * 4;
    float acc[2][4] = {};

    for (int k0 = 0; k0 < K; k0 += GK) {
        for (int i = tid; i < GM*GK; i += 256) {
            int r = i >> 5, c = i & 31;
            int m = m0 + r;
            As[r][c] = (m < M) ? A[(size_t)m*K + k0 + c] : 0.f;
        }
        for (int i = tid; i < GN*GK; i += 256) {
            int r = i >> 5, c = i & 31;
            int n = n0 + r;
            Bs[r][c] = (n < N) ? B[(size_t)n*K + k0 + c] : 0.f;
        }
        __syncthreads();
        #pragma unroll
        for (int kk = 0; kk < GK; ++kk) {
            float a0 = As[mi][kk], a1 = As[mi+16][kk];
            float b0 = Bs[ni][kk], b1 = Bs[ni+1][kk], b2 = Bs[ni+2][kk], b3 = Bs[ni+3][kk];
            acc[0][0] += a0*b0; acc[0][1] += a0*b1; acc[0][2] += a0*b2; acc[0][3] += a0*b3;
            acc[1][0] += a1*b0; acc[1][1] += a1*b1; acc[1][2] += a1*b2; acc[1][3] += a1*b3;
        }
        __syncthreads();
    }
    #pragma unroll
    for (int r = 0; r < 2; ++r) {
        int m = m0 + mi + r*16;
        if (m >= M) continue;
        #pragma unroll
        for (int q = 0; q < 4; ++q) {
            int n = n0 + ni + q;
            if (n >= N) continue;
            float v = acc[r][q];
            if (bias)  v += bias[n];
            if (bias2) v += bias2[n];
            if (XPOSE) C[((size_t)(m % 31)*32 + (m / 31))*N + n] = v;
            else       C[(size_t)m*N + n] = v;
        }
    }
}

// ---------------- LSTM scan via MFMA: 2 blocks (one per direction), 32 batches/block ----------------
// Per kc: wave stages its 4KB whh slice (double-buffered via global_load_lds, counted
// vmcnt across raw barriers) and does 8 MFMAs (2 batch-tiles). Single hbuf, 2 barriers/step.
__launch_bounds__(1024)
__global__ void lstm_scan_mfma(const float* __restrict__ xpT,
                               const unsigned short* __restrict__ wf,
                               float* __restrict__ hcat)
{
    const int d = blockIdx.x;
    const int tid = threadIdx.x;
    const int u0 = tid >> 6;
    const int lane = tid & 63;
    const int l15 = lane & 15;
    const int q = lane >> 4;

    __shared__ unsigned short hbuf[8192];             // 16 KB (32 batches x 256 k)
    __shared__ unsigned short wst[16][2][2048];       // 128 KB

    ((int4*)hbuf)[tid] = make_int4(0,0,0,0);          // 1024 int4 = 16 KB

    const unsigned short* wfd = wf + (size_t)d*262144;
    const float* xpd = xpT + (size_t)d*992*1024;
    const unsigned short* wsrc = wfd + (size_t)u0*4096 + (size_t)lane*8;
    unsigned short* wl = &wst[u0][0][0];

#define STAGE(KC, PB) do { \
    unsigned short* dst_ = wl + (PB)*2048; \
    stage16(wsrc + 0*65536 + (KC)*512, dst_ + 0*512); \
    stage16(wsrc + 1*65536 + (KC)*512, dst_ + 1*512); \
    stage16(wsrc + 2*65536 + (KC)*512, dst_ + 2*512); \
    stage16(wsrc + 3*65536 + (KC)*512, dst_ + 3*512); \
} while(0)

    float c00=0.f,c01=0.f,c02=0.f,c03=0.f;   // cell, batch-tile 0
    float c10=0.f,c11=0.f,c12=0.f,c13=0.f;   // cell, batch-tile 1
    const int ubase = u0*16 + q*4;
    const int b0i = l15, b1i = 16 + l15;
    const int rb0 = b0i*512 + q*16;
    const int rb1 = b1i*512 + q*16;
    const int xr = (l15&7)<<4;               // same for b0i and b1i

    STAGE(0, 0);
    asm volatile("s_waitcnt lgkmcnt(0)" ::: "memory");
    __builtin_amdgcn_s_barrier();

#define HRD(RB, kc) (*(const short8*)(hb + (((RB) + (kc)*64) ^ xr)))
#define MF(w_,h_,a_) a_ = __builtin_amdgcn_mfma_f32_16x16x32_bf16(w_, h_, a_, 0, 0, 0)

    for (int s = 0; s < 31; ++s) {
        const int t = d ? (30 - s) : s;

        // xp for this step (drained at kc=1's vmcnt(4))
        const float* xb0 = xpd + (size_t)t*32768 + (size_t)b0i*1024;
        const float* xb1 = xpd + (size_t)t*32768 + (size_t)b1i*1024;
        float4 xi0 = *(const float4*)(xb0 + ubase);
        float4 xf0 = *(const float4*)(xb0 + 256 + ubase);
        float4 xg0 = *(const float4*)(xb0 + 512 + ubase);
        float4 xo0 = *(const float4*)(xb0 + 768 + ubase);
        float4 xi1 = *(const float4*)(xb1 + ubase);
        float4 xf1 = *(const float4*)(xb1 + 256 + ubase);
        float4 xg1 = *(const float4*)(xb1 + 512 + ubase);
        float4 xo1 = *(const float4*)(xb1 + 768 + ubase);

        const char* hb = (const char*)hbuf;
        f32x4 a00={0,0,0,0}, a01={0,0,0,0}, a02={0,0,0,0}, a03={0,0,0,0};
        f32x4 a10={0,0,0,0}, a11={0,0,0,0}, a12={0,0,0,0}, a13={0,0,0,0};

        #pragma unroll
        for (int kc = 0; kc < 8; ++kc) {
            if (kc < 7) STAGE(kc+1, (kc+1)&1);
            else        STAGE(0, 0);
            // kc==0: [stage0(old), stores(2,old), xp(8), stage1] -> drain stage0: vmcnt(14)
            // kc>=1: [<=xp(8) older..., stage kc, stage kc+1]   -> drain through stage kc: vmcnt(4)
            if (kc == 0) asm volatile("s_waitcnt vmcnt(14)" ::: "memory");
            else         asm volatile("s_waitcnt vmcnt(4)" ::: "memory");
            const unsigned short* wb = wl + (kc&1)*2048;
            short8 w0 = *(const short8*)(wb + 0*512 + lane*8);
            short8 w1 = *(const short8*)(wb + 1*512 + lane*8);
            short8 w2 = *(const short8*)(wb + 2*512 + lane*8);
            short8 w3 = *(const short8*)(wb + 3*512 + lane*8);
            short8 h0 = HRD(rb0, kc);
            short8 h1 = HRD(rb1, kc);
            MF(w0,h0,a00); MF(w1,h0,a01); MF(w2,h0,a02); MF(w3,h0,a03);
            MF(w0,h1,a10); MF(w1,h1,a11); MF(w2,h1,a12); MF(w3,h1,a13);
        }

        // all h reads done -> barrier #1, then overwrite hbuf in place
        asm volatile("s_waitcnt lgkmcnt(0)" ::: "memory");
        __builtin_amdgcn_s_barrier();

#define CELL(AI,AF,AG,AO, C0,C1,C2,C3, XI,XF,XG,XO, BIDX, RB) do { \
        float hv0, hv1, hv2, hv3; \
        { float gi=AI[0]+XI.x, gf=AF[0]+XF.x, gg=AG[0]+XG.x, go=AO[0]+XO.x; \
          float cn = sigmoidf_(gf)*C0 + sigmoidf_(gi)*tanhf(gg); C0 = cn; hv0 = sigmoidf_(go)*tanhf(cn); } \
        { float gi=AI[1]+XI.y, gf=AF[1]+XF.y, gg=AG[1]+XG.y, go=AO[1]+XO.y; \
          float cn = sigmoidf_(gf)*C1 + sigmoidf_(gi)*tanhf(gg); C1 = cn; hv1 = sigmoidf_(go)*tanhf(cn); } \
        { float gi=AI[2]+XI.z, gf=AF[2]+XF.z, gg=AG[2]+XG.z, go=AO[2]+XO.z; \
          float cn = sigmoidf_(gf)*C2 + sigmoidf_(gi)*tanhf(gg); C2 = cn; hv2 = sigmoidf_(go)*tanhf(cn); } \
        { float gi=AI[3]+XI.w, gf=AF[3]+XF.w, gg=AG[3]+XG.w, go=AO[3]+XO.w; \
          float cn = sigmoidf_(gf)*C3 + sigmoidf_(gi)*tanhf(gg); C3 = cn; hv3 = sigmoidf_(go)*tanhf(cn); } \
        short4 hp; \
        hp.x = (short)f2bf(hv0); hp.y = (short)f2bf(hv1); \
        hp.z = (short)f2bf(hv2); hp.w = (short)f2bf(hv3); \
        *(short4*)((char*)hbuf + ((((BIDX)*512 + ubase*2)) ^ xr)) = hp; \
        *(float4*)(&hcat[((size_t)(BIDX)*31 + t)*512 + (size_t)d*256 + ubase]) = \
            make_float4(hv0, hv1, hv2, hv3); \
} while(0)
        CELL(a00,a01,a02,a03, c00,c01,c02,c03, xi0,xf0,xg0,xo0, b0i, rb0);
        CELL(a10,a11,a12,a13, c10,c11,c12,c13, xi1,xf1,xg1,xo1, b1i, rb1);
#undef CELL

        // barrier #2: writes visible before next step's reads
        asm volatile("s_waitcnt lgkmcnt(0)" ::: "memory");
        __builtin_amdgcn_s_barrier();
    }
#undef STAGE
#undef HRD
#undef MF
}

extern "C" void kernel_launch(void* const* d_in, const int* in_sizes, int n_in,
                              void* d_out, int out_size, void* d_ws, size_t ws_size,
                              hipStream_t stream)
{
    const float* x    = (const float*)d_in[0];
    const float* fW   = (const float*)d_in[1];
    const float* fB   = (const float*)d_in[2];
    const float* cbw1 = (const float*)d_in[3];
    const float* cbg  = (const float*)d_in[4];
    const float* cbb  = (const float*)d_in[5];
    const float* cbw2 = (const float*)d_in[6];
    const float* r1pg = (const float*)d_in[7];
    const float* r1pb = (const float*)d_in[8];
    const float* r1wA = (const float*)d_in[9];
    const float* r1g  = (const float*)d_in[10];
    const float* r1b  = (const float*)d_in[11];
    const float* r1wB = (const float*)d_in[12];
    const float* r1s  = (const float*)d_in[13];
    const float* r2pg = (const float*)d_in[14];
    const float* r2pb = (const float*)d_in[15];
    const float* r2wA = (const float*)d_in[16];
    const float* r2g  = (const float*)d_in[17];
    const float* r2b  = (const float*)d_in[18];
    const float* r2wB = (const float*)d_in[19];
    const float* r2s  = (const float*)d_in[20];
    const float* r3pg = (const float*)d_in[21];
    const float* r3pb = (const float*)d_in[22];
    const float* r3wA = (const float*)d_in[23];
    const float* r3g  = (const float*)d_in[24];
    const float* r3b  = (const float*)d_in[25];
    const float* r3wB = (const float*)d_in[26];
    const float* r3s  = (const float*)d_in[27];
    const float* pbg  = (const float*)d_in[28];
    const float* pbb  = (const float*)d_in[29];
    const float* wih_f = (const float*)d_in[30];
    const float* whh_f = (const float*)d_in[31];
    const float* bih_f = (const float*)d_in[32];
    const float* bhh_f = (const float*)d_in[33];
    const float* wih_b = (const float*)d_in[34];
    const float* whh_b = (const float*)d_in[35];
    const float* bih_b = (const float*)d_in[36];
    const float* bhh_b = (const float*)d_in[37];
    const float* clsw  = (const float*)d_in[38];
    const float* clsb  = (const float*)d_in[39];
    float* out = (float*)d_out;
    float* ws  = (float*)d_ws;

    // ---- workspace sizing ----
    const size_t FIXEDF = 5543872;
    const size_t PCS = 2422720;
    const size_t PCF = (PCS + 1)/2;
    int NC = 0;
    const int cands[6] = {32,16,8,4,2,1};
    for (int i = 0; i < 6; ++i) {
        if ((FIXEDF + (size_t)cands[i]*PCF + 64)*sizeof(float) <= ws_size) { NC = cands[i]; break; }
    }
    if (!NC) return;

    float* p = ws;
    unsigned short* WTR = (unsigned short*)p; p += 962560;
    float* P   = p; p += 508896;
    float* XM  = p; p += 508896;
    unsigned short* XP4 = (unsigned short*)p; p += 253952;
    float* FE  = p; p += 507904;
    unsigned short* WF = (unsigned short*)p; p += 262144;
    float* XPT = p; p += 2031616;
    float* HC  = p; p += 507904;
    unsigned short* q = (unsigned short*)p;
    unsigned short* A1  = q; q += (size_t)NC*1087680;
    unsigned short* C1p = q; q += (size_t)NC*274560;
    unsigned short* A2  = q; q += (size_t)NC*549120;
    unsigned short* C2p = q; q += (size_t)NC*143616;
    unsigned short* A3  = q; q += (size_t)NC*215424;
    unsigned short* XP3 = q; q += (size_t)NC*65280;
    unsigned short* A4  = q; q += (size_t)NC*87040;

    unsigned short* w2T  = WTR + 0;
    unsigned short* r1AT = WTR + 36864;
    unsigned short* r1BT = WTR + 110592;
    unsigned short* r1ST = WTR + 258048;
    unsigned short* r2AT = WTR + 266240;
    unsigned short* r2BT = WTR + 487424;
    unsigned short* r2ST = WTR + 819200;
    unsigned short* r3AT = WTR + 843776;
    unsigned short* r3BT = WTR + 1286144;
    unsigned short* r3ST = WTR + 1875968;

    auto cdiv = [](int a, int b){ return (a + b - 1) / b; };

    // ---- weight transforms ----
    wtrans9_kernel<<<cdiv(9*64*64,256),   256, 0, stream>>>(cbw2, w2T, 64, 64);
    wtrans9_kernel<<<cdiv(9*128*64,256),  256, 0, stream>>>(r1wA, r1AT, 128, 64);
    wtrans9_kernel<<<cdiv(9*128*128,256), 256, 0, stream>>>(r1wB, r1BT, 128, 128);
    wtrans1_kernel<<<cdiv(128*64,256),    256, 0, stream>>>(r1s, r1ST, 128*64);
    wtrans9_kernel<<<cdiv(9*192*128,256), 256, 0, stream>>>(r2wA, r2AT, 192, 128);
    wtrans9_kernel<<<cdiv(9*192*192,256), 256, 0, stream>>>(r2wB, r2BT, 192, 192);
    wtrans1_kernel<<<cdiv(192*128,256),   256, 0, stream>>>(r2s, r2ST, 192*128);
    wtrans9_kernel<<<cdiv(9*256*192,256), 256, 0, stream>>>(r3wA, r3AT, 256, 192);
    wtrans9_kernel<<<cdiv(9*256*256,256), 256, 0, stream>>>(r3wB, r3BT, 256, 256);
    wtrans1_kernel<<<cdiv(256*192,256),   256, 0, stream>>>(r3s, r3ST, 256*192);
    whh_frag_kernel<<<1024, 256, 0, stream>>>(whh_f, WF);
    whh_frag_kernel<<<1024, 256, 0, stream>>>(whh_b, WF + 262144);

    // ---- frontend mask ----
    mask_partial_kernel<<<dim3(63, 32), 256, 0, stream>>>(fW, fB, P);
    mask_finalize_apply<<<63, 256, 0, stream>>>(P, x, XM);

    // ---- zero padded staging region (all halos stay zero) ----
    hipMemsetAsync(A1, 0, (size_t)NC*PCS*sizeof(unsigned short), stream);

    // ---- conv stack, chunked over batch ----
    for (int c0 = 0; c0 < 32; c0 += NC) {
        const float* xmc = XM + (size_t)c0*15903;
        conv1_kernel<<<dim3(63, 1, NC), 256, 0, stream>>>(xmc, cbw1, cbg, cbb, A1);
        // conv2 + bn+lrelu+pool4: 64ch, 513->128 -> C1p [33][130][64]
        conv_lds_kernel<64,8,0,1><<<dim3(4*31, 1, NC), 256, 0, stream>>>(
            A1, w2T, nullptr, nullptr, C1p, 515, 4, 0, 33, 1, 130, 1, 64, r1pg, r1pb);
        // r1A: 64->128 -> A2 [33][130][128]
        conv_lds_kernel<64,8,0,0><<<dim3(31, 2, NC), 256, 0, stream>>>(
            C1p, r1AT, nullptr, nullptr, A2, 130, 1, 0, 33, 1, 130, 1, 128, r1g, r1b);
        // r1B + shortcut + pool4: 128ch, 128->32 -> C2p [33][34][128]  (TPX=8, round-13 config)
        conv_lds_kernel<128,8,64,1><<<dim3(31, 2, NC), 256, 0, stream>>>(
            A2, r1BT, C1p, r1ST, C2p, 130, 1, 130, 33, 1, 34, 1, 128, r2pg, r2pb);
        // r2A: 128->192 -> A3 [33][34][192]
        conv_lds_kernel<128,2,0,0><<<dim3(31, 3, NC), 256, 0, stream>>>(
            C2p, r2AT, nullptr, nullptr, A3, 34, 1, 0, 33, 1, 34, 1, 192, r2g, r2b);
        // r2B + shortcut + pool4: 192ch, 32->8 -> XP3 [34][10][192] padded
        conv_lds_kernel<192,2,128,1><<<dim3(31, 3, NC), 256, 0, stream>>>(
            A3, r2BT, C2p, r2ST, XP3, 34, 1, 34, 34, 1, 10, 1, 192, r3pg, r3pb);
        // r3A: 192->256 -> A4 [34][10][256] padded
        conv_w8_kernel<192,0,0><<<dim3(16, 2, NC), 256, 0, stream>>>(
            XP3, r3AT, nullptr, nullptr, A4, 256, r3g, r3b);
        // r3B + shortcut + bn+lrelu+pool(8->2) -> XP4 slice directly
        conv_w8_kernel<256,192,1><<<dim3(16, 2, NC), 256, 0, stream>>>(
            A4, r3BT, XP3, r3ST, XP4 + (size_t)c0*15872, 256, pbg, pbb);
    }

    // feats (32,31,512) fp32
    feats_kernel<<<1984, 256, 0, stream>>>(XP4, FE);

    // LSTM input projections -> xpT [d][t][b][j]
    gemm_bias_kernel<1><<<dim3(31, 16), 256, 0, stream>>>(FE, wih_f, bih_f, bhh_f, XPT,           992, 1024, 512);
    gemm_bias_kernel<1><<<dim3(31, 16), 256, 0, stream>>>(FE, wih_b, bih_b, bhh_b, XPT + 1015808, 992, 1024, 512);

    // fused bidirectional scan (2 blocks: one per direction, 32 batches each)
    lstm_scan_mfma<<<2, 1024, 0, stream>>>(XPT, WF, HC);

    // classifier -> d_out (32,31,722)
    gemm_bias_kernel<0><<<dim3(31, 12), 256, 0, stream>>>(HC, clsw, clsb, nullptr, out, 992, 722, 512);
}

// Round 16
// 1368.671 us; speedup vs baseline: 1.3172x; 1.3172x over previous
//
#include <hip/hip_runtime.h>
#include <hip/hip_bf16.h>
#include <math.h>

#define RSQ 0.99999500003749969f   // 1/sqrt(1+1e-5)
#define SLOPE 0.01f

typedef __attribute__((ext_vector_type(8))) short short8;
typedef __attribute__((ext_vector_type(4))) float f32x4;

__device__ __forceinline__ float sigmoidf_(float x){ return 1.0f/(1.0f+expf(-x)); }

__device__ __forceinline__ unsigned short f2bf(float f){
    unsigned u = __float_as_uint(f);
    u += 0x7fff + ((u >> 16) & 1);      // RNE
    return (unsigned short)(u >> 16);
}
__device__ __forceinline__ float bf2f(unsigned short s){
    return __uint_as_float(((unsigned)s) << 16);
}

// async global->LDS, 16B per lane
__device__ __forceinline__ void stage16(const unsigned short* g, unsigned short* l) {
    __builtin_amdgcn_global_load_lds(
        (const __attribute__((address_space(1))) unsigned int*)g,
        (__attribute__((address_space(3))) unsigned int*)l, 16, 0, 0);
}

// ---------------- mask: prod_k cos(fW*rng + fB) ----------------
__global__ void mask_partial_kernel(const float* __restrict__ fW, const float* __restrict__ fB,
                                    float* __restrict__ partial)
{
    int p = blockIdx.x*256 + threadIdx.x;   // 0..15902
    if (p >= 15903) return;
    int w = p % 513;
    float r = (float)(w + 1);
    int k0 = blockIdx.y * 32;
    float prod = 1.0f;
    for (int k = k0; k < k0 + 32; ++k) {
        float a = fW[(size_t)k*15903 + p] * r + fB[(size_t)k*15903 + p];
        prod *= cosf(a);
    }
    partial[blockIdx.y*15903 + p] = prod;
}

__global__ void mask_finalize_apply(const float* __restrict__ partial, const float* __restrict__ x,
                                    float* __restrict__ xm)
{
    int p = blockIdx.x*256 + threadIdx.x;
    if (p >= 15903) return;
    float m = 1.0f;
    #pragma unroll
    for (int c = 0; c < 32; ++c) m *= partial[c*15903 + p];
    for (int n = 0; n < 32; ++n)
        xm[(size_t)n*15903 + p] = x[(size_t)n*15903 + p] * m;
}

// ---------------- weight transforms ----------------
__global__ void wtrans9_kernel(const float* __restrict__ w, unsigned short* __restrict__ o,
                               int Cout, int Cin)
{
    int idx = blockIdx.x*256 + threadIdx.x;
    int cc = Cout*Cin;
    if (idx >= 9*cc) return;
    int tap = idx / cc;
    int r = idx - tap*cc;
    int co = r / Cin, ci = r - co*Cin;
    int kh = tap/3, kw = tap - kh*3;
    o[idx] = f2bf(w[((size_t)(co*Cin + ci)*3 + kh)*3 + kw]);
}
__global__ void wtrans1_kernel(const float* __restrict__ w, unsigned short* __restrict__ o, int total)
{
    int idx = blockIdx.x*256 + threadIdx.x;
    if (idx < total) o[idx] = f2bf(w[idx]);
}

// whh (1024,256) fp32 -> MFMA-fragment-contiguous bf16
__global__ void whh_frag_kernel(const float* __restrict__ whh, unsigned short* __restrict__ out)
{
    int tid = blockIdx.x*256 + threadIdx.x;  // 262144 exact
    int e    = tid & 7;
    int lane = (tid >> 3) & 63;
    int kc   = (tid >> 9) & 7;
    int u0   = (tid >> 12) & 15;
    int g    = tid >> 16;
    int j = (g << 8) + (u0 << 4) + (lane & 15);
    int k = (kc << 5) + ((lane >> 4) << 3) + e;
    out[tid] = f2bf(whh[(size_t)j*256 + k]);
}

// ---------------- conv1: Cin=1 direct, fp32 in -> bf16 NHWC (rows 1..31 of [33][515][64]) ----------------
__launch_bounds__(256)
__global__ void conv1_kernel(const float* __restrict__ xm, const float* __restrict__ w1,
                             const float* __restrict__ g, const float* __restrict__ b,
                             unsigned short* __restrict__ O)
{
    __shared__ float wl[576];
    __shared__ float sg[64], sb[64];
    int tid = threadIdx.x;
    if (tid < 64) { sg[tid] = g[tid]*RSQ; sb[tid] = b[tid]; }
    for (int i = tid; i < 576; i += 256) wl[i] = w1[i];
    __syncthreads();
    int px = blockIdx.x*256 + tid;
    int n = blockIdx.z;
    if (px >= 15903) return;
    int h = px / 513, w = px - h*513;
    const float* xp = xm + (size_t)n*15903;
    float v[9];
    #pragma unroll
    for (int dh = 0; dh < 3; ++dh)
      #pragma unroll
      for (int dw = 0; dw < 3; ++dw) {
        int hh = h+dh-1, ww = w+dw-1;
        bool ok = ((unsigned)hh < 31u) && ((unsigned)ww < 513u);
        v[dh*3+dw] = ok ? xp[hh*513 + ww] : 0.f;
      }
    unsigned short* op = O + (((size_t)(n*33 + h + 1))*515 + (w + 1))*64;
    #pragma unroll
    for (int c8 = 0; c8 < 8; ++c8) {
        unsigned tmp[8];
        #pragma unroll
        for (int j = 0; j < 8; ++j) {
            int co = c8*8 + j;
            const float* wr = &wl[co*9];
            float a = 0.f;
            #pragma unroll
            for (int t2 = 0; t2 < 9; ++t2) a += wr[t2]*v[t2];
            a = a*sg[co] + sb[co];
            a = (a >= 0.f) ? a : SLOPE*a;
            tmp[j] = f2bf(a);
        }
        uint4 pk;
        pk.x = tmp[0] | (tmp[1]<<16);
        pk.y = tmp[2] | (tmp[3]<<16);
        pk.z = tmp[4] | (tmp[5]<<16);
        pk.w = tmp[6] | (tmp[7]<<16);
        *(uint4*)(op + c8*8) = pk;
    }
}

// ---------------- LDS-staged implicit-GEMM 3x3 conv (+1x1 shortcut) via MFMA ----------------
template<int CIN, int TPX, int CS, int POOL>
__launch_bounds__(256, 2)
__global__ void conv_lds_kernel(const unsigned short* __restrict__ X,
                                const unsigned short* __restrict__ W9,
                                const unsigned short* __restrict__ Xs,
                                const unsigned short* __restrict__ Ws,
                                unsigned short* __restrict__ O,
                                int Wp, int WT, int WpS,
                                int HO, int HOFF, int WpO, int OOFF, int Cout,
                                const float* __restrict__ g, const float* __restrict__ b)
{
    constexpr int KQ  = CIN/8;
    constexpr int PXT = TPX*16 + 2;
    constexpr int UX  = 3*PXT*KQ;
    constexpr int KQS = (CS > 0) ? CS/8 : 8;
    constexpr int US  = (CS > 0) ? TPX*16*KQS : 0;
    constexpr int UT  = UX + US;
    constexpr int NU  = (UT + 255)/256;
    constexpr int NKC = CIN/32;
    __shared__ uint4 lds4[UT + 8];

    const int tid = threadIdx.x;
    const int lane = tid & 63;
    const int wave = tid >> 6;
    const int cob  = blockIdx.y*64 + wave*16;
    const int n  = blockIdx.z;
    const int wt = blockIdx.x % WT;
    const int h  = blockIdx.x / WT;
    const int w0 = wt*(TPX*16);
    const int l15 = lane & 15;
    const int gq  = lane >> 4;

    uint4 tmp[NU];
    #pragma unroll
    for (int i = 0; i < NU; ++i) {
        int u = tid + i*256;
        if (u < UX) {
            int r   = u / (PXT*KQ);
            int rem = u - r*(PXT*KQ);
            int px  = rem / KQ;
            int kq  = rem - px*KQ;
            tmp[i] = *(const uint4*)(X + (((size_t)(n*33 + h + r))*Wp + w0 + px)*CIN + kq*8);
        } else if (CS > 0 && u < UT) {
            int us = u - UX;
            int px = us / KQS;
            int kq = us - px*KQS;
            tmp[i] = *(const uint4*)(Xs + (((size_t)(n*33 + h + 1))*WpS + w0 + 1 + px)*CS + kq*8);
        }
    }
    #pragma unroll
    for (int i = 0; i < NU; ++i) {
        int u = tid + i*256;
        if (u < UT) {
            int px;
            if (u < UX) { int rem = u % (PXT*KQ); px = rem / KQ; }
            else        { px = (u - UX) / KQS; }
            *(uint4*)((char*)lds4 + ((u*16) ^ ((px & 7) << 4))) = tmp[i];
        }
    }
    __syncthreads();

    f32x4 acc[TPX] = {};
    #pragma unroll
    for (int dh = 0; dh < 3; ++dh) {
        short8 aw[3*NKC];
        #pragma unroll
        for (int dw = 0; dw < 3; ++dw)
            #pragma unroll
            for (int kc = 0; kc < NKC; ++kc)
                aw[dw*NKC + kc] = *(const short8*)(W9 +
                    ((size_t)((dh*3 + dw)*Cout + cob + l15))*CIN + kc*32 + gq*8);
        #pragma unroll
        for (int dw = 0; dw < 3; ++dw) {
            #pragma unroll
            for (int kc = 0; kc < NKC; ++kc) {
                short8 a = aw[dw*NKC + kc];
                #pragma unroll
                for (int t = 0; t < TPX; ++t) {
                    int px = dw + t*16 + l15;
                    int u  = (dh*PXT + px)*KQ + kc*4 + gq;
                    short8 bv = *(const short8*)((const char*)lds4 + ((u*16) ^ ((px & 7) << 4)));
                    acc[t] = __builtin_amdgcn_mfma_f32_16x16x32_bf16(a, bv, acc[t], 0, 0, 0);
                }
            }
        }
    }

    if (CS > 0) {
        #pragma unroll
        for (int kc = 0; kc < KQS/4; ++kc) {
            short8 a = *(const short8*)(Ws + (size_t)(cob + l15)*CS + kc*32 + gq*8);
            #pragma unroll
            for (int t = 0; t < TPX; ++t) {
                int px = t*16 + l15;
                int u  = UX + px*KQS + kc*4 + gq;
                short8 bv = *(const short8*)((const char*)lds4 + ((u*16) ^ ((px & 7) << 4)));
                acc[t] = __builtin_amdgcn_mfma_f32_16x16x32_bf16(a, bv, acc[t], 0, 0, 0);
            }
        }
    }

    int cb = cob + gq*4;
    float s0 = g[cb+0]*RSQ, s1 = g[cb+1]*RSQ, s2 = g[cb+2]*RSQ, s3 = g[cb+3]*RSQ;
    float o0 = b[cb+0], o1 = b[cb+1], o2 = b[cb+2], o3 = b[cb+3];
    #pragma unroll
    for (int t = 0; t < TPX; ++t) {
        float v0 = acc[t][0]*s0 + o0; v0 = (v0 >= 0.f) ? v0 : SLOPE*v0;
        float v1 = acc[t][1]*s1 + o1; v1 = (v1 >= 0.f) ? v1 : SLOPE*v1;
        float v2 = acc[t][2]*s2 + o2; v2 = (v2 >= 0.f) ? v2 : SLOPE*v2;
        float v3 = acc[t][3]*s3 + o3; v3 = (v3 >= 0.f) ? v3 : SLOPE*v3;
        if (POOL) {
            v0 = fmaxf(v0, __shfl_xor(v0, 1)); v0 = fmaxf(v0, __shfl_xor(v0, 2));
            v1 = fmaxf(v1, __shfl_xor(v1, 1)); v1 = fmaxf(v1, __shfl_xor(v1, 2));
            v2 = fmaxf(v2, __shfl_xor(v2, 1)); v2 = fmaxf(v2, __shfl_xor(v2, 2));
            v3 = fmaxf(v3, __shfl_xor(v3, 1)); v3 = fmaxf(v3, __shfl_xor(v3, 2));
            if ((l15 & 3) == 0) {
                int pw = (w0 + t*16 + l15) >> 2;
                uint2 pk;
                pk.x = (unsigned)f2bf(v0) | ((unsigned)f2bf(v1) << 16);
                pk.y = (unsigned)f2bf(v2) | ((unsigned)f2bf(v3) << 16);
                *(uint2*)(O + (((size_t)(n*HO + h + HOFF))*WpO + pw + OOFF)*Cout + cb) = pk;
            }
        } else {
            int w = w0 + t*16 + l15;
            uint2 pk;
            pk.x = (unsigned)f2bf(v0) | ((unsigned)f2bf(v1) << 16);
            pk.y = (unsigned)f2bf(v2) | ((unsigned)f2bf(v3) << 16);
            *(uint2*)(O + (((size_t)(n*HO + h + HOFF))*WpO + w + OOFF)*Cout + cb) = pk;
        }
    }
}

// ---------------- W=8 LDS-staged conv for r3 layers ----------------
template<int CIN, int CS, int POOL>
__launch_bounds__(256, 2)
__global__ void conv_w8_kernel(const unsigned short* __restrict__ X,
                               const unsigned short* __restrict__ W9,
                               const unsigned short* __restrict__ Xs,
                               const unsigned short* __restrict__ Ws,
                               unsigned short* __restrict__ O, int Cout,
                               const float* __restrict__ g, const float* __restrict__ b)
{
    constexpr int KQ  = CIN/8;
    constexpr int UX  = 4*10*KQ;
    constexpr int KQS = (CS > 0) ? CS/8 : 8;
    constexpr int US  = (CS > 0) ? 2*8*KQS : 0;
    constexpr int UT  = UX + US;
    constexpr int NU  = (UT + 255)/256;
    constexpr int NKC = CIN/32;
    __shared__ uint4 lds4[UT + 8];

    const int tid = threadIdx.x;
    const int lane = tid & 63;
    const int wave = tid >> 6;
    const int hp = blockIdx.x;          // 0..15
    const int n  = blockIdx.z;
    const int h0 = hp*2;
    const int l15 = lane & 15;
    const int gq  = lane >> 4;
    const int r = l15 >> 3;
    const int w = l15 & 7;
    const int cwb = blockIdx.y*128 + wave*32;

    uint4 tmp[NU];
    #pragma unroll
    for (int i = 0; i < NU; ++i) {
        int u = tid + i*256;
        if (u < UX) {
            int row = u / (10*KQ);
            int rem = u - row*(10*KQ);
            int px  = rem / KQ;
            int kq  = rem - px*KQ;
            tmp[i] = *(const uint4*)(X + (((size_t)(n*34 + h0 + row))*10 + px)*CIN + kq*8);
        } else if (CS > 0 && u < UT) {
            int us = u - UX;
            int rs = us / (8*KQS);
            int rem = us - rs*(8*KQS);
            int px8 = rem / KQS;
            int kq  = rem - px8*KQS;
            tmp[i] = *(const uint4*)(Xs + (((size_t)(n*34 + h0 + 1 + rs))*10 + px8 + 1)*CS + kq*8);
        }
    }
    #pragma unroll
    for (int i = 0; i < NU; ++i) {
        int u = tid + i*256;
        if (u < UT) {
            int key;
            if (u < UX) { int rem = u % (10*KQ); key = rem / KQ; }
            else        { key = ((u - UX) % (8*KQS)) / KQS; }
            *(uint4*)((char*)lds4 + ((u*16) ^ ((key & 7) << 4))) = tmp[i];
        }
    }
    __syncthreads();

    f32x4 acc0 = {0,0,0,0}, acc1 = {0,0,0,0};
    #pragma unroll
    for (int dh = 0; dh < 3; ++dh) {
        #pragma unroll
        for (int dw = 0; dw < 3; ++dw) {
            short8 a0[NKC], a1[NKC];
            #pragma unroll
            for (int kc = 0; kc < NKC; ++kc) {
                a0[kc] = *(const short8*)(W9 + ((size_t)((dh*3+dw)*Cout + cwb + l15))*CIN + kc*32 + gq*8);
                a1[kc] = *(const short8*)(W9 + ((size_t)((dh*3+dw)*Cout + cwb + 16 + l15))*CIN + kc*32 + gq*8);
            }
            #pragma unroll
            for (int kc = 0; kc < NKC; ++kc) {
                int row_s = r + dh;
                int col = w + dw;
                int u = (row_s*10 + col)*KQ + kc*4 + gq;
                short8 bv = *(const short8*)((const char*)lds4 + ((u*16) ^ ((col & 7) << 4)));
                acc0 = __builtin_amdgcn_mfma_f32_16x16x32_bf16(a0[kc], bv, acc0, 0, 0, 0);
                acc1 = __builtin_amdgcn_mfma_f32_16x16x32_bf16(a1[kc], bv, acc1, 0, 0, 0);
            }
        }
    }

    if (CS > 0) {
        #pragma unroll
        for (int kc = 0; kc < KQS/4; ++kc) {
            short8 a0 = *(const short8*)(Ws + (size_t)(cwb + l15)*CS + kc*32 + gq*8);
            short8 a1 = *(const short8*)(Ws + (size_t)(cwb + 16 + l15)*CS + kc*32 + gq*8);
            int u = UX + (r*8 + w)*KQS + kc*4 + gq;
            short8 bv = *(const short8*)((const char*)lds4 + ((u*16) ^ ((w & 7) << 4)));
            acc0 = __builtin_amdgcn_mfma_f32_16x16x32_bf16(a0, bv, acc0, 0, 0, 0);
            acc1 = __builtin_amdgcn_mfma_f32_16x16x32_bf16(a1, bv, acc1, 0, 0, 0);
        }
    }

    const int hr = h0 + r;
    const bool valid = hr < 31;
#define EPIG8(ACC, G) do { \
    int cb = cwb + (G)*16 + gq*4; \
    float s0 = g[cb+0]*RSQ, s1 = g[cb+1]*RSQ, s2 = g[cb+2]*RSQ, s3 = g[cb+3]*RSQ; \
    float o0 = b[cb+0], o1 = b[cb+1], o2 = b[cb+2], o3 = b[cb+3]; \
    float v0 = ACC[0]*s0 + o0; v0 = (v0 >= 0.f) ? v0 : SLOPE*v0; \
    float v1 = ACC[1]*s1 + o1; v1 = (v1 >= 0.f) ? v1 : SLOPE*v1; \
    float v2 = ACC[2]*s2 + o2; v2 = (v2 >= 0.f) ? v2 : SLOPE*v2; \
    float v3 = ACC[3]*s3 + o3; v3 = (v3 >= 0.f) ? v3 : SLOPE*v3; \
    if (POOL) { \
        v0 = fmaxf(v0, __shfl_xor(v0, 1)); v0 = fmaxf(v0, __shfl_xor(v0, 2)); \
        v1 = fmaxf(v1, __shfl_xor(v1, 1)); v1 = fmaxf(v1, __shfl_xor(v1, 2)); \
        v2 = fmaxf(v2, __shfl_xor(v2, 1)); v2 = fmaxf(v2, __shfl_xor(v2, 2)); \
        v3 = fmaxf(v3, __shfl_xor(v3, 1)); v3 = fmaxf(v3, __shfl_xor(v3, 2)); \
        if (((l15 & 3) == 0) && valid) { \
            uint2 pk; \
            pk.x = (unsigned)f2bf(v0) | ((unsigned)f2bf(v1) << 16); \
            pk.y = (unsigned)f2bf(v2) | ((unsigned)f2bf(v3) << 16); \
            *(uint2*)(O + (((size_t)(n*31 + hr))*2 + (w >> 2))*Cout + cb) = pk; \
        } \
    } else if (valid) { \
        uint2 pk; \
        pk.x = (unsigned)f2bf(v0) | ((unsigned)f2bf(v1) << 16); \
        pk.y = (unsigned)f2bf(v2) | ((unsigned)f2bf(v3) << 16); \
        *(uint2*)(O + (((size_t)(n*34 + hr + 1))*10 + w + 1)*Cout + cb) = pk; \
    } \
} while(0)
    EPIG8(acc0, 0);
    EPIG8(acc1, 1);
#undef EPIG8
}

// ---------------- feats: [n][31][2][256] bf16 NHWC -> [n][31][512] fp32 ----------------
__global__ void feats_kernel(const unsigned short* __restrict__ p4, float* __restrict__ fe)
{
    int idx = blockIdx.x*256 + threadIdx.x;   // 507904
    int cw = idx & 511;
    int nh = idx >> 9;
    int c = cw >> 1, w = cw & 1;
    fe[idx] = bf2f(p4[((size_t)nh*2 + w)*256 + c]);
}

// ---------------- tiled SGEMM: C[M,N] = A[M,K] @ B[N,K]^T + bias(+bias2) ----------------
#define GM 32
#define GN 64
#define GK 32
template<int XPOSE>
__launch_bounds__(256)
__global__ void gemm_bias_kernel(const float* __restrict__ A, const float* __restrict__ B,
                                 const float* __restrict__ bias, const float* __restrict__ bias2,
                                 float* __restrict__ C, int M, int N, int K)
{
    __shared__ float As[GM][GK+1];
    __shared__ float Bs[GN][GK+1];
    int m0 = blockIdx.x*GM, n0 = blockIdx.y*GN;
    int tid = threadIdx.x;
    int mi = tid >> 4;
    int ni = (tid & 15) * 4;
    float acc[2][4] = {};

    for (int k0 = 0; k0 < K; k0 += GK) {
        for (int i = tid; i < GM*GK; i += 256) {
            int r = i >> 5, c = i & 31;
            int m = m0 + r;
            As[r][c] = (m < M) ? A[(size_t)m*K + k0 + c] : 0.f;
        }
        for (int i = tid; i < GN*GK; i += 256) {
            int r = i >> 5, c = i & 31;
            int n = n0 + r;
            Bs[r][c] = (n < N) ? B[(size_t)n*K + k0 + c] : 0.f;
        }
        __syncthreads();
        #pragma unroll
        for (int kk = 0; kk < GK; ++kk) {
            float a0 = As[mi][kk], a1 = As[mi+16][kk];
            float b0 = Bs[ni][kk], b1 = Bs[ni+1][kk], b2 = Bs[ni+2][kk], b3 = Bs[ni+3][kk];
            acc[0][0] += a0*b0; acc[0][1] += a0*b1; acc[0][2] += a0*b2; acc[0][3] += a0*b3;
            acc[1][0] += a1*b0; acc[1][1] += a1*b1; acc[1][2] += a1*b2; acc[1][3] += a1*b3;
        }
        __syncthreads();
    }
    #pragma unroll
    for (int r = 0; r < 2; ++r) {
        int m = m0 + mi + r*16;
        if (m >= M) continue;
        #pragma unroll
        for (int q = 0; q < 4; ++q) {
            int n = n0 + ni + q;
            if (n >= N) continue;
            float v = acc[r][q];
            if (bias)  v += bias[n];
            if (bias2) v += bias2[n];
            if (XPOSE) C[((size_t)(m % 31)*32 + (m / 31))*N + n] = v;
            else       C[(size_t)m*N + n] = v;
        }
    }
}

// ---------------- LSTM scan via MFMA: 4 blocks = (dir x batch-half), 1024 thr ----------------
// (round-14 proven version: counted vmcnt across raw barriers, xp prefetched 1 step ahead)
__launch_bounds__(1024)
__global__ void lstm_scan_mfma(const float* __restrict__ xpT,
                               const unsigned short* __restrict__ wf,
                               float* __restrict__ hcat)
{
    const int d  = blockIdx.x >> 1;
    const int bh = blockIdx.x & 1;
    const int tid = threadIdx.x;
    const int u0 = tid >> 6;
    const int lane = tid & 63;
    const int l15 = lane & 15;
    const int q = lane >> 4;

    __shared__ unsigned short hbuf[2][4096];          // 16 KB
    __shared__ unsigned short wst[16][2][2048];       // 128 KB

    ((int4*)hbuf)[tid & 1023] = make_int4(0,0,0,0);

    const unsigned short* wfd = wf + (size_t)d*262144;
    const float* xpd = xpT + (size_t)d*992*1024 + (size_t)bh*16*1024;
    const unsigned short* wsrc = wfd + (size_t)u0*4096 + (size_t)lane*8;
    unsigned short* wl = &wst[u0][0][0];

#define STAGE(KC, PB) do { \
    unsigned short* dst_ = wl + (PB)*2048; \
    stage16(wsrc + 0*65536 + (KC)*512, dst_ + 0*512); \
    stage16(wsrc + 1*65536 + (KC)*512, dst_ + 1*512); \
    stage16(wsrc + 2*65536 + (KC)*512, dst_ + 2*512); \
    stage16(wsrc + 3*65536 + (KC)*512, dst_ + 3*512); \
} while(0)

    float c0=0.f, c1=0.f, c2=0.f, c3=0.f;
    const int ubase = u0*16 + q*4;
    const int rb = l15*512 + q*16;
    const int xr = (l15&7)<<4;

    STAGE(0, 0);
    float4 xi, xf, xg, xo;
    {
        const int t0 = d ? 30 : 0;
        const float* xb = xpd + (size_t)t0*32768 + (size_t)l15*1024;
        xi = *(const float4*)(xb + ubase);
        xf = *(const float4*)(xb + 256 + ubase);
        xg = *(const float4*)(xb + 512 + ubase);
        xo = *(const float4*)(xb + 768 + ubase);
    }
    asm volatile("s_waitcnt lgkmcnt(0)" ::: "memory");
    __builtin_amdgcn_s_barrier();

#define HRD(kc)   (*(const short8*)(hb + ((rb + (kc)*64) ^ xr)))
#define MF(w_,h_,a_) a_ = __builtin_amdgcn_mfma_f32_16x16x32_bf16(w_, h_, a_, 0, 0, 0)

    for (int s = 0; s < 31; ++s) {
        const int t = d ? (30 - s) : s;
        const int cur = s & 1, nxt = cur ^ 1;

        const char* hb = (const char*)hbuf[cur];
        f32x4 a0={0,0,0,0}, a1={0,0,0,0}, a2={0,0,0,0}, a3={0,0,0,0};

        #pragma unroll
        for (int kc = 0; kc < 8; ++kc) {
            if (kc < 7) STAGE(kc+1, (kc+1)&1);
            else        STAGE(0, 0);
            if (kc == 0) asm volatile("s_waitcnt vmcnt(8)" ::: "memory");
            else         asm volatile("s_waitcnt vmcnt(4)" ::: "memory");
            const unsigned short* wb = wl + (kc&1)*2048;
            short8 w0 = *(const short8*)(wb + 0*512 + lane*8);
            short8 w1 = *(const short8*)(wb + 1*512 + lane*8);
            short8 w2 = *(const short8*)(wb + 2*512 + lane*8);
            short8 w3 = *(const short8*)(wb + 3*512 + lane*8);
            short8 h = HRD(kc);
            MF(w0,h,a0); MF(w1,h,a1); MF(w2,h,a2); MF(w3,h,a3);
        }

        float4 nxi, nxf, nxg, nxo;
        {
            int s2 = (s < 30) ? s + 1 : s;
            int t2 = d ? (30 - s2) : s2;
            const float* xb = xpd + (size_t)t2*32768 + (size_t)l15*1024;
            nxi = *(const float4*)(xb + ubase);
            nxf = *(const float4*)(xb + 256 + ubase);
            nxg = *(const float4*)(xb + 512 + ubase);
            nxo = *(const float4*)(xb + 768 + ubase);
        }

        float hv0, hv1, hv2, hv3;
        { float gi=a0[0]+xi.x, gf=a1[0]+xf.x, gg=a2[0]+xg.x, go=a3[0]+xo.x;
          float cn = sigmoidf_(gf)*c0 + sigmoidf_(gi)*tanhf(gg); c0 = cn; hv0 = sigmoidf_(go)*tanhf(cn); }
        { float gi=a0[1]+xi.y, gf=a1[1]+xf.y, gg=a2[1]+xg.y, go=a3[1]+xo.y;
          float cn = sigmoidf_(gf)*c1 + sigmoidf_(gi)*tanhf(gg); c1 = cn; hv1 = sigmoidf_(go)*tanhf(cn); }
        { float gi=a0[2]+xi.z, gf=a1[2]+xf.z, gg=a2[2]+xg.z, go=a3[2]+xo.z;
          float cn = sigmoidf_(gf)*c2 + sigmoidf_(gi)*tanhf(gg); c2 = cn; hv2 = sigmoidf_(go)*tanhf(cn); }
        { float gi=a0[3]+xi.w, gf=a1[3]+xf.w, gg=a2[3]+xg.w, go=a3[3]+xo.w;
          float cn = sigmoidf_(gf)*c3 + sigmoidf_(gi)*tanhf(gg); c3 = cn; hv3 = sigmoidf_(go)*tanhf(cn); }

        short4 hp;
        hp.x = (short)f2bf(hv0); hp.y = (short)f2bf(hv1);
        hp.z = (short)f2bf(hv2); hp.w = (short)f2bf(hv3);
        *(short4*)((char*)hbuf[nxt] + ((l15*512 + ubase*2) ^ xr)) = hp;
        int bg = bh*16 + l15;
        *(float4*)(&hcat[((size_t)bg*31 + t)*512 + (size_t)d*256 + ubase]) =
            make_float4(hv0, hv1, hv2, hv3);

        asm volatile("s_waitcnt lgkmcnt(0)" ::: "memory");
        __builtin_amdgcn_s_barrier();

        xi = nxi; xf = nxf; xg = nxg; xo = nxo;
    }
#undef STAGE
#undef HRD
#undef MF
}

extern "C" void kernel_launch(void* const* d_in, const int* in_sizes, int n_in,
                              void* d_out, int out_size, void* d_ws, size_t ws_size,
                              hipStream_t stream)
{
    const float* x    = (const float*)d_in[0];
    const float* fW   = (const float*)d_in[1];
    const float* fB   = (const float*)d_in[2];
    const float* cbw1 = (const float*)d_in[3];
    const float* cbg  = (const float*)d_in[4];
    const float* cbb  = (const float*)d_in[5];
    const float* cbw2 = (const float*)d_in[6];
    const float* r1pg = (const float*)d_in[7];
    const float* r1pb = (const float*)d_in[8];
    const float* r1wA = (const float*)d_in[9];
    const float* r1g  = (const float*)d_in[10];
    const float* r1b  = (const float*)d_in[11];
    const float* r1wB = (const float*)d_in[12];
    const float* r1s  = (const float*)d_in[13];
    const float* r2pg = (const float*)d_in[14];
    const float* r2pb = (const float*)d_in[15];
    const float* r2wA = (const float*)d_in[16];
    const float* r2g  = (const float*)d_in[17];
    const float* r2b  = (const float*)d_in[18];
    const float* r2wB = (const float*)d_in[19];
    const float* r2s  = (const float*)d_in[20];
    const float* r3pg = (const float*)d_in[21];
    const float* r3pb = (const float*)d_in[22];
    const float* r3wA = (const float*)d_in[23];
    const float* r3g  = (const float*)d_in[24];
    const float* r3b  = (const float*)d_in[25];
    const float* r3wB = (const float*)d_in[26];
    const float* r3s  = (const float*)d_in[27];
    const float* pbg  = (const float*)d_in[28];
    const float* pbb  = (const float*)d_in[29];
    const float* wih_f = (const float*)d_in[30];
    const float* whh_f = (const float*)d_in[31];
    const float* bih_f = (const float*)d_in[32];
    const float* bhh_f = (const float*)d_in[33];
    const float* wih_b = (const float*)d_in[34];
    const float* whh_b = (const float*)d_in[35];
    const float* bih_b = (const float*)d_in[36];
    const float* bhh_b = (const float*)d_in[37];
    const float* clsw  = (const float*)d_in[38];
    const float* clsb  = (const float*)d_in[39];
    float* out = (float*)d_out;
    float* ws  = (float*)d_ws;

    // ---- workspace sizing ----
    const size_t FIXEDF = 5543872;
    const size_t PCS = 2422720;
    const size_t PCF = (PCS + 1)/2;
    int NC = 0;
    const int cands[6] = {32,16,8,4,2,1};
    for (int i = 0; i < 6; ++i) {
        if ((FIXEDF + (size_t)cands[i]*PCF + 64)*sizeof(float) <= ws_size) { NC = cands[i]; break; }
    }
    if (!NC) return;

    float* p = ws;
    unsigned short* WTR = (unsigned short*)p; p += 962560;
    float* P   = p; p += 508896;
    float* XM  = p; p += 508896;
    unsigned short* XP4 = (unsigned short*)p; p += 253952;
    float* FE  = p; p += 507904;
    unsigned short* WF = (unsigned short*)p; p += 262144;
    float* XPT = p; p += 2031616;
    float* HC  = p; p += 507904;
    unsigned short* q = (unsigned short*)p;
    unsigned short* A1  = q; q += (size_t)NC*1087680;
    unsigned short* C1p = q; q += (size_t)NC*274560;
    unsigned short* A2  = q; q += (size_t)NC*549120;
    unsigned short* C2p = q; q += (size_t)NC*143616;
    unsigned short* A3  = q; q += (size_t)NC*215424;
    unsigned short* XP3 = q; q += (size_t)NC*65280;
    unsigned short* A4  = q; q += (size_t)NC*87040;

    unsigned short* w2T  = WTR + 0;
    unsigned short* r1AT = WTR + 36864;
    unsigned short* r1BT = WTR + 110592;
    unsigned short* r1ST = WTR + 258048;
    unsigned short* r2AT = WTR + 266240;
    unsigned short* r2BT = WTR + 487424;
    unsigned short* r2ST = WTR + 819200;
    unsigned short* r3AT = WTR + 843776;
    unsigned short* r3BT = WTR + 1286144;
    unsigned short* r3ST = WTR + 1875968;

    auto cdiv = [](int a, int b){ return (a + b - 1) / b; };

    // ---- weight transforms ----
    wtrans9_kernel<<<cdiv(9*64*64,256),   256, 0, stream>>>(cbw2, w2T, 64, 64);
    wtrans9_kernel<<<cdiv(9*128*64,256),  256, 0, stream>>>(r1wA, r1AT, 128, 64);
    wtrans9_kernel<<<cdiv(9*128*128,256), 256, 0, stream>>>(r1wB, r1BT, 128, 128);
    wtrans1_kernel<<<cdiv(128*64,256),    256, 0, stream>>>(r1s, r1ST, 128*64);
    wtrans9_kernel<<<cdiv(9*192*128,256), 256, 0, stream>>>(r2wA, r2AT, 192, 128);
    wtrans9_kernel<<<cdiv(9*192*192,256), 256, 0, stream>>>(r2wB, r2BT, 192, 192);
    wtrans1_kernel<<<cdiv(192*128,256),   256, 0, stream>>>(r2s, r2ST, 192*128);
    wtrans9_kernel<<<cdiv(9*256*192,256), 256, 0, stream>>>(r3wA, r3AT, 256, 192);
    wtrans9_kernel<<<cdiv(9*256*256,256), 256, 0, stream>>>(r3wB, r3BT, 256, 256);
    wtrans1_kernel<<<cdiv(256*192,256),   256, 0, stream>>>(r3s, r3ST, 256*192);
    whh_frag_kernel<<<1024, 256, 0, stream>>>(whh_f, WF);
    whh_frag_kernel<<<1024, 256, 0, stream>>>(whh_b, WF + 262144);

    // ---- frontend mask ----
    mask_partial_kernel<<<dim3(63, 32), 256, 0, stream>>>(fW, fB, P);
    mask_finalize_apply<<<63, 256, 0, stream>>>(P, x, XM);

    // ---- zero padded staging region (all halos stay zero) ----
    hipMemsetAsync(A1, 0, (size_t)NC*PCS*sizeof(unsigned short), stream);

    // ---- conv stack, chunked over batch ----
    for (int c0 = 0; c0 < 32; c0 += NC) {
        const float* xmc = XM + (size_t)c0*15903;
        conv1_kernel<<<dim3(63, 1, NC), 256, 0, stream>>>(xmc, cbw1, cbg, cbb, A1);
        // conv2 + bn+lrelu+pool4: 64ch, 513->128 -> C1p [33][130][64]
        conv_lds_kernel<64,8,0,1><<<dim3(4*31, 1, NC), 256, 0, stream>>>(
            A1, w2T, nullptr, nullptr, C1p, 515, 4, 0, 33, 1, 130, 1, 64, r1pg, r1pb);
        // r1A: 64->128 -> A2 [33][130][128]
        conv_lds_kernel<64,8,0,0><<<dim3(31, 2, NC), 256, 0, stream>>>(
            C1p, r1AT, nullptr, nullptr, A2, 130, 1, 0, 33, 1, 130, 1, 128, r1g, r1b);
        // r1B + shortcut + pool4: 128ch, 128->32 -> C2p [33][34][128]
        conv_lds_kernel<128,8,64,1><<<dim3(31, 2, NC), 256, 0, stream>>>(
            A2, r1BT, C1p, r1ST, C2p, 130, 1, 130, 33, 1, 34, 1, 128, r2pg, r2pb);
        // r2A: 128->192 -> A3 [33][34][192]
        conv_lds_kernel<128,2,0,0><<<dim3(31, 3, NC), 256, 0, stream>>>(
            C2p, r2AT, nullptr, nullptr, A3, 34, 1, 0, 33, 1, 34, 1, 192, r2g, r2b);
        // r2B + shortcut + pool4: 192ch, 32->8 -> XP3 [34][10][192] padded
        conv_lds_kernel<192,2,128,1><<<dim3(31, 3, NC), 256, 0, stream>>>(
            A3, r2BT, C2p, r2ST, XP3, 34, 1, 34, 34, 1, 10, 1, 192, r3pg, r3pb);
        // r3A: 192->256 -> A4 [34][10][256] padded
        conv_w8_kernel<192,0,0><<<dim3(16, 2, NC), 256, 0, stream>>>(
            XP3, r3AT, nullptr, nullptr, A4, 256, r3g, r3b);
        // r3B + shortcut + bn+lrelu+pool(8->2) -> XP4 slice directly
        conv_w8_kernel<256,192,1><<<dim3(16, 2, NC), 256, 0, stream>>>(
            A4, r3BT, XP3, r3ST, XP4 + (size_t)c0*15872, 256, pbg, pbb);
    }

    // feats (32,31,512) fp32
    feats_kernel<<<1984, 256, 0, stream>>>(XP4, FE);

    // LSTM input projections -> xpT [d][t][b][j]
    gemm_bias_kernel<1><<<dim3(31, 16), 256, 0, stream>>>(FE, wih_f, bih_f, bhh_f, XPT,           992, 1024, 512);
    gemm_bias_kernel<1><<<dim3(31, 16), 256, 0, stream>>>(FE, wih_b, bih_b, bhh_b, XPT + 1015808, 992, 1024, 512);

    // fused bidirectional scan (4 blocks: dir x batch-half)
    lstm_scan_mfma<<<4, 1024, 0, stream>>>(XPT, WF, HC);

    // classifier -> d_out (32,31,722)
    gemm_bias_kernel<0><<<dim3(31, 12), 256, 0, stream>>>(HC, clsw, clsb, nullptr, out, 992, 722, 512);
}

// Round 17
// 1142.953 us; speedup vs baseline: 1.5774x; 1.1975x over previous
//
#include <hip/hip_runtime.h>
#include <hip/hip_bf16.h>
#include <math.h>

#define RSQ 0.99999500003749969f   // 1/sqrt(1+1e-5)
#define SLOPE 0.01f

typedef __attribute__((ext_vector_type(8))) short short8;
typedef __attribute__((ext_vector_type(4))) float f32x4;

__device__ __forceinline__ float sigmoidf_(float x){ return 1.0f/(1.0f+expf(-x)); }

__device__ __forceinline__ unsigned short f2bf(float f){
    unsigned u = __float_as_uint(f);
    u += 0x7fff + ((u >> 16) & 1);      // RNE
    return (unsigned short)(u >> 16);
}
__device__ __forceinline__ float bf2f(unsigned short s){
    return __uint_as_float(((unsigned)s) << 16);
}

// async global->LDS, 16B per lane; LDS dest is wave-uniform base + lane*16
__device__ __forceinline__ void stage16(const unsigned short* g, unsigned short* l) {
    __builtin_amdgcn_global_load_lds(
        (const __attribute__((address_space(1))) unsigned int*)g,
        (__attribute__((address_space(3))) unsigned int*)l, 16, 0, 0);
}

// ---------------- mask: prod_k cos(fW*rng + fB) ----------------
__global__ void mask_partial_kernel(const float* __restrict__ fW, const float* __restrict__ fB,
                                    float* __restrict__ partial)
{
    int p = blockIdx.x*256 + threadIdx.x;   // 0..15902
    if (p >= 15903) return;
    int w = p % 513;
    float r = (float)(w + 1);
    int k0 = blockIdx.y * 32;
    float prod = 1.0f;
    for (int k = k0; k < k0 + 32; ++k) {
        float a = fW[(size_t)k*15903 + p] * r + fB[(size_t)k*15903 + p];
        prod *= cosf(a);
    }
    partial[blockIdx.y*15903 + p] = prod;
}

__global__ void mask_finalize_apply(const float* __restrict__ partial, const float* __restrict__ x,
                                    float* __restrict__ xm)
{
    int p = blockIdx.x*256 + threadIdx.x;
    if (p >= 15903) return;
    float m = 1.0f;
    #pragma unroll
    for (int c = 0; c < 32; ++c) m *= partial[c*15903 + p];
    for (int n = 0; n < 32; ++n)
        xm[(size_t)n*15903 + p] = x[(size_t)n*15903 + p] * m;
}

// ---------------- weight transforms ----------------
__global__ void wtrans9_kernel(const float* __restrict__ w, unsigned short* __restrict__ o,
                               int Cout, int Cin)
{
    int idx = blockIdx.x*256 + threadIdx.x;
    int cc = Cout*Cin;
    if (idx >= 9*cc) return;
    int tap = idx / cc;
    int r = idx - tap*cc;
    int co = r / Cin, ci = r - co*Cin;
    int kh = tap/3, kw = tap - kh*3;
    o[idx] = f2bf(w[((size_t)(co*Cin + ci)*3 + kh)*3 + kw]);
}
__global__ void wtrans1_kernel(const float* __restrict__ w, unsigned short* __restrict__ o, int total)
{
    int idx = blockIdx.x*256 + threadIdx.x;
    if (idx < total) o[idx] = f2bf(w[idx]);
}

// whh (1024,256) fp32 -> MFMA-fragment-contiguous bf16
__global__ void whh_frag_kernel(const float* __restrict__ whh, unsigned short* __restrict__ out)
{
    int tid = blockIdx.x*256 + threadIdx.x;  // 262144 exact
    int e    = tid & 7;
    int lane = (tid >> 3) & 63;
    int kc   = (tid >> 9) & 7;
    int u0   = (tid >> 12) & 15;
    int g    = tid >> 16;
    int j = (g << 8) + (u0 << 4) + (lane & 15);
    int k = (kc << 5) + ((lane >> 4) << 3) + e;
    out[tid] = f2bf(whh[(size_t)j*256 + k]);
}

// ---------------- conv1: Cin=1 direct, fp32 in -> bf16 NHWC (rows 1..31 of [33][515][64]) ----------------
__launch_bounds__(256)
__global__ void conv1_kernel(const float* __restrict__ xm, const float* __restrict__ w1,
                             const float* __restrict__ g, const float* __restrict__ b,
                             unsigned short* __restrict__ O)
{
    __shared__ float wl[576];
    __shared__ float sg[64], sb[64];
    int tid = threadIdx.x;
    if (tid < 64) { sg[tid] = g[tid]*RSQ; sb[tid] = b[tid]; }
    for (int i = tid; i < 576; i += 256) wl[i] = w1[i];
    __syncthreads();
    int px = blockIdx.x*256 + tid;
    int n = blockIdx.z;
    if (px >= 15903) return;
    int h = px / 513, w = px - h*513;
    const float* xp = xm + (size_t)n*15903;
    float v[9];
    #pragma unroll
    for (int dh = 0; dh < 3; ++dh)
      #pragma unroll
      for (int dw = 0; dw < 3; ++dw) {
        int hh = h+dh-1, ww = w+dw-1;
        bool ok = ((unsigned)hh < 31u) && ((unsigned)ww < 513u);
        v[dh*3+dw] = ok ? xp[hh*513 + ww] : 0.f;
      }
    unsigned short* op = O + (((size_t)(n*33 + h + 1))*515 + (w + 1))*64;
    #pragma unroll
    for (int c8 = 0; c8 < 8; ++c8) {
        unsigned tmp[8];
        #pragma unroll
        for (int j = 0; j < 8; ++j) {
            int co = c8*8 + j;
            const float* wr = &wl[co*9];
            float a = 0.f;
            #pragma unroll
            for (int t2 = 0; t2 < 9; ++t2) a += wr[t2]*v[t2];
            a = a*sg[co] + sb[co];
            a = (a >= 0.f) ? a : SLOPE*a;
            tmp[j] = f2bf(a);
        }
        uint4 pk;
        pk.x = tmp[0] | (tmp[1]<<16);
        pk.y = tmp[2] | (tmp[3]<<16);
        pk.z = tmp[4] | (tmp[5]<<16);
        pk.w = tmp[6] | (tmp[7]<<16);
        *(uint4*)(op + c8*8) = pk;
    }
}

// ---------------- LDS-staged implicit-GEMM 3x3 conv (+1x1 shortcut) via MFMA ----------------
// Staging via global_load_lds: linear LDS dest (wave-uniform base + lane*16),
// pre-swizzled global SOURCE (u = v ^ (px(v)&7), valid since KQ,KQS >= 8 => XOR
// stays within kq bits and px(v)==px(u)). Read side keeps the same involution.
template<int CIN, int TPX, int CS, int POOL>
__launch_bounds__(256, 2)
__global__ void conv_lds_kernel(const unsigned short* __restrict__ X,
                                const unsigned short* __restrict__ W9,
                                const unsigned short* __restrict__ Xs,
                                const unsigned short* __restrict__ Ws,
                                unsigned short* __restrict__ O,
                                int Wp, int WT, int WpS,
                                int HO, int HOFF, int WpO, int OOFF, int Cout,
                                const float* __restrict__ g, const float* __restrict__ b)
{
    constexpr int KQ  = CIN/8;
    constexpr int PXT = TPX*16 + 2;
    constexpr int UX  = 3*PXT*KQ;
    constexpr int KQS = (CS > 0) ? CS/8 : 8;
    constexpr int US  = (CS > 0) ? TPX*16*KQS : 0;
    constexpr int UT  = UX + US;
    constexpr int NU  = (UT + 255)/256;
    constexpr int NKC = CIN/32;
    __shared__ uint4 lds4[UT + 8];

    const int tid = threadIdx.x;
    const int lane = tid & 63;
    const int wave = tid >> 6;
    const int cob  = blockIdx.y*64 + wave*16;
    const int n  = blockIdx.z;
    const int wt = blockIdx.x % WT;
    const int h  = blockIdx.x / WT;
    const int w0 = wt*(TPX*16);
    const int l15 = lane & 15;
    const int gq  = lane >> 4;

    // ---- stage: async global->LDS, source pre-swizzled ----
    #pragma unroll
    for (int i = 0; i < NU; ++i) {
        int v = tid + i*256;
        unsigned short* ldst = (unsigned short*)lds4 + (size_t)(i*256 + wave*64)*8;
        if (v < UX) {
            int r   = v / (PXT*KQ);
            int rem = v - r*(PXT*KQ);
            int px  = rem / KQ;
            int kq  = rem - px*KQ;
            int kqs = kq ^ (px & 7);
            stage16(X + (((size_t)(n*33 + h + r))*Wp + w0 + px)*CIN + kqs*8, ldst);
        } else if (CS > 0 && v < UT) {
            int us = v - UX;
            int px = us / KQS;
            int kq = us - px*KQS;
            int kqs = kq ^ (px & 7);
            stage16(Xs + (((size_t)(n*33 + h + 1))*WpS + w0 + 1 + px)*CS + kqs*8, ldst);
        }
    }
    __syncthreads();

    f32x4 acc[TPX] = {};
    #pragma unroll
    for (int dh = 0; dh < 3; ++dh) {
        short8 aw[3*NKC];
        #pragma unroll
        for (int dw = 0; dw < 3; ++dw)
            #pragma unroll
            for (int kc = 0; kc < NKC; ++kc)
                aw[dw*NKC + kc] = *(const short8*)(W9 +
                    ((size_t)((dh*3 + dw)*Cout + cob + l15))*CIN + kc*32 + gq*8);
        #pragma unroll
        for (int dw = 0; dw < 3; ++dw) {
            #pragma unroll
            for (int kc = 0; kc < NKC; ++kc) {
                short8 a = aw[dw*NKC + kc];
                #pragma unroll
                for (int t = 0; t < TPX; ++t) {
                    int px = dw + t*16 + l15;
                    int u  = (dh*PXT + px)*KQ + kc*4 + gq;
                    short8 bv = *(const short8*)((const char*)lds4 + ((u*16) ^ ((px & 7) << 4)));
                    acc[t] = __builtin_amdgcn_mfma_f32_16x16x32_bf16(a, bv, acc[t], 0, 0, 0);
                }
            }
        }
    }

    if (CS > 0) {
        #pragma unroll
        for (int kc = 0; kc < KQS/4; ++kc) {
            short8 a = *(const short8*)(Ws + (size_t)(cob + l15)*CS + kc*32 + gq*8);
            #pragma unroll
            for (int t = 0; t < TPX; ++t) {
                int px = t*16 + l15;
                int u  = UX + px*KQS + kc*4 + gq;
                short8 bv = *(const short8*)((const char*)lds4 + ((u*16) ^ ((px & 7) << 4)));
                acc[t] = __builtin_amdgcn_mfma_f32_16x16x32_bf16(a, bv, acc[t], 0, 0, 0);
            }
        }
    }

    int cb = cob + gq*4;
    float s0 = g[cb+0]*RSQ, s1 = g[cb+1]*RSQ, s2 = g[cb+2]*RSQ, s3 = g[cb+3]*RSQ;
    float o0 = b[cb+0], o1 = b[cb+1], o2 = b[cb+2], o3 = b[cb+3];
    #pragma unroll
    for (int t = 0; t < TPX; ++t) {
        float v0 = acc[t][0]*s0 + o0; v0 = (v0 >= 0.f) ? v0 : SLOPE*v0;
        float v1 = acc[t][1]*s1 + o1; v1 = (v1 >= 0.f) ? v1 : SLOPE*v1;
        float v2 = acc[t][2]*s2 + o2; v2 = (v2 >= 0.f) ? v2 : SLOPE*v2;
        float v3 = acc[t][3]*s3 + o3; v3 = (v3 >= 0.f) ? v3 : SLOPE*v3;
        if (POOL) {
            v0 = fmaxf(v0, __shfl_xor(v0, 1)); v0 = fmaxf(v0, __shfl_xor(v0, 2));
            v1 = fmaxf(v1, __shfl_xor(v1, 1)); v1 = fmaxf(v1, __shfl_xor(v1, 2));
            v2 = fmaxf(v2, __shfl_xor(v2, 1)); v2 = fmaxf(v2, __shfl_xor(v2, 2));
            v3 = fmaxf(v3, __shfl_xor(v3, 1)); v3 = fmaxf(v3, __shfl_xor(v3, 2));
            if ((l15 & 3) == 0) {
                int pw = (w0 + t*16 + l15) >> 2;
                uint2 pk;
                pk.x = (unsigned)f2bf(v0) | ((unsigned)f2bf(v1) << 16);
                pk.y = (unsigned)f2bf(v2) | ((unsigned)f2bf(v3) << 16);
                *(uint2*)(O + (((size_t)(n*HO + h + HOFF))*WpO + pw + OOFF)*Cout + cb) = pk;
            }
        } else {
            int w = w0 + t*16 + l15;
            uint2 pk;
            pk.x = (unsigned)f2bf(v0) | ((unsigned)f2bf(v1) << 16);
            pk.y = (unsigned)f2bf(v2) | ((unsigned)f2bf(v3) << 16);
            *(uint2*)(O + (((size_t)(n*HO + h + HOFF))*WpO + w + OOFF)*Cout + cb) = pk;
        }
    }
}

// ---------------- W=8 LDS-staged conv for r3 layers ----------------
template<int CIN, int CS, int POOL>
__launch_bounds__(256, 2)
__global__ void conv_w8_kernel(const unsigned short* __restrict__ X,
                               const unsigned short* __restrict__ W9,
                               const unsigned short* __restrict__ Xs,
                               const unsigned short* __restrict__ Ws,
                               unsigned short* __restrict__ O, int Cout,
                               const float* __restrict__ g, const float* __restrict__ b)
{
    constexpr int KQ  = CIN/8;
    constexpr int UX  = 4*10*KQ;
    constexpr int KQS = (CS > 0) ? CS/8 : 8;
    constexpr int US  = (CS > 0) ? 2*8*KQS : 0;
    constexpr int UT  = UX + US;
    constexpr int NU  = (UT + 255)/256;
    constexpr int NKC = CIN/32;
    __shared__ uint4 lds4[UT + 8];

    const int tid = threadIdx.x;
    const int lane = tid & 63;
    const int wave = tid >> 6;
    const int hp = blockIdx.x;          // 0..15
    const int n  = blockIdx.z;
    const int h0 = hp*2;
    const int l15 = lane & 15;
    const int gq  = lane >> 4;
    const int r = l15 >> 3;
    const int w = l15 & 7;
    const int cwb = blockIdx.y*128 + wave*32;

    // ---- stage: async global->LDS, source pre-swizzled ----
    #pragma unroll
    for (int i = 0; i < NU; ++i) {
        int v = tid + i*256;
        unsigned short* ldst = (unsigned short*)lds4 + (size_t)(i*256 + wave*64)*8;
        if (v < UX) {
            int row = v / (10*KQ);
            int rem = v - row*(10*KQ);
            int px  = rem / KQ;
            int kq  = rem - px*KQ;
            int kqs = kq ^ (px & 7);
            stage16(X + (((size_t)(n*34 + h0 + row))*10 + px)*CIN + kqs*8, ldst);
        } else if (CS > 0 && v < UT) {
            int us = v - UX;
            int rs = us / (8*KQS);
            int rem = us - rs*(8*KQS);
            int px8 = rem / KQS;
            int kq  = rem - px8*KQS;
            int kqs = kq ^ (px8 & 7);
            stage16(Xs + (((size_t)(n*34 + h0 + 1 + rs))*10 + px8 + 1)*CS + kqs*8, ldst);
        }
    }
    __syncthreads();

    f32x4 acc0 = {0,0,0,0}, acc1 = {0,0,0,0};
    #pragma unroll
    for (int dh = 0; dh < 3; ++dh) {
        #pragma unroll
        for (int dw = 0; dw < 3; ++dw) {
            short8 a0[NKC], a1[NKC];
            #pragma unroll
            for (int kc = 0; kc < NKC; ++kc) {
                a0[kc] = *(const short8*)(W9 + ((size_t)((dh*3+dw)*Cout + cwb + l15))*CIN + kc*32 + gq*8);
                a1[kc] = *(const short8*)(W9 + ((size_t)((dh*3+dw)*Cout + cwb + 16 + l15))*CIN + kc*32 + gq*8);
            }
            #pragma unroll
            for (int kc = 0; kc < NKC; ++kc) {
                int row_s = r + dh;
                int col = w + dw;
                int u = (row_s*10 + col)*KQ + kc*4 + gq;
                short8 bv = *(const short8*)((const char*)lds4 + ((u*16) ^ ((col & 7) << 4)));
                acc0 = __builtin_amdgcn_mfma_f32_16x16x32_bf16(a0[kc], bv, acc0, 0, 0, 0);
                acc1 = __builtin_amdgcn_mfma_f32_16x16x32_bf16(a1[kc], bv, acc1, 0, 0, 0);
            }
        }
    }

    if (CS > 0) {
        #pragma unroll
        for (int kc = 0; kc < KQS/4; ++kc) {
            short8 a0 = *(const short8*)(Ws + (size_t)(cwb + l15)*CS + kc*32 + gq*8);
            short8 a1 = *(const short8*)(Ws + (size_t)(cwb + 16 + l15)*CS + kc*32 + gq*8);
            int u = UX + (r*8 + w)*KQS + kc*4 + gq;
            short8 bv = *(const short8*)((const char*)lds4 + ((u*16) ^ ((w & 7) << 4)));
            acc0 = __builtin_amdgcn_mfma_f32_16x16x32_bf16(a0, bv, acc0, 0, 0, 0);
            acc1 = __builtin_amdgcn_mfma_f32_16x16x32_bf16(a1, bv, acc1, 0, 0, 0);
        }
    }

    const int hr = h0 + r;
    const bool valid = hr < 31;
#define EPIG8(ACC, G) do { \
    int cb = cwb + (G)*16 + gq*4; \
    float s0 = g[cb+0]*RSQ, s1 = g[cb+1]*RSQ, s2 = g[cb+2]*RSQ, s3 = g[cb+3]*RSQ; \
    float o0 = b[cb+0], o1 = b[cb+1], o2 = b[cb+2], o3 = b[cb+3]; \
    float v0 = ACC[0]*s0 + o0; v0 = (v0 >= 0.f) ? v0 : SLOPE*v0; \
    float v1 = ACC[1]*s1 + o1; v1 = (v1 >= 0.f) ? v1 : SLOPE*v1; \
    float v2 = ACC[2]*s2 + o2; v2 = (v2 >= 0.f) ? v2 : SLOPE*v2; \
    float v3 = ACC[3]*s3 + o3; v3 = (v3 >= 0.f) ? v3 : SLOPE*v3; \
    if (POOL) { \
        v0 = fmaxf(v0, __shfl_xor(v0, 1)); v0 = fmaxf(v0, __shfl_xor(v0, 2)); \
        v1 = fmaxf(v1, __shfl_xor(v1, 1)); v1 = fmaxf(v1, __shfl_xor(v1, 2)); \
        v2 = fmaxf(v2, __shfl_xor(v2, 1)); v2 = fmaxf(v2, __shfl_xor(v2, 2)); \
        v3 = fmaxf(v3, __shfl_xor(v3, 1)); v3 = fmaxf(v3, __shfl_xor(v3, 2)); \
        if (((l15 & 3) == 0) && valid) { \
            uint2 pk; \
            pk.x = (unsigned)f2bf(v0) | ((unsigned)f2bf(v1) << 16); \
            pk.y = (unsigned)f2bf(v2) | ((unsigned)f2bf(v3) << 16); \
            *(uint2*)(O + (((size_t)(n*31 + hr))*2 + (w >> 2))*Cout + cb) = pk; \
        } \
    } else if (valid) { \
        uint2 pk; \
        pk.x = (unsigned)f2bf(v0) | ((unsigned)f2bf(v1) << 16); \
        pk.y = (unsigned)f2bf(v2) | ((unsigned)f2bf(v3) << 16); \
        *(uint2*)(O + (((size_t)(n*34 + hr + 1))*10 + w + 1)*Cout + cb) = pk; \
    } \
} while(0)
    EPIG8(acc0, 0);
    EPIG8(acc1, 1);
#undef EPIG8
}

// ---------------- feats: [n][31][2][256] bf16 NHWC -> [n][31][512] fp32 ----------------
__global__ void feats_kernel(const unsigned short* __restrict__ p4, float* __restrict__ fe)
{
    int idx = blockIdx.x*256 + threadIdx.x;   // 507904
    int cw = idx & 511;
    int nh = idx >> 9;
    int c = cw >> 1, w = cw & 1;
    fe[idx] = bf2f(p4[((size_t)nh*2 + w)*256 + c]);
}

// ---------------- tiled SGEMM: C[M,N] = A[M,K] @ B[N,K]^T + bias(+bias2) ----------------
#define GM 32
#define GN 64
#define GK 32
template<int XPOSE>
__launch_bounds__(256)
__global__ void gemm_bias_kernel(const float* __restrict__ A, const float* __restrict__ B,
                                 const float* __restrict__ bias, const float* __restrict__ bias2,
                                 float* __restrict__ C, int M, int N, int K)
{
    __shared__ float As[GM][GK+1];
    __shared__ float Bs[GN][GK+1];
    int m0 = blockIdx.x*GM, n0 = blockIdx.y*GN;
    int tid = threadIdx.x;
    int mi = tid >> 4;
    int ni = (tid & 15) * 4;
    float acc[2][4] = {};

    for (int k0 = 0; k0 < K; k0 += GK) {
        for (int i = tid; i < GM*GK; i += 256) {
            int r = i >> 5, c = i & 31;
            int m = m0 + r;
            As[r][c] = (m < M) ? A[(size_t)m*K + k0 + c] : 0.f;
        }
        for (int i = tid; i < GN*GK; i += 256) {
            int r = i >> 5, c = i & 31;
            int n = n0 + r;
            Bs[r][c] = (n < N) ? B[(size_t)n*K + k0 + c] : 0.f;
        }
        __syncthreads();
        #pragma unroll
        for (int kk = 0; kk < GK; ++kk) {
            float a0 = As[mi][kk], a1 = As[mi+16][kk];
            float b0 = Bs[ni][kk], b1 = Bs[ni+1][kk], b2 = Bs[ni+2][kk], b3 = Bs[ni+3][kk];
            acc[0][0] += a0*b0; acc[0][1] += a0*b1; acc[0][2] += a0*b2; acc[0][3] += a0*b3;
            acc[1][0] += a1*b0; acc[1][1] += a1*b1; acc[1][2] += a1*b2; acc[1][3] += a1*b3;
        }
        __syncthreads();
    }
    #pragma unroll
    for (int r = 0; r < 2; ++r) {
        int m = m0 + mi + r*16;
        if (m >= M) continue;
        #pragma unroll
        for (int q = 0; q < 4; ++q) {
            int n = n0 + ni + q;
            if (n >= N) continue;
            float v = acc[r][q];
            if (bias)  v += bias[n];
            if (bias2) v += bias2[n];
            if (XPOSE) C[((size_t)(m % 31)*32 + (m / 31))*N + n] = v;
            else       C[(size_t)m*N + n] = v;
        }
    }
}

// ---------------- LSTM scan via MFMA: 4 blocks = (dir x batch-half), 1024 thr ----------------
__launch_bounds__(1024)
__global__ void lstm_scan_mfma(const float* __restrict__ xpT,
                               const unsigned short* __restrict__ wf,
                               float* __restrict__ hcat)
{
    const int d  = blockIdx.x >> 1;
    const int bh = blockIdx.x & 1;
    const int tid = threadIdx.x;
    const int u0 = tid >> 6;
    const int lane = tid & 63;
    const int l15 = lane & 15;
    const int q = lane >> 4;

    __shared__ unsigned short hbuf[2][4096];          // 16 KB
    __shared__ unsigned short wst[16][2][2048];       // 128 KB

    ((int4*)hbuf)[tid & 1023] = make_int4(0,0,0,0);

    const unsigned short* wfd = wf + (size_t)d*262144;
    const float* xpd = xpT + (size_t)d*992*1024 + (size_t)bh*16*1024;
    const unsigned short* wsrc = wfd + (size_t)u0*4096 + (size_t)lane*8;
    unsigned short* wl = &wst[u0][0][0];

#define STAGE(KC, PB) do { \
    unsigned short* dst_ = wl + (PB)*2048; \
    stage16(wsrc + 0*65536 + (KC)*512, dst_ + 0*512); \
    stage16(wsrc + 1*65536 + (KC)*512, dst_ + 1*512); \
    stage16(wsrc + 2*65536 + (KC)*512, dst_ + 2*512); \
    stage16(wsrc + 3*65536 + (KC)*512, dst_ + 3*512); \
} while(0)

    float c0=0.f, c1=0.f, c2=0.f, c3=0.f;
    const int ubase = u0*16 + q*4;
    const int rb = l15*512 + q*16;
    const int xr = (l15&7)<<4;

    STAGE(0, 0);
    float4 xi, xf, xg, xo;
    {
        const int t0 = d ? 30 : 0;
        const float* xb = xpd + (size_t)t0*32768 + (size_t)l15*1024;
        xi = *(const float4*)(xb + ubase);
        xf = *(const float4*)(xb + 256 + ubase);
        xg = *(const float4*)(xb + 512 + ubase);
        xo = *(const float4*)(xb + 768 + ubase);
    }
    asm volatile("s_waitcnt lgkmcnt(0)" ::: "memory");
    __builtin_amdgcn_s_barrier();

#define HRD(kc)   (*(const short8*)(hb + ((rb + (kc)*64) ^ xr)))
#define MF(w_,h_,a_) a_ = __builtin_amdgcn_mfma_f32_16x16x32_bf16(w_, h_, a_, 0, 0, 0)

    for (int s = 0; s < 31; ++s) {
        const int t = d ? (30 - s) : s;
        const int cur = s & 1, nxt = cur ^ 1;

        const char* hb = (const char*)hbuf[cur];
        f32x4 a0={0,0,0,0}, a1={0,0,0,0}, a2={0,0,0,0}, a3={0,0,0,0};

        #pragma unroll
        for (int kc = 0; kc < 8; ++kc) {
            if (kc < 7) STAGE(kc+1, (kc+1)&1);
            else        STAGE(0, 0);
            if (kc == 0) asm volatile("s_waitcnt vmcnt(8)" ::: "memory");
            else         asm volatile("s_waitcnt vmcnt(4)" ::: "memory");
            const unsigned short* wb = wl + (kc&1)*2048;
            short8 w0 = *(const short8*)(wb + 0*512 + lane*8);
            short8 w1 = *(const short8*)(wb + 1*512 + lane*8);
            short8 w2 = *(const short8*)(wb + 2*512 + lane*8);
            short8 w3 = *(const short8*)(wb + 3*512 + lane*8);
            short8 h = HRD(kc);
            MF(w0,h,a0); MF(w1,h,a1); MF(w2,h,a2); MF(w3,h,a3);
        }

        float4 nxi, nxf, nxg, nxo;
        {
            int s2 = (s < 30) ? s + 1 : s;
            int t2 = d ? (30 - s2) : s2;
            const float* xb = xpd + (size_t)t2*32768 + (size_t)l15*1024;
            nxi = *(const float4*)(xb + ubase);
            nxf = *(const float4*)(xb + 256 + ubase);
            nxg = *(const float4*)(xb + 512 + ubase);
            nxo = *(const float4*)(xb + 768 + ubase);
        }

        float hv0, hv1, hv2, hv3;
        { float gi=a0[0]+xi.x, gf=a1[0]+xf.x, gg=a2[0]+xg.x, go=a3[0]+xo.x;
          float cn = sigmoidf_(gf)*c0 + sigmoidf_(gi)*tanhf(gg); c0 = cn; hv0 = sigmoidf_(go)*tanhf(cn); }
        { float gi=a0[1]+xi.y, gf=a1[1]+xf.y, gg=a2[1]+xg.y, go=a3[1]+xo.y;
          float cn = sigmoidf_(gf)*c1 + sigmoidf_(gi)*tanhf(gg); c1 = cn; hv1 = sigmoidf_(go)*tanhf(cn); }
        { float gi=a0[2]+xi.z, gf=a1[2]+xf.z, gg=a2[2]+xg.z, go=a3[2]+xo.z;
          float cn = sigmoidf_(gf)*c2 + sigmoidf_(gi)*tanhf(gg); c2 = cn; hv2 = sigmoidf_(go)*tanhf(cn); }
        { float gi=a0[3]+xi.w, gf=a1[3]+xf.w, gg=a2[3]+xg.w, go=a3[3]+xo.w;
          float cn = sigmoidf_(gf)*c3 + sigmoidf_(gi)*tanhf(gg); c3 = cn; hv3 = sigmoidf_(go)*tanhf(cn); }

        short4 hp;
        hp.x = (short)f2bf(hv0); hp.y = (short)f2bf(hv1);
        hp.z = (short)f2bf(hv2); hp.w = (short)f2bf(hv3);
        *(short4*)((char*)hbuf[nxt] + ((l15*512 + ubase*2) ^ xr)) = hp;
        int bg = bh*16 + l15;
        *(float4*)(&hcat[((size_t)bg*31 + t)*512 + (size_t)d*256 + ubase]) =
            make_float4(hv0, hv1, hv2, hv3);

        asm volatile("s_waitcnt lgkmcnt(0)" ::: "memory");
        __builtin_amdgcn_s_barrier();

        xi = nxi; xf = nxf; xg = nxg; xo = nxo;
    }
#undef STAGE
#undef HRD
#undef MF
}

extern "C" void kernel_launch(void* const* d_in, const int* in_sizes, int n_in,
                              void* d_out, int out_size, void* d_ws, size_t ws_size,
                              hipStream_t stream)
{
    const float* x    = (const float*)d_in[0];
    const float* fW   = (const float*)d_in[1];
    const float* fB   = (const float*)d_in[2];
    const float* cbw1 = (const float*)d_in[3];
    const float* cbg  = (const float*)d_in[4];
    const float* cbb  = (const float*)d_in[5];
    const float* cbw2 = (const float*)d_in[6];
    const float* r1pg = (const float*)d_in[7];
    const float* r1pb = (const float*)d_in[8];
    const float* r1wA = (const float*)d_in[9];
    const float* r1g  = (const float*)d_in[10];
    const float* r1b  = (const float*)d_in[11];
    const float* r1wB = (const float*)d_in[12];
    const float* r1s  = (const float*)d_in[13];
    const float* r2pg = (const float*)d_in[14];
    const float* r2pb = (const float*)d_in[15];
    const float* r2wA = (const float*)d_in[16];
    const float* r2g  = (const float*)d_in[17];
    const float* r2b  = (const float*)d_in[18];
    const float* r2wB = (const float*)d_in[19];
    const float* r2s  = (const float*)d_in[20];
    const float* r3pg = (const float*)d_in[21];
    const float* r3pb = (const float*)d_in[22];
    const float* r3wA = (const float*)d_in[23];
    const float* r3g  = (const float*)d_in[24];
    const float* r3b  = (const float*)d_in[25];
    const float* r3wB = (const float*)d_in[26];
    const float* r3s  = (const float*)d_in[27];
    const float* pbg  = (const float*)d_in[28];
    const float* pbb  = (const float*)d_in[29];
    const float* wih_f = (const float*)d_in[30];
    const float* whh_f = (const float*)d_in[31];
    const float* bih_f = (const float*)d_in[32];
    const float* bhh_f = (const float*)d_in[33];
    const float* wih_b = (const float*)d_in[34];
    const float* whh_b = (const float*)d_in[35];
    const float* bih_b = (const float*)d_in[36];
    const float* bhh_b = (const float*)d_in[37];
    const float* clsw  = (const float*)d_in[38];
    const float* clsb  = (const float*)d_in[39];
    float* out = (float*)d_out;
    float* ws  = (float*)d_ws;

    // ---- workspace sizing ----
    const size_t FIXEDF = 5543872;
    const size_t PCS = 2422720;
    const size_t PCF = (PCS + 1)/2;
    int NC = 0;
    const int cands[6] = {32,16,8,4,2,1};
    for (int i = 0; i < 6; ++i) {
        if ((FIXEDF + (size_t)cands[i]*PCF + 64)*sizeof(float) <= ws_size) { NC = cands[i]; break; }
    }
    if (!NC) return;

    float* p = ws;
    unsigned short* WTR = (unsigned short*)p; p += 962560;
    float* P   = p; p += 508896;
    float* XM  = p; p += 508896;
    unsigned short* XP4 = (unsigned short*)p; p += 253952;
    float* FE  = p; p += 507904;
    unsigned short* WF = (unsigned short*)p; p += 262144;
    float* XPT = p; p += 2031616;
    float* HC  = p; p += 507904;
    unsigned short* q = (unsigned short*)p;
    unsigned short* A1  = q; q += (size_t)NC*1087680;
    unsigned short* C1p = q; q += (size_t)NC*274560;
    unsigned short* A2  = q; q += (size_t)NC*549120;
    unsigned short* C2p = q; q += (size_t)NC*143616;
    unsigned short* A3  = q; q += (size_t)NC*215424;
    unsigned short* XP3 = q; q += (size_t)NC*65280;
    unsigned short* A4  = q; q += (size_t)NC*87040;

    unsigned short* w2T  = WTR + 0;
    unsigned short* r1AT = WTR + 36864;
    unsigned short* r1BT = WTR + 110592;
    unsigned short* r1ST = WTR + 258048;
    unsigned short* r2AT = WTR + 266240;
    unsigned short* r2BT = WTR + 487424;
    unsigned short* r2ST = WTR + 819200;
    unsigned short* r3AT = WTR + 843776;
    unsigned short* r3BT = WTR + 1286144;
    unsigned short* r3ST = WTR + 1875968;

    auto cdiv = [](int a, int b){ return (a + b - 1) / b; };

    // ---- weight transforms ----
    wtrans9_kernel<<<cdiv(9*64*64,256),   256, 0, stream>>>(cbw2, w2T, 64, 64);
    wtrans9_kernel<<<cdiv(9*128*64,256),  256, 0, stream>>>(r1wA, r1AT, 128, 64);
    wtrans9_kernel<<<cdiv(9*128*128,256), 256, 0, stream>>>(r1wB, r1BT, 128, 128);
    wtrans1_kernel<<<cdiv(128*64,256),    256, 0, stream>>>(r1s, r1ST, 128*64);
    wtrans9_kernel<<<cdiv(9*192*128,256), 256, 0, stream>>>(r2wA, r2AT, 192, 128);
    wtrans9_kernel<<<cdiv(9*192*192,256), 256, 0, stream>>>(r2wB, r2BT, 192, 192);
    wtrans1_kernel<<<cdiv(192*128,256),   256, 0, stream>>>(r2s, r2ST, 192*128);
    wtrans9_kernel<<<cdiv(9*256*192,256), 256, 0, stream>>>(r3wA, r3AT, 256, 192);
    wtrans9_kernel<<<cdiv(9*256*256,256), 256, 0, stream>>>(r3wB, r3BT, 256, 256);
    wtrans1_kernel<<<cdiv(256*192,256),   256, 0, stream>>>(r3s, r3ST, 256*192);
    whh_frag_kernel<<<1024, 256, 0, stream>>>(whh_f, WF);
    whh_frag_kernel<<<1024, 256, 0, stream>>>(whh_b, WF + 262144);

    // ---- frontend mask ----
    mask_partial_kernel<<<dim3(63, 32), 256, 0, stream>>>(fW, fB, P);
    mask_finalize_apply<<<63, 256, 0, stream>>>(P, x, XM);

    // ---- zero padded staging region (all halos stay zero) ----
    hipMemsetAsync(A1, 0, (size_t)NC*PCS*sizeof(unsigned short), stream);

    // ---- conv stack, chunked over batch ----
    for (int c0 = 0; c0 < 32; c0 += NC) {
        const float* xmc = XM + (size_t)c0*15903;
        conv1_kernel<<<dim3(63, 1, NC), 256, 0, stream>>>(xmc, cbw1, cbg, cbb, A1);
        // conv2 + bn+lrelu+pool4: 64ch, 513->128 -> C1p [33][130][64]
        conv_lds_kernel<64,8,0,1><<<dim3(4*31, 1, NC), 256, 0, stream>>>(
            A1, w2T, nullptr, nullptr, C1p, 515, 4, 0, 33, 1, 130, 1, 64, r1pg, r1pb);
        // r1A: 64->128 -> A2 [33][130][128]
        conv_lds_kernel<64,8,0,0><<<dim3(31, 2, NC), 256, 0, stream>>>(
            C1p, r1AT, nullptr, nullptr, A2, 130, 1, 0, 33, 1, 130, 1, 128, r1g, r1b);
        // r1B + shortcut + pool4: 128ch, 128->32 -> C2p [33][34][128]
        conv_lds_kernel<128,8,64,1><<<dim3(31, 2, NC), 256, 0, stream>>>(
            A2, r1BT, C1p, r1ST, C2p, 130, 1, 130, 33, 1, 34, 1, 128, r2pg, r2pb);
        // r2A: 128->192 -> A3 [33][34][192]
        conv_lds_kernel<128,2,0,0><<<dim3(31, 3, NC), 256, 0, stream>>>(
            C2p, r2AT, nullptr, nullptr, A3, 34, 1, 0, 33, 1, 34, 1, 192, r2g, r2b);
        // r2B + shortcut + pool4: 192ch, 32->8 -> XP3 [34][10][192] padded
        conv_lds_kernel<192,2,128,1><<<dim3(31, 3, NC), 256, 0, stream>>>(
            A3, r2BT, C2p, r2ST, XP3, 34, 1, 34, 34, 1, 10, 1, 192, r3pg, r3pb);
        // r3A: 192->256 -> A4 [34][10][256] padded
        conv_w8_kernel<192,0,0><<<dim3(16, 2, NC), 256, 0, stream>>>(
            XP3, r3AT, nullptr, nullptr, A4, 256, r3g, r3b);
        // r3B + shortcut + bn+lrelu+pool(8->2) -> XP4 slice directly
        conv_w8_kernel<256,192,1><<<dim3(16, 2, NC), 256, 0, stream>>>(
            A4, r3BT, XP3, r3ST, XP4 + (size_t)c0*15872, 256, pbg, pbb);
    }

    // feats (32,31,512) fp32
    feats_kernel<<<1984, 256, 0, stream>>>(XP4, FE);

    // LSTM input projections -> xpT [d][t][b][j]
    gemm_bias_kernel<1><<<dim3(31, 16), 256, 0, stream>>>(FE, wih_f, bih_f, bhh_f, XPT,           992, 1024, 512);
    gemm_bias_kernel<1><<<dim3(31, 16), 256, 0, stream>>>(FE, wih_b, bih_b, bhh_b, XPT + 1015808, 992, 1024, 512);

    // fused bidirectional scan (4 blocks: dir x batch-half)
    lstm_scan_mfma<<<4, 1024, 0, stream>>>(XPT, WF, HC);

    // classifier -> d_out (32,31,722)
    gemm_bias_kernel<0><<<dim3(31, 12), 256, 0, stream>>>(HC, clsw, clsb, nullptr, out, 992, 722, 512);
}

// Round 18
// 929.299 us; speedup vs baseline: 1.9400x; 1.2299x over previous
//
#include <hip/hip_runtime.h>
#include <hip/hip_bf16.h>
#include <math.h>

#define RSQ 0.99999500003749969f   // 1/sqrt(1+1e-5)
#define SLOPE 0.01f

typedef __attribute__((ext_vector_type(8))) short short8;
typedef __attribute__((ext_vector_type(4))) float f32x4;

__device__ __forceinline__ float sigmoidf_(float x){ return 1.0f/(1.0f+expf(-x)); }

__device__ __forceinline__ unsigned short f2bf(float f){
    unsigned u = __float_as_uint(f);
    u += 0x7fff + ((u >> 16) & 1);      // RNE
    return (unsigned short)(u >> 16);
}
__device__ __forceinline__ float bf2f(unsigned short s){
    return __uint_as_float(((unsigned)s) << 16);
}

// async global->LDS, 16B per lane; LDS dest is wave-uniform base + lane*16
__device__ __forceinline__ void stage16(const unsigned short* g, unsigned short* l) {
    __builtin_amdgcn_global_load_lds(
        (const __attribute__((address_space(1))) unsigned int*)g,
        (__attribute__((address_space(3))) unsigned int*)l, 16, 0, 0);
}

// ---------------- mask: prod_k cos(fW*rng + fB) ----------------
__global__ void mask_partial_kernel(const float* __restrict__ fW, const float* __restrict__ fB,
                                    float* __restrict__ partial)
{
    int p = blockIdx.x*256 + threadIdx.x;   // 0..15902
    if (p >= 15903) return;
    int w = p % 513;
    float r = (float)(w + 1);
    int k0 = blockIdx.y * 32;
    float prod = 1.0f;
    for (int k = k0; k < k0 + 32; ++k) {
        float a = fW[(size_t)k*15903 + p] * r + fB[(size_t)k*15903 + p];
        prod *= cosf(a);
    }
    partial[blockIdx.y*15903 + p] = prod;
}

__global__ void mask_finalize_apply(const float* __restrict__ partial, const float* __restrict__ x,
                                    float* __restrict__ xm)
{
    int p = blockIdx.x*256 + threadIdx.x;
    if (p >= 15903) return;
    float m = 1.0f;
    #pragma unroll
    for (int c = 0; c < 32; ++c) m *= partial[c*15903 + p];
    for (int n = 0; n < 32; ++n)
        xm[(size_t)n*15903 + p] = x[(size_t)n*15903 + p] * m;
}

// ---------------- weight transforms ----------------
__global__ void wtrans9_kernel(const float* __restrict__ w, unsigned short* __restrict__ o,
                               int Cout, int Cin)
{
    int idx = blockIdx.x*256 + threadIdx.x;
    int cc = Cout*Cin;
    if (idx >= 9*cc) return;
    int tap = idx / cc;
    int r = idx - tap*cc;
    int co = r / Cin, ci = r - co*Cin;
    int kh = tap/3, kw = tap - kh*3;
    o[idx] = f2bf(w[((size_t)(co*Cin + ci)*3 + kh)*3 + kw]);
}
__global__ void wtrans1_kernel(const float* __restrict__ w, unsigned short* __restrict__ o, int total)
{
    int idx = blockIdx.x*256 + threadIdx.x;
    if (idx < total) o[idx] = f2bf(w[idx]);
}

// whh (1024,256) fp32 -> MFMA-fragment-contiguous bf16
__global__ void whh_frag_kernel(const float* __restrict__ whh, unsigned short* __restrict__ out)
{
    int tid = blockIdx.x*256 + threadIdx.x;  // 262144 exact
    int e    = tid & 7;
    int lane = (tid >> 3) & 63;
    int kc   = (tid >> 9) & 7;
    int u0   = (tid >> 12) & 15;
    int g    = tid >> 16;
    int j = (g << 8) + (u0 << 4) + (lane & 15);
    int k = (kc << 5) + ((lane >> 4) << 3) + e;
    out[tid] = f2bf(whh[(size_t)j*256 + k]);
}

// ---------------- conv1: Cin=1 direct, fp32 in -> bf16 NHWC (rows 1..31 of [33][515][64]) ----------------
__launch_bounds__(256)
__global__ void conv1_kernel(const float* __restrict__ xm, const float* __restrict__ w1,
                             const float* __restrict__ g, const float* __restrict__ b,
                             unsigned short* __restrict__ O)
{
    __shared__ float wl[576];
    __shared__ float sg[64], sb[64];
    int tid = threadIdx.x;
    if (tid < 64) { sg[tid] = g[tid]*RSQ; sb[tid] = b[tid]; }
    for (int i = tid; i < 576; i += 256) wl[i] = w1[i];
    __syncthreads();
    int px = blockIdx.x*256 + tid;
    int n = blockIdx.z;
    if (px >= 15903) return;
    int h = px / 513, w = px - h*513;
    const float* xp = xm + (size_t)n*15903;
    float v[9];
    #pragma unroll
    for (int dh = 0; dh < 3; ++dh)
      #pragma unroll
      for (int dw = 0; dw < 3; ++dw) {
        int hh = h+dh-1, ww = w+dw-1;
        bool ok = ((unsigned)hh < 31u) && ((unsigned)ww < 513u);
        v[dh*3+dw] = ok ? xp[hh*513 + ww] : 0.f;
      }
    unsigned short* op = O + (((size_t)(n*33 + h + 1))*515 + (w + 1))*64;
    #pragma unroll
    for (int c8 = 0; c8 < 8; ++c8) {
        unsigned tmp[8];
        #pragma unroll
        for (int j = 0; j < 8; ++j) {
            int co = c8*8 + j;
            const float* wr = &wl[co*9];
            float a = 0.f;
            #pragma unroll
            for (int t2 = 0; t2 < 9; ++t2) a += wr[t2]*v[t2];
            a = a*sg[co] + sb[co];
            a = (a >= 0.f) ? a : SLOPE*a;
            tmp[j] = f2bf(a);
        }
        uint4 pk;
        pk.x = tmp[0] | (tmp[1]<<16);
        pk.y = tmp[2] | (tmp[3]<<16);
        pk.z = tmp[4] | (tmp[5]<<16);
        pk.w = tmp[6] | (tmp[7]<<16);
        *(uint4*)(op + c8*8) = pk;
    }
}

// ---------------- LDS-staged implicit-GEMM 3x3 conv (+1x1 shortcut) via MFMA ----------------
template<int CIN, int TPX, int CS, int POOL>
__launch_bounds__(256, 2)
__global__ void conv_lds_kernel(const unsigned short* __restrict__ X,
                                const unsigned short* __restrict__ W9,
                                const unsigned short* __restrict__ Xs,
                                const unsigned short* __restrict__ Ws,
                                unsigned short* __restrict__ O,
                                int Wp, int WT, int WpS,
                                int HO, int HOFF, int WpO, int OOFF, int Cout,
                                const float* __restrict__ g, const float* __restrict__ b)
{
    constexpr int KQ  = CIN/8;
    constexpr int PXT = TPX*16 + 2;
    constexpr int UX  = 3*PXT*KQ;
    constexpr int KQS = (CS > 0) ? CS/8 : 8;
    constexpr int US  = (CS > 0) ? TPX*16*KQS : 0;
    constexpr int UT  = UX + US;
    constexpr int NU  = (UT + 255)/256;
    constexpr int NKC = CIN/32;
    __shared__ uint4 lds4[UT + 8];

    const int tid = threadIdx.x;
    const int lane = tid & 63;
    const int wave = tid >> 6;
    const int cob  = blockIdx.y*64 + wave*16;
    const int n  = blockIdx.z;
    const int wt = blockIdx.x % WT;
    const int h  = blockIdx.x / WT;
    const int w0 = wt*(TPX*16);
    const int l15 = lane & 15;
    const int gq  = lane >> 4;

    // ---- stage: async global->LDS, source pre-swizzled ----
    #pragma unroll
    for (int i = 0; i < NU; ++i) {
        int v = tid + i*256;
        unsigned short* ldst = (unsigned short*)lds4 + (size_t)(i*256 + wave*64)*8;
        if (v < UX) {
            int r   = v / (PXT*KQ);
            int rem = v - r*(PXT*KQ);
            int px  = rem / KQ;
            int kq  = rem - px*KQ;
            int kqs = kq ^ (px & 7);
            stage16(X + (((size_t)(n*33 + h + r))*Wp + w0 + px)*CIN + kqs*8, ldst);
        } else if (CS > 0 && v < UT) {
            int us = v - UX;
            int px = us / KQS;
            int kq = us - px*KQS;
            int kqs = kq ^ (px & 7);
            stage16(Xs + (((size_t)(n*33 + h + 1))*WpS + w0 + 1 + px)*CS + kqs*8, ldst);
        }
    }
    __syncthreads();

    f32x4 acc[TPX] = {};
    #pragma unroll
    for (int dh = 0; dh < 3; ++dh) {
        short8 aw[3*NKC];
        #pragma unroll
        for (int dw = 0; dw < 3; ++dw)
            #pragma unroll
            for (int kc = 0; kc < NKC; ++kc)
                aw[dw*NKC + kc] = *(const short8*)(W9 +
                    ((size_t)((dh*3 + dw)*Cout + cob + l15))*CIN + kc*32 + gq*8);
        #pragma unroll
        for (int dw = 0; dw < 3; ++dw) {
            #pragma unroll
            for (int kc = 0; kc < NKC; ++kc) {
                short8 a = aw[dw*NKC + kc];
                #pragma unroll
                for (int t = 0; t < TPX; ++t) {
                    int px = dw + t*16 + l15;
                    int u  = (dh*PXT + px)*KQ + kc*4 + gq;
                    short8 bv = *(const short8*)((const char*)lds4 + ((u*16) ^ ((px & 7) << 4)));
                    acc[t] = __builtin_amdgcn_mfma_f32_16x16x32_bf16(a, bv, acc[t], 0, 0, 0);
                }
            }
        }
    }

    if (CS > 0) {
        #pragma unroll
        for (int kc = 0; kc < KQS/4; ++kc) {
            short8 a = *(const short8*)(Ws + (size_t)(cob + l15)*CS + kc*32 + gq*8);
            #pragma unroll
            for (int t = 0; t < TPX; ++t) {
                int px = t*16 + l15;
                int u  = UX + px*KQS + kc*4 + gq;
                short8 bv = *(const short8*)((const char*)lds4 + ((u*16) ^ ((px & 7) << 4)));
                acc[t] = __builtin_amdgcn_mfma_f32_16x16x32_bf16(a, bv, acc[t], 0, 0, 0);
            }
        }
    }

    int cb = cob + gq*4;
    float s0 = g[cb+0]*RSQ, s1 = g[cb+1]*RSQ, s2 = g[cb+2]*RSQ, s3 = g[cb+3]*RSQ;
    float o0 = b[cb+0], o1 = b[cb+1], o2 = b[cb+2], o3 = b[cb+3];
    #pragma unroll
    for (int t = 0; t < TPX; ++t) {
        float v0 = acc[t][0]*s0 + o0; v0 = (v0 >= 0.f) ? v0 : SLOPE*v0;
        float v1 = acc[t][1]*s1 + o1; v1 = (v1 >= 0.f) ? v1 : SLOPE*v1;
        float v2 = acc[t][2]*s2 + o2; v2 = (v2 >= 0.f) ? v2 : SLOPE*v2;
        float v3 = acc[t][3]*s3 + o3; v3 = (v3 >= 0.f) ? v3 : SLOPE*v3;
        if (POOL) {
            v0 = fmaxf(v0, __shfl_xor(v0, 1)); v0 = fmaxf(v0, __shfl_xor(v0, 2));
            v1 = fmaxf(v1, __shfl_xor(v1, 1)); v1 = fmaxf(v1, __shfl_xor(v1, 2));
            v2 = fmaxf(v2, __shfl_xor(v2, 1)); v2 = fmaxf(v2, __shfl_xor(v2, 2));
            v3 = fmaxf(v3, __shfl_xor(v3, 1)); v3 = fmaxf(v3, __shfl_xor(v3, 2));
            if ((l15 & 3) == 0) {
                int pw = (w0 + t*16 + l15) >> 2;
                uint2 pk;
                pk.x = (unsigned)f2bf(v0) | ((unsigned)f2bf(v1) << 16);
                pk.y = (unsigned)f2bf(v2) | ((unsigned)f2bf(v3) << 16);
                *(uint2*)(O + (((size_t)(n*HO + h + HOFF))*WpO + pw + OOFF)*Cout + cb) = pk;
            }
        } else {
            int w = w0 + t*16 + l15;
            uint2 pk;
            pk.x = (unsigned)f2bf(v0) | ((unsigned)f2bf(v1) << 16);
            pk.y = (unsigned)f2bf(v2) | ((unsigned)f2bf(v3) << 16);
            *(uint2*)(O + (((size_t)(n*HO + h + HOFF))*WpO + w + OOFF)*Cout + cb) = pk;
        }
    }
}

// ---------------- W=8 LDS-staged conv for r3 layers ----------------
template<int CIN, int CS, int POOL>
__launch_bounds__(256, 2)
__global__ void conv_w8_kernel(const unsigned short* __restrict__ X,
                               const unsigned short* __restrict__ W9,
                               const unsigned short* __restrict__ Xs,
                               const unsigned short* __restrict__ Ws,
                               unsigned short* __restrict__ O, int Cout,
                               const float* __restrict__ g, const float* __restrict__ b)
{
    constexpr int KQ  = CIN/8;
    constexpr int UX  = 4*10*KQ;
    constexpr int KQS = (CS > 0) ? CS/8 : 8;
    constexpr int US  = (CS > 0) ? 2*8*KQS : 0;
    constexpr int UT  = UX + US;
    constexpr int NU  = (UT + 255)/256;
    constexpr int NKC = CIN/32;
    __shared__ uint4 lds4[UT + 8];

    const int tid = threadIdx.x;
    const int lane = tid & 63;
    const int wave = tid >> 6;
    const int hp = blockIdx.x;          // 0..15
    const int n  = blockIdx.z;
    const int h0 = hp*2;
    const int l15 = lane & 15;
    const int gq  = lane >> 4;
    const int r = l15 >> 3;
    const int w = l15 & 7;
    const int cwb = blockIdx.y*128 + wave*32;

    #pragma unroll
    for (int i = 0; i < NU; ++i) {
        int v = tid + i*256;
        unsigned short* ldst = (unsigned short*)lds4 + (size_t)(i*256 + wave*64)*8;
        if (v < UX) {
            int row = v / (10*KQ);
            int rem = v - row*(10*KQ);
            int px  = rem / KQ;
            int kq  = rem - px*KQ;
            int kqs = kq ^ (px & 7);
            stage16(X + (((size_t)(n*34 + h0 + row))*10 + px)*CIN + kqs*8, ldst);
        } else if (CS > 0 && v < UT) {
            int us = v - UX;
            int rs = us / (8*KQS);
            int rem = us - rs*(8*KQS);
            int px8 = rem / KQS;
            int kq  = rem - px8*KQS;
            int kqs = kq ^ (px8 & 7);
            stage16(Xs + (((size_t)(n*34 + h0 + 1 + rs))*10 + px8 + 1)*CS + kqs*8, ldst);
        }
    }
    __syncthreads();

    f32x4 acc0 = {0,0,0,0}, acc1 = {0,0,0,0};
    #pragma unroll
    for (int dh = 0; dh < 3; ++dh) {
        #pragma unroll
        for (int dw = 0; dw < 3; ++dw) {
            short8 a0[NKC], a1[NKC];
            #pragma unroll
            for (int kc = 0; kc < NKC; ++kc) {
                a0[kc] = *(const short8*)(W9 + ((size_t)((dh*3+dw)*Cout + cwb + l15))*CIN + kc*32 + gq*8);
                a1[kc] = *(const short8*)(W9 + ((size_t)((dh*3+dw)*Cout + cwb + 16 + l15))*CIN + kc*32 + gq*8);
            }
            #pragma unroll
            for (int kc = 0; kc < NKC; ++kc) {
                int row_s = r + dh;
                int col = w + dw;
                int u = (row_s*10 + col)*KQ + kc*4 + gq;
                short8 bv = *(const short8*)((const char*)lds4 + ((u*16) ^ ((col & 7) << 4)));
                acc0 = __builtin_amdgcn_mfma_f32_16x16x32_bf16(a0[kc], bv, acc0, 0, 0, 0);
                acc1 = __builtin_amdgcn_mfma_f32_16x16x32_bf16(a1[kc], bv, acc1, 0, 0, 0);
            }
        }
    }

    if (CS > 0) {
        #pragma unroll
        for (int kc = 0; kc < KQS/4; ++kc) {
            short8 a0 = *(const short8*)(Ws + (size_t)(cwb + l15)*CS + kc*32 + gq*8);
            short8 a1 = *(const short8*)(Ws + (size_t)(cwb + 16 + l15)*CS + kc*32 + gq*8);
            int u = UX + (r*8 + w)*KQS + kc*4 + gq;
            short8 bv = *(const short8*)((const char*)lds4 + ((u*16) ^ ((w & 7) << 4)));
            acc0 = __builtin_amdgcn_mfma_f32_16x16x32_bf16(a0, bv, acc0, 0, 0, 0);
            acc1 = __builtin_amdgcn_mfma_f32_16x16x32_bf16(a1, bv, acc1, 0, 0, 0);
        }
    }

    const int hr = h0 + r;
    const bool valid = hr < 31;
#define EPIG8(ACC, G) do { \
    int cb = cwb + (G)*16 + gq*4; \
    float s0 = g[cb+0]*RSQ, s1 = g[cb+1]*RSQ, s2 = g[cb+2]*RSQ, s3 = g[cb+3]*RSQ; \
    float o0 = b[cb+0], o1 = b[cb+1], o2 = b[cb+2], o3 = b[cb+3]; \
    float v0 = ACC[0]*s0 + o0; v0 = (v0 >= 0.f) ? v0 : SLOPE*v0; \
    float v1 = ACC[1]*s1 + o1; v1 = (v1 >= 0.f) ? v1 : SLOPE*v1; \
    float v2 = ACC[2]*s2 + o2; v2 = (v2 >= 0.f) ? v2 : SLOPE*v2; \
    float v3 = ACC[3]*s3 + o3; v3 = (v3 >= 0.f) ? v3 : SLOPE*v3; \
    if (POOL) { \
        v0 = fmaxf(v0, __shfl_xor(v0, 1)); v0 = fmaxf(v0, __shfl_xor(v0, 2)); \
        v1 = fmaxf(v1, __shfl_xor(v1, 1)); v1 = fmaxf(v1, __shfl_xor(v1, 2)); \
        v2 = fmaxf(v2, __shfl_xor(v2, 1)); v2 = fmaxf(v2, __shfl_xor(v2, 2)); \
        v3 = fmaxf(v3, __shfl_xor(v3, 1)); v3 = fmaxf(v3, __shfl_xor(v3, 2)); \
        if (((l15 & 3) == 0) && valid) { \
            uint2 pk; \
            pk.x = (unsigned)f2bf(v0) | ((unsigned)f2bf(v1) << 16); \
            pk.y = (unsigned)f2bf(v2) | ((unsigned)f2bf(v3) << 16); \
            *(uint2*)(O + (((size_t)(n*31 + hr))*2 + (w >> 2))*Cout + cb) = pk; \
        } \
    } else if (valid) { \
        uint2 pk; \
        pk.x = (unsigned)f2bf(v0) | ((unsigned)f2bf(v1) << 16); \
        pk.y = (unsigned)f2bf(v2) | ((unsigned)f2bf(v3) << 16); \
        *(uint2*)(O + (((size_t)(n*34 + hr + 1))*10 + w + 1)*Cout + cb) = pk; \
    } \
} while(0)
    EPIG8(acc0, 0);
    EPIG8(acc1, 1);
#undef EPIG8
}

// ---------------- feats: [n][31][2][256] bf16 NHWC -> [n][31][512] bf16 (pure permute) ----------------
__global__ void feats_kernel(const unsigned short* __restrict__ p4, unsigned short* __restrict__ fe)
{
    int idx = blockIdx.x*256 + threadIdx.x;   // 507904
    int cw = idx & 511;
    int nh = idx >> 9;
    int c = cw >> 1, w = cw & 1;
    fe[idx] = p4[((size_t)nh*2 + w)*256 + c];
}

// ---------------- MFMA GEMM: C[M,N] = A[M,K](bf16) @ B[N,K]^T(bf16) + bias(+bias2), fp32 out ----------------
// Fragment mapping mirrors conv_lds (verified): A-op = B rows (n, via l15),
// B-op = A rows (m, via t*16+l15); acc[t][j] -> (m = m0+t*16+l15, n = n0w+gq*4+j).
// XPOSE=1: store C[((m%31)*32 + m/31)*N + n] (xp layout [t][b][j], M = b*31+t).
template<int XPOSE>
__launch_bounds__(256)
__global__ void gemm_mfma_kernel(const unsigned short* __restrict__ A,
                                 const unsigned short* __restrict__ B,
                                 const float* __restrict__ bias, const float* __restrict__ bias2,
                                 float* __restrict__ C, int M, int N, int K)
{
    const int lane = threadIdx.x & 63;
    const int wave = threadIdx.x >> 6;
    const int l15 = lane & 15;
    const int gq = lane >> 4;
    const int n0 = blockIdx.y*64 + wave*16;
    const int m0 = blockIdx.x*64;

    int nrow = n0 + l15; if (nrow > N-1) nrow = N-1;
    const unsigned short* bp = B + (size_t)nrow*K + gq*8;
    int mr[4];
    #pragma unroll
    for (int t = 0; t < 4; ++t) {
        int m = m0 + t*16 + l15;
        mr[t] = (m > M-1) ? (M-1) : m;
    }

    f32x4 acc[4] = {};
    for (int k0 = 0; k0 < K; k0 += 32) {
        short8 a = *(const short8*)(bp + k0);
        #pragma unroll
        for (int t = 0; t < 4; ++t) {
            short8 b = *(const short8*)(A + (size_t)mr[t]*K + gq*8 + k0);
            acc[t] = __builtin_amdgcn_mfma_f32_16x16x32_bf16(a, b, acc[t], 0, 0, 0);
        }
    }

    int nb = n0 + gq*4;
    float bs[4];
    #pragma unroll
    for (int j = 0; j < 4; ++j) {
        int n = nb + j; int nc = (n > N-1) ? (N-1) : n;
        bs[j] = (bias ? bias[nc] : 0.f) + (bias2 ? bias2[nc] : 0.f);
    }
    #pragma unroll
    for (int t = 0; t < 4; ++t) {
        int m = m0 + t*16 + l15;
        if (m >= M) continue;
        size_t rowoff = XPOSE ? ((size_t)(m % 31)*32 + (m / 31))*(size_t)N : (size_t)m*N;
        #pragma unroll
        for (int j = 0; j < 4; ++j) {
            int n = nb + j;
            if (n < N) C[rowoff + n] = acc[t][j] + bs[j];
        }
    }
}

// ---------------- LSTM scan via MFMA: 4 blocks = (dir x batch-half), 1024 thr ----------------
__launch_bounds__(1024)
__global__ void lstm_scan_mfma(const float* __restrict__ xpT,
                               const unsigned short* __restrict__ wf,
                               unsigned short* __restrict__ hcat)
{
    const int d  = blockIdx.x >> 1;
    const int bh = blockIdx.x & 1;
    const int tid = threadIdx.x;
    const int u0 = tid >> 6;
    const int lane = tid & 63;
    const int l15 = lane & 15;
    const int q = lane >> 4;

    __shared__ unsigned short hbuf[2][4096];          // 16 KB
    __shared__ unsigned short wst[16][2][2048];       // 128 KB

    ((int4*)hbuf)[tid & 1023] = make_int4(0,0,0,0);

    const unsigned short* wfd = wf + (size_t)d*262144;
    const float* xpd = xpT + (size_t)d*992*1024 + (size_t)bh*16*1024;
    const unsigned short* wsrc = wfd + (size_t)u0*4096 + (size_t)lane*8;
    unsigned short* wl = &wst[u0][0][0];

#define STAGE(KC, PB) do { \
    unsigned short* dst_ = wl + (PB)*2048; \
    stage16(wsrc + 0*65536 + (KC)*512, dst_ + 0*512); \
    stage16(wsrc + 1*65536 + (KC)*512, dst_ + 1*512); \
    stage16(wsrc + 2*65536 + (KC)*512, dst_ + 2*512); \
    stage16(wsrc + 3*65536 + (KC)*512, dst_ + 3*512); \
} while(0)

    float c0=0.f, c1=0.f, c2=0.f, c3=0.f;
    const int ubase = u0*16 + q*4;
    const int rb = l15*512 + q*16;
    const int xr = (l15&7)<<4;

    STAGE(0, 0);
    float4 xi, xf, xg, xo;
    {
        const int t0 = d ? 30 : 0;
        const float* xb = xpd + (size_t)t0*32768 + (size_t)l15*1024;
        xi = *(const float4*)(xb + ubase);
        xf = *(const float4*)(xb + 256 + ubase);
        xg = *(const float4*)(xb + 512 + ubase);
        xo = *(const float4*)(xb + 768 + ubase);
    }
    asm volatile("s_waitcnt lgkmcnt(0)" ::: "memory");
    __builtin_amdgcn_s_barrier();

#define HRD(kc)   (*(const short8*)(hb + ((rb + (kc)*64) ^ xr)))
#define MF(w_,h_,a_) a_ = __builtin_amdgcn_mfma_f32_16x16x32_bf16(w_, h_, a_, 0, 0, 0)

    for (int s = 0; s < 31; ++s) {
        const int t = d ? (30 - s) : s;
        const int cur = s & 1, nxt = cur ^ 1;

        const char* hb = (const char*)hbuf[cur];
        f32x4 a0={0,0,0,0}, a1={0,0,0,0}, a2={0,0,0,0}, a3={0,0,0,0};

        #pragma unroll
        for (int kc = 0; kc < 8; ++kc) {
            if (kc < 7) STAGE(kc+1, (kc+1)&1);
            else        STAGE(0, 0);
            if (kc == 0) asm volatile("s_waitcnt vmcnt(8)" ::: "memory");
            else         asm volatile("s_waitcnt vmcnt(4)" ::: "memory");
            const unsigned short* wb = wl + (kc&1)*2048;
            short8 w0 = *(const short8*)(wb + 0*512 + lane*8);
            short8 w1 = *(const short8*)(wb + 1*512 + lane*8);
            short8 w2 = *(const short8*)(wb + 2*512 + lane*8);
            short8 w3 = *(const short8*)(wb + 3*512 + lane*8);
            short8 h = HRD(kc);
            MF(w0,h,a0); MF(w1,h,a1); MF(w2,h,a2); MF(w3,h,a3);
        }

        float4 nxi, nxf, nxg, nxo;
        {
            int s2 = (s < 30) ? s + 1 : s;
            int t2 = d ? (30 - s2) : s2;
            const float* xb = xpd + (size_t)t2*32768 + (size_t)l15*1024;
            nxi = *(const float4*)(xb + ubase);
            nxf = *(const float4*)(xb + 256 + ubase);
            nxg = *(const float4*)(xb + 512 + ubase);
            nxo = *(const float4*)(xb + 768 + ubase);
        }

        float hv0, hv1, hv2, hv3;
        { float gi=a0[0]+xi.x, gf=a1[0]+xf.x, gg=a2[0]+xg.x, go=a3[0]+xo.x;
          float cn = sigmoidf_(gf)*c0 + sigmoidf_(gi)*tanhf(gg); c0 = cn; hv0 = sigmoidf_(go)*tanhf(cn); }
        { float gi=a0[1]+xi.y, gf=a1[1]+xf.y, gg=a2[1]+xg.y, go=a3[1]+xo.y;
          float cn = sigmoidf_(gf)*c1 + sigmoidf_(gi)*tanhf(gg); c1 = cn; hv1 = sigmoidf_(go)*tanhf(cn); }
        { float gi=a0[2]+xi.z, gf=a1[2]+xf.z, gg=a2[2]+xg.z, go=a3[2]+xo.z;
          float cn = sigmoidf_(gf)*c2 + sigmoidf_(gi)*tanhf(gg); c2 = cn; hv2 = sigmoidf_(go)*tanhf(cn); }
        { float gi=a0[3]+xi.w, gf=a1[3]+xf.w, gg=a2[3]+xg.w, go=a3[3]+xo.w;
          float cn = sigmoidf_(gf)*c3 + sigmoidf_(gi)*tanhf(gg); c3 = cn; hv3 = sigmoidf_(go)*tanhf(cn); }

        short4 hp;
        hp.x = (short)f2bf(hv0); hp.y = (short)f2bf(hv1);
        hp.z = (short)f2bf(hv2); hp.w = (short)f2bf(hv3);
        *(short4*)((char*)hbuf[nxt] + ((l15*512 + ubase*2) ^ xr)) = hp;
        int bg = bh*16 + l15;
        *(short4*)(&hcat[((size_t)bg*31 + t)*512 + (size_t)d*256 + ubase]) = hp;

        asm volatile("s_waitcnt lgkmcnt(0)" ::: "memory");
        __builtin_amdgcn_s_barrier();

        xi = nxi; xf = nxf; xg = nxg; xo = nxo;
    }
#undef STAGE
#undef HRD
#undef MF
}

extern "C" void kernel_launch(void* const* d_in, const int* in_sizes, int n_in,
                              void* d_out, int out_size, void* d_ws, size_t ws_size,
                              hipStream_t stream)
{
    const float* x    = (const float*)d_in[0];
    const float* fW   = (const float*)d_in[1];
    const float* fB   = (const float*)d_in[2];
    const float* cbw1 = (const float*)d_in[3];
    const float* cbg  = (const float*)d_in[4];
    const float* cbb  = (const float*)d_in[5];
    const float* cbw2 = (const float*)d_in[6];
    const float* r1pg = (const float*)d_in[7];
    const float* r1pb = (const float*)d_in[8];
    const float* r1wA = (const float*)d_in[9];
    const float* r1g  = (const float*)d_in[10];
    const float* r1b  = (const float*)d_in[11];
    const float* r1wB = (const float*)d_in[12];
    const float* r1s  = (const float*)d_in[13];
    const float* r2pg = (const float*)d_in[14];
    const float* r2pb = (const float*)d_in[15];
    const float* r2wA = (const float*)d_in[16];
    const float* r2g  = (const float*)d_in[17];
    const float* r2b  = (const float*)d_in[18];
    const float* r2wB = (const float*)d_in[19];
    const float* r2s  = (const float*)d_in[20];
    const float* r3pg = (const float*)d_in[21];
    const float* r3pb = (const float*)d_in[22];
    const float* r3wA = (const float*)d_in[23];
    const float* r3g  = (const float*)d_in[24];
    const float* r3b  = (const float*)d_in[25];
    const float* r3wB = (const float*)d_in[26];
    const float* r3s  = (const float*)d_in[27];
    const float* pbg  = (const float*)d_in[28];
    const float* pbb  = (const float*)d_in[29];
    const float* wih_f = (const float*)d_in[30];
    const float* whh_f = (const float*)d_in[31];
    const float* bih_f = (const float*)d_in[32];
    const float* bhh_f = (const float*)d_in[33];
    const float* wih_b = (const float*)d_in[34];
    const float* whh_b = (const float*)d_in[35];
    const float* bih_b = (const float*)d_in[36];
    const float* bhh_b = (const float*)d_in[37];
    const float* clsw  = (const float*)d_in[38];
    const float* clsb  = (const float*)d_in[39];
    float* out = (float*)d_out;
    float* ws  = (float*)d_ws;

    // ---- workspace sizing (floats) ----
    // fixed: WTR 962560 + WIHT 524288 + CLST 184832 + P 508896 + XM 508896
    //      + XP4 253952 + FE 253952 + WF 262144 + XPT 2031616 + HC 253952 = 5745088
    const size_t FIXEDF = 5745088;
    const size_t PCS = 2422720;
    const size_t PCF = (PCS + 1)/2;
    int NC = 0;
    const int cands[6] = {32,16,8,4,2,1};
    for (int i = 0; i < 6; ++i) {
        if ((FIXEDF + (size_t)cands[i]*PCF + 64)*sizeof(float) <= ws_size) { NC = cands[i]; break; }
    }
    if (!NC) return;

    float* p = ws;
    unsigned short* WTR  = (unsigned short*)p; p += 962560;
    unsigned short* WIHT = (unsigned short*)p; p += 524288;   // 2 x 1024x512 bf16
    unsigned short* CLST = (unsigned short*)p; p += 184832;   // 722x512 bf16
    float* P   = p; p += 508896;
    float* XM  = p; p += 508896;
    unsigned short* XP4 = (unsigned short*)p; p += 253952;
    unsigned short* FEb = (unsigned short*)p; p += 253952;
    unsigned short* WF  = (unsigned short*)p; p += 262144;
    float* XPT = p; p += 2031616;
    unsigned short* HCb = (unsigned short*)p; p += 253952;
    unsigned short* q = (unsigned short*)p;
    unsigned short* A1  = q; q += (size_t)NC*1087680;
    unsigned short* C1p = q; q += (size_t)NC*274560;
    unsigned short* A2  = q; q += (size_t)NC*549120;
    unsigned short* C2p = q; q += (size_t)NC*143616;
    unsigned short* A3  = q; q += (size_t)NC*215424;
    unsigned short* XP3 = q; q += (size_t)NC*65280;
    unsigned short* A4  = q; q += (size_t)NC*87040;

    unsigned short* w2T  = WTR + 0;
    unsigned short* r1AT = WTR + 36864;
    unsigned short* r1BT = WTR + 110592;
    unsigned short* r1ST = WTR + 258048;
    unsigned short* r2AT = WTR + 266240;
    unsigned short* r2BT = WTR + 487424;
    unsigned short* r2ST = WTR + 819200;
    unsigned short* r3AT = WTR + 843776;
    unsigned short* r3BT = WTR + 1286144;
    unsigned short* r3ST = WTR + 1875968;

    auto cdiv = [](int a, int b){ return (a + b - 1) / b; };

    // ---- weight transforms ----
    wtrans9_kernel<<<cdiv(9*64*64,256),   256, 0, stream>>>(cbw2, w2T, 64, 64);
    wtrans9_kernel<<<cdiv(9*128*64,256),  256, 0, stream>>>(r1wA, r1AT, 128, 64);
    wtrans9_kernel<<<cdiv(9*128*128,256), 256, 0, stream>>>(r1wB, r1BT, 128, 128);
    wtrans1_kernel<<<cdiv(128*64,256),    256, 0, stream>>>(r1s, r1ST, 128*64);
    wtrans9_kernel<<<cdiv(9*192*128,256), 256, 0, stream>>>(r2wA, r2AT, 192, 128);
    wtrans9_kernel<<<cdiv(9*192*192,256), 256, 0, stream>>>(r2wB, r2BT, 192, 192);
    wtrans1_kernel<<<cdiv(192*128,256),   256, 0, stream>>>(r2s, r2ST, 192*128);
    wtrans9_kernel<<<cdiv(9*256*192,256), 256, 0, stream>>>(r3wA, r3AT, 256, 192);
    wtrans9_kernel<<<cdiv(9*256*256,256), 256, 0, stream>>>(r3wB, r3BT, 256, 256);
    wtrans1_kernel<<<cdiv(256*192,256),   256, 0, stream>>>(r3s, r3ST, 256*192);
    whh_frag_kernel<<<1024, 256, 0, stream>>>(whh_f, WF);
    whh_frag_kernel<<<1024, 256, 0, stream>>>(whh_b, WF + 262144);
    wtrans1_kernel<<<cdiv(1024*512,256),  256, 0, stream>>>(wih_f, WIHT, 1024*512);
    wtrans1_kernel<<<cdiv(1024*512,256),  256, 0, stream>>>(wih_b, WIHT + 524288, 1024*512);
    wtrans1_kernel<<<cdiv(722*512,256),   256, 0, stream>>>(clsw, CLST, 722*512);

    // ---- frontend mask ----
    mask_partial_kernel<<<dim3(63, 32), 256, 0, stream>>>(fW, fB, P);
    mask_finalize_apply<<<63, 256, 0, stream>>>(P, x, XM);

    // ---- zero padded staging region (all halos stay zero) ----
    hipMemsetAsync(A1, 0, (size_t)NC*PCS*sizeof(unsigned short), stream);

    // ---- conv stack, chunked over batch ----
    for (int c0 = 0; c0 < 32; c0 += NC) {
        const float* xmc = XM + (size_t)c0*15903;
        conv1_kernel<<<dim3(63, 1, NC), 256, 0, stream>>>(xmc, cbw1, cbg, cbb, A1);
        conv_lds_kernel<64,8,0,1><<<dim3(4*31, 1, NC), 256, 0, stream>>>(
            A1, w2T, nullptr, nullptr, C1p, 515, 4, 0, 33, 1, 130, 1, 64, r1pg, r1pb);
        conv_lds_kernel<64,8,0,0><<<dim3(31, 2, NC), 256, 0, stream>>>(
            C1p, r1AT, nullptr, nullptr, A2, 130, 1, 0, 33, 1, 130, 1, 128, r1g, r1b);
        conv_lds_kernel<128,8,64,1><<<dim3(31, 2, NC), 256, 0, stream>>>(
            A2, r1BT, C1p, r1ST, C2p, 130, 1, 130, 33, 1, 34, 1, 128, r2pg, r2pb);
        conv_lds_kernel<128,2,0,0><<<dim3(31, 3, NC), 256, 0, stream>>>(
            C2p, r2AT, nullptr, nullptr, A3, 34, 1, 0, 33, 1, 34, 1, 192, r2g, r2b);
        conv_lds_kernel<192,2,128,1><<<dim3(31, 3, NC), 256, 0, stream>>>(
            A3, r2BT, C2p, r2ST, XP3, 34, 1, 34, 34, 1, 10, 1, 192, r3pg, r3pb);
        conv_w8_kernel<192,0,0><<<dim3(16, 2, NC), 256, 0, stream>>>(
            XP3, r3AT, nullptr, nullptr, A4, 256, r3g, r3b);
        conv_w8_kernel<256,192,1><<<dim3(16, 2, NC), 256, 0, stream>>>(
            A4, r3BT, XP3, r3ST, XP4 + (size_t)c0*15872, 256, pbg, pbb);
    }

    // feats (32,31,512) bf16 (pure permute of XP4)
    feats_kernel<<<1984, 256, 0, stream>>>(XP4, FEb);

    // LSTM input projections (MFMA) -> xpT [d][t][b][j] fp32
    gemm_mfma_kernel<1><<<dim3(16, 16), 256, 0, stream>>>(FEb, WIHT,          bih_f, bhh_f, XPT,           992, 1024, 512);
    gemm_mfma_kernel<1><<<dim3(16, 16), 256, 0, stream>>>(FEb, WIHT + 524288, bih_b, bhh_b, XPT + 1015808, 992, 1024, 512);

    // fused bidirectional scan (4 blocks: dir x batch-half), hcat bf16
    lstm_scan_mfma<<<4, 1024, 0, stream>>>(XPT, WF, HCb);

    // classifier (MFMA) -> d_out (32,31,722) fp32
    gemm_mfma_kernel<0><<<dim3(16, 12), 256, 0, stream>>>(HCb, CLST, clsb, nullptr, out, 992, 722, 512);
}

// Round 19
// 902.470 us; speedup vs baseline: 1.9977x; 1.0297x over previous
//
#include <hip/hip_runtime.h>
#include <hip/hip_bf16.h>
#include <math.h>

#define RSQ 0.99999500003749969f   // 1/sqrt(1+1e-5)
#define SLOPE 0.01f

typedef __attribute__((ext_vector_type(8))) short short8;
typedef __attribute__((ext_vector_type(4))) float f32x4;

__device__ __forceinline__ float sigmoidf_(float x){ return 1.0f/(1.0f+expf(-x)); }

__device__ __forceinline__ unsigned short f2bf(float f){
    unsigned u = __float_as_uint(f);
    u += 0x7fff + ((u >> 16) & 1);      // RNE
    return (unsigned short)(u >> 16);
}
__device__ __forceinline__ float bf2f(unsigned short s){
    return __uint_as_float(((unsigned)s) << 16);
}

// async global->LDS, 16B per lane; LDS dest is wave-uniform base + lane*16
__device__ __forceinline__ void stage16(const unsigned short* g, unsigned short* l) {
    __builtin_amdgcn_global_load_lds(
        (const __attribute__((address_space(1))) unsigned int*)g,
        (__attribute__((address_space(3))) unsigned int*)l, 16, 0, 0);
}

// ---------------- mask: prod_k cos(fW*rng + fB) ----------------
__global__ void mask_partial_kernel(const float* __restrict__ fW, const float* __restrict__ fB,
                                    float* __restrict__ partial)
{
    int p = blockIdx.x*256 + threadIdx.x;   // 0..15902
    if (p >= 15903) return;
    int w = p % 513;
    float r = (float)(w + 1);
    int k0 = blockIdx.y * 32;
    float prod = 1.0f;
    for (int k = k0; k < k0 + 32; ++k) {
        float a = fW[(size_t)k*15903 + p] * r + fB[(size_t)k*15903 + p];
        prod *= cosf(a);
    }
    partial[blockIdx.y*15903 + p] = prod;
}

__global__ void mask_finalize_apply(const float* __restrict__ partial, const float* __restrict__ x,
                                    float* __restrict__ xm)
{
    int p = blockIdx.x*256 + threadIdx.x;
    if (p >= 15903) return;
    float m = 1.0f;
    #pragma unroll
    for (int c = 0; c < 32; ++c) m *= partial[c*15903 + p];
    for (int n = 0; n < 32; ++n)
        xm[(size_t)n*15903 + p] = x[(size_t)n*15903 + p] * m;
}

// ---------------- ALL weight transforms in one launch (job table) ----------------
struct XJobs { const float* s[15]; unsigned short* d[15]; };

__global__ void wtrans_all_kernel(XJobs j)
{
    // type: 0 = OIHW->(tap,co,ci), 1 = flat bf16 cast, 2 = whh fragment pack
    constexpr int TYPE[15] = {0,0,0,1,0,0,1,0,0,1,2,2,1,1,1};
    constexpr int TOT[15]  = {36864,73728,147456,8192,221184,331776,24576,
                              442368,589824,49152,262144,262144,524288,524288,369664};
    constexpr int COUT[15] = {64,128,128,0,192,192,0,256,256,0,0,0,0,0,0};
    constexpr int CIN[15]  = {64,64,128,0,128,192,0,192,256,0,0,0,0,0,0};

    const int job = blockIdx.y;
    const int idx = blockIdx.x*256 + threadIdx.x;
    if (idx >= TOT[job]) return;
    const float* w = j.s[job];
    unsigned short* o = j.d[job];

    if (TYPE[job] == 0) {
        int cc = COUT[job]*CIN[job];
        int tap = idx / cc;
        int r = idx - tap*cc;
        int co = r / CIN[job], ci = r - co*CIN[job];
        int kh = tap/3, kw = tap - kh*3;
        o[idx] = f2bf(w[((size_t)(co*CIN[job] + ci)*3 + kh)*3 + kw]);
    } else if (TYPE[job] == 1) {
        o[idx] = f2bf(w[idx]);
    } else {
        int e    = idx & 7;
        int lane = (idx >> 3) & 63;
        int kc   = (idx >> 9) & 7;
        int u0   = (idx >> 12) & 15;
        int g    = idx >> 16;
        int jj = (g << 8) + (u0 << 4) + (lane & 15);
        int k  = (kc << 5) + ((lane >> 4) << 3) + e;
        o[idx] = f2bf(w[(size_t)jj*256 + k]);
    }
}

// ---------------- conv1: Cin=1 direct, fp32 in -> bf16 NHWC (rows 1..31 of [33][515][64]) ----------------
__launch_bounds__(256)
__global__ void conv1_kernel(const float* __restrict__ xm, const float* __restrict__ w1,
                             const float* __restrict__ g, const float* __restrict__ b,
                             unsigned short* __restrict__ O)
{
    __shared__ float wl[576];
    __shared__ float sg[64], sb[64];
    int tid = threadIdx.x;
    if (tid < 64) { sg[tid] = g[tid]*RSQ; sb[tid] = b[tid]; }
    for (int i = tid; i < 576; i += 256) wl[i] = w1[i];
    __syncthreads();
    int px = blockIdx.x*256 + tid;
    int n = blockIdx.z;
    if (px >= 15903) return;
    int h = px / 513, w = px - h*513;
    const float* xp = xm + (size_t)n*15903;
    float v[9];
    #pragma unroll
    for (int dh = 0; dh < 3; ++dh)
      #pragma unroll
      for (int dw = 0; dw < 3; ++dw) {
        int hh = h+dh-1, ww = w+dw-1;
        bool ok = ((unsigned)hh < 31u) && ((unsigned)ww < 513u);
        v[dh*3+dw] = ok ? xp[hh*513 + ww] : 0.f;
      }
    unsigned short* op = O + (((size_t)(n*33 + h + 1))*515 + (w + 1))*64;
    #pragma unroll
    for (int c8 = 0; c8 < 8; ++c8) {
        unsigned tmp[8];
        #pragma unroll
        for (int j = 0; j < 8; ++j) {
            int co = c8*8 + j;
            const float* wr = &wl[co*9];
            float a = 0.f;
            #pragma unroll
            for (int t2 = 0; t2 < 9; ++t2) a += wr[t2]*v[t2];
            a = a*sg[co] + sb[co];
            a = (a >= 0.f) ? a : SLOPE*a;
            tmp[j] = f2bf(a);
        }
        uint4 pk;
        pk.x = tmp[0] | (tmp[1]<<16);
        pk.y = tmp[2] | (tmp[3]<<16);
        pk.z = tmp[4] | (tmp[5]<<16);
        pk.w = tmp[6] | (tmp[7]<<16);
        *(uint4*)(op + c8*8) = pk;
    }
}

// ---------------- LDS-staged implicit-GEMM 3x3 conv (+1x1 shortcut) via MFMA ----------------
template<int CIN, int TPX, int CS, int POOL>
__launch_bounds__(256, 2)
__global__ void conv_lds_kernel(const unsigned short* __restrict__ X,
                                const unsigned short* __restrict__ W9,
                                const unsigned short* __restrict__ Xs,
                                const unsigned short* __restrict__ Ws,
                                unsigned short* __restrict__ O,
                                int Wp, int WT, int WpS,
                                int HO, int HOFF, int WpO, int OOFF, int Cout,
                                const float* __restrict__ g, const float* __restrict__ b)
{
    constexpr int KQ  = CIN/8;
    constexpr int PXT = TPX*16 + 2;
    constexpr int UX  = 3*PXT*KQ;
    constexpr int KQS = (CS > 0) ? CS/8 : 8;
    constexpr int US  = (CS > 0) ? TPX*16*KQS : 0;
    constexpr int UT  = UX + US;
    constexpr int NU  = (UT + 255)/256;
    constexpr int NKC = CIN/32;
    __shared__ uint4 lds4[UT + 8];

    const int tid = threadIdx.x;
    const int lane = tid & 63;
    const int wave = tid >> 6;
    const int cob  = blockIdx.y*64 + wave*16;
    const int n  = blockIdx.z;
    const int wt = blockIdx.x % WT;
    const int h  = blockIdx.x / WT;
    const int w0 = wt*(TPX*16);
    const int l15 = lane & 15;
    const int gq  = lane >> 4;

    #pragma unroll
    for (int i = 0; i < NU; ++i) {
        int v = tid + i*256;
        unsigned short* ldst = (unsigned short*)lds4 + (size_t)(i*256 + wave*64)*8;
        if (v < UX) {
            int r   = v / (PXT*KQ);
            int rem = v - r*(PXT*KQ);
            int px  = rem / KQ;
            int kq  = rem - px*KQ;
            int kqs = kq ^ (px & 7);
            stage16(X + (((size_t)(n*33 + h + r))*Wp + w0 + px)*CIN + kqs*8, ldst);
        } else if (CS > 0 && v < UT) {
            int us = v - UX;
            int px = us / KQS;
            int kq = us - px*KQS;
            int kqs = kq ^ (px & 7);
            stage16(Xs + (((size_t)(n*33 + h + 1))*WpS + w0 + 1 + px)*CS + kqs*8, ldst);
        }
    }
    __syncthreads();

    f32x4 acc[TPX] = {};
    #pragma unroll
    for (int dh = 0; dh < 3; ++dh) {
        short8 aw[3*NKC];
        #pragma unroll
        for (int dw = 0; dw < 3; ++dw)
            #pragma unroll
            for (int kc = 0; kc < NKC; ++kc)
                aw[dw*NKC + kc] = *(const short8*)(W9 +
                    ((size_t)((dh*3 + dw)*Cout + cob + l15))*CIN + kc*32 + gq*8);
        #pragma unroll
        for (int dw = 0; dw < 3; ++dw) {
            #pragma unroll
            for (int kc = 0; kc < NKC; ++kc) {
                short8 a = aw[dw*NKC + kc];
                #pragma unroll
                for (int t = 0; t < TPX; ++t) {
                    int px = dw + t*16 + l15;
                    int u  = (dh*PXT + px)*KQ + kc*4 + gq;
                    short8 bv = *(const short8*)((const char*)lds4 + ((u*16) ^ ((px & 7) << 4)));
                    acc[t] = __builtin_amdgcn_mfma_f32_16x16x32_bf16(a, bv, acc[t], 0, 0, 0);
                }
            }
        }
    }

    if (CS > 0) {
        #pragma unroll
        for (int kc = 0; kc < KQS/4; ++kc) {
            short8 a = *(const short8*)(Ws + (size_t)(cob + l15)*CS + kc*32 + gq*8);
            #pragma unroll
            for (int t = 0; t < TPX; ++t) {
                int px = t*16 + l15;
                int u  = UX + px*KQS + kc*4 + gq;
                short8 bv = *(const short8*)((const char*)lds4 + ((u*16) ^ ((px & 7) << 4)));
                acc[t] = __builtin_amdgcn_mfma_f32_16x16x32_bf16(a, bv, acc[t], 0, 0, 0);
            }
        }
    }

    int cb = cob + gq*4;
    float s0 = g[cb+0]*RSQ, s1 = g[cb+1]*RSQ, s2 = g[cb+2]*RSQ, s3 = g[cb+3]*RSQ;
    float o0 = b[cb+0], o1 = b[cb+1], o2 = b[cb+2], o3 = b[cb+3];
    #pragma unroll
    for (int t = 0; t < TPX; ++t) {
        float v0 = acc[t][0]*s0 + o0; v0 = (v0 >= 0.f) ? v0 : SLOPE*v0;
        float v1 = acc[t][1]*s1 + o1; v1 = (v1 >= 0.f) ? v1 : SLOPE*v1;
        float v2 = acc[t][2]*s2 + o2; v2 = (v2 >= 0.f) ? v2 : SLOPE*v2;
        float v3 = acc[t][3]*s3 + o3; v3 = (v3 >= 0.f) ? v3 : SLOPE*v3;
        if (POOL) {
            v0 = fmaxf(v0, __shfl_xor(v0, 1)); v0 = fmaxf(v0, __shfl_xor(v0, 2));
            v1 = fmaxf(v1, __shfl_xor(v1, 1)); v1 = fmaxf(v1, __shfl_xor(v1, 2));
            v2 = fmaxf(v2, __shfl_xor(v2, 1)); v2 = fmaxf(v2, __shfl_xor(v2, 2));
            v3 = fmaxf(v3, __shfl_xor(v3, 1)); v3 = fmaxf(v3, __shfl_xor(v3, 2));
            if ((l15 & 3) == 0) {
                int pw = (w0 + t*16 + l15) >> 2;
                uint2 pk;
                pk.x = (unsigned)f2bf(v0) | ((unsigned)f2bf(v1) << 16);
                pk.y = (unsigned)f2bf(v2) | ((unsigned)f2bf(v3) << 16);
                *(uint2*)(O + (((size_t)(n*HO + h + HOFF))*WpO + pw + OOFF)*Cout + cb) = pk;
            }
        } else {
            int w = w0 + t*16 + l15;
            uint2 pk;
            pk.x = (unsigned)f2bf(v0) | ((unsigned)f2bf(v1) << 16);
            pk.y = (unsigned)f2bf(v2) | ((unsigned)f2bf(v3) << 16);
            *(uint2*)(O + (((size_t)(n*HO + h + HOFF))*WpO + w + OOFF)*Cout + cb) = pk;
        }
    }
}

// ---------------- W=8 LDS-staged conv for r3 layers ----------------
// FEATS=1 (with POOL=1): write [n][31][512] feats layout directly (c*2 + pw).
template<int CIN, int CS, int POOL, int FEATS>
__launch_bounds__(256, 2)
__global__ void conv_w8_kernel(const unsigned short* __restrict__ X,
                               const unsigned short* __restrict__ W9,
                               const unsigned short* __restrict__ Xs,
                               const unsigned short* __restrict__ Ws,
                               unsigned short* __restrict__ O, int Cout,
                               const float* __restrict__ g, const float* __restrict__ b)
{
    constexpr int KQ  = CIN/8;
    constexpr int UX  = 4*10*KQ;
    constexpr int KQS = (CS > 0) ? CS/8 : 8;
    constexpr int US  = (CS > 0) ? 2*8*KQS : 0;
    constexpr int UT  = UX + US;
    constexpr int NU  = (UT + 255)/256;
    constexpr int NKC = CIN/32;
    __shared__ uint4 lds4[UT + 8];

    const int tid = threadIdx.x;
    const int lane = tid & 63;
    const int wave = tid >> 6;
    const int hp = blockIdx.x;          // 0..15
    const int n  = blockIdx.z;
    const int h0 = hp*2;
    const int l15 = lane & 15;
    const int gq  = lane >> 4;
    const int r = l15 >> 3;
    const int w = l15 & 7;
    const int cwb = blockIdx.y*128 + wave*32;

    #pragma unroll
    for (int i = 0; i < NU; ++i) {
        int v = tid + i*256;
        unsigned short* ldst = (unsigned short*)lds4 + (size_t)(i*256 + wave*64)*8;
        if (v < UX) {
            int row = v / (10*KQ);
            int rem = v - row*(10*KQ);
            int px  = rem / KQ;
            int kq  = rem - px*KQ;
            int kqs = kq ^ (px & 7);
            stage16(X + (((size_t)(n*34 + h0 + row))*10 + px)*CIN + kqs*8, ldst);
        } else if (CS > 0 && v < UT) {
            int us = v - UX;
            int rs = us / (8*KQS);
            int rem = us - rs*(8*KQS);
            int px8 = rem / KQS;
            int kq  = rem - px8*KQS;
            int kqs = kq ^ (px8 & 7);
            stage16(Xs + (((size_t)(n*34 + h0 + 1 + rs))*10 + px8 + 1)*CS + kqs*8, ldst);
        }
    }
    __syncthreads();

    f32x4 acc0 = {0,0,0,0}, acc1 = {0,0,0,0};
    #pragma unroll
    for (int dh = 0; dh < 3; ++dh) {
        #pragma unroll
        for (int dw = 0; dw < 3; ++dw) {
            short8 a0[NKC], a1[NKC];
            #pragma unroll
            for (int kc = 0; kc < NKC; ++kc) {
                a0[kc] = *(const short8*)(W9 + ((size_t)((dh*3+dw)*Cout + cwb + l15))*CIN + kc*32 + gq*8);
                a1[kc] = *(const short8*)(W9 + ((size_t)((dh*3+dw)*Cout + cwb + 16 + l15))*CIN + kc*32 + gq*8);
            }
            #pragma unroll
            for (int kc = 0; kc < NKC; ++kc) {
                int row_s = r + dh;
                int col = w + dw;
                int u = (row_s*10 + col)*KQ + kc*4 + gq;
                short8 bv = *(const short8*)((const char*)lds4 + ((u*16) ^ ((col & 7) << 4)));
                acc0 = __builtin_amdgcn_mfma_f32_16x16x32_bf16(a0[kc], bv, acc0, 0, 0, 0);
                acc1 = __builtin_amdgcn_mfma_f32_16x16x32_bf16(a1[kc], bv, acc1, 0, 0, 0);
            }
        }
    }

    if (CS > 0) {
        #pragma unroll
        for (int kc = 0; kc < KQS/4; ++kc) {
            short8 a0 = *(const short8*)(Ws + (size_t)(cwb + l15)*CS + kc*32 + gq*8);
            short8 a1 = *(const short8*)(Ws + (size_t)(cwb + 16 + l15)*CS + kc*32 + gq*8);
            int u = UX + (r*8 + w)*KQS + kc*4 + gq;
            short8 bv = *(const short8*)((const char*)lds4 + ((u*16) ^ ((w & 7) << 4)));
            acc0 = __builtin_amdgcn_mfma_f32_16x16x32_bf16(a0, bv, acc0, 0, 0, 0);
            acc1 = __builtin_amdgcn_mfma_f32_16x16x32_bf16(a1, bv, acc1, 0, 0, 0);
        }
    }

    const int hr = h0 + r;
    const bool valid = hr < 31;
#define EPIG8(ACC, G) do { \
    int cb = cwb + (G)*16 + gq*4; \
    float s0 = g[cb+0]*RSQ, s1 = g[cb+1]*RSQ, s2 = g[cb+2]*RSQ, s3 = g[cb+3]*RSQ; \
    float o0 = b[cb+0], o1 = b[cb+1], o2 = b[cb+2], o3 = b[cb+3]; \
    float v0 = ACC[0]*s0 + o0; v0 = (v0 >= 0.f) ? v0 : SLOPE*v0; \
    float v1 = ACC[1]*s1 + o1; v1 = (v1 >= 0.f) ? v1 : SLOPE*v1; \
    float v2 = ACC[2]*s2 + o2; v2 = (v2 >= 0.f) ? v2 : SLOPE*v2; \
    float v3 = ACC[3]*s3 + o3; v3 = (v3 >= 0.f) ? v3 : SLOPE*v3; \
    if (POOL) { \
        v0 = fmaxf(v0, __shfl_xor(v0, 1)); v0 = fmaxf(v0, __shfl_xor(v0, 2)); \
        v1 = fmaxf(v1, __shfl_xor(v1, 1)); v1 = fmaxf(v1, __shfl_xor(v1, 2)); \
        v2 = fmaxf(v2, __shfl_xor(v2, 1)); v2 = fmaxf(v2, __shfl_xor(v2, 2)); \
        v3 = fmaxf(v3, __shfl_xor(v3, 1)); v3 = fmaxf(v3, __shfl_xor(v3, 2)); \
        if (((l15 & 3) == 0) && valid) { \
            if (FEATS) { \
                int pw = w >> 2; \
                unsigned short* fp = O + ((size_t)(n*31 + hr))*512 + pw; \
                fp[(cb+0)*2] = f2bf(v0); \
                fp[(cb+1)*2] = f2bf(v1); \
                fp[(cb+2)*2] = f2bf(v2); \
                fp[(cb+3)*2] = f2bf(v3); \
            } else { \
                uint2 pk; \
                pk.x = (unsigned)f2bf(v0) | ((unsigned)f2bf(v1) << 16); \
                pk.y = (unsigned)f2bf(v2) | ((unsigned)f2bf(v3) << 16); \
                *(uint2*)(O + (((size_t)(n*31 + hr))*2 + (w >> 2))*Cout + cb) = pk; \
            } \
        } \
    } else if (valid) { \
        uint2 pk; \
        pk.x = (unsigned)f2bf(v0) | ((unsigned)f2bf(v1) << 16); \
        pk.y = (unsigned)f2bf(v2) | ((unsigned)f2bf(v3) << 16); \
        *(uint2*)(O + (((size_t)(n*34 + hr + 1))*10 + w + 1)*Cout + cb) = pk; \
    } \
} while(0)
    EPIG8(acc0, 0);
    EPIG8(acc1, 1);
#undef EPIG8
}

// ---------------- MFMA GEMM: C[M,N] = A[M,K](bf16) @ B[N,K]^T(bf16) + bias(+bias2), fp32 out ----------------
template<int XPOSE>
__launch_bounds__(256)
__global__ void gemm_mfma_kernel(const unsigned short* __restrict__ A,
                                 const unsigned short* __restrict__ B,
                                 const float* __restrict__ bias, const float* __restrict__ bias2,
                                 float* __restrict__ C, int M, int N, int K)
{
    const int lane = threadIdx.x & 63;
    const int wave = threadIdx.x >> 6;
    const int l15 = lane & 15;
    const int gq = lane >> 4;
    const int n0 = blockIdx.y*64 + wave*16;
    const int m0 = blockIdx.x*64;

    int nrow = n0 + l15; if (nrow > N-1) nrow = N-1;
    const unsigned short* bp = B + (size_t)nrow*K + gq*8;
    int mr[4];
    #pragma unroll
    for (int t = 0; t < 4; ++t) {
        int m = m0 + t*16 + l15;
        mr[t] = (m > M-1) ? (M-1) : m;
    }

    f32x4 acc[4] = {};
    for (int k0 = 0; k0 < K; k0 += 32) {
        short8 a = *(const short8*)(bp + k0);
        #pragma unroll
        for (int t = 0; t < 4; ++t) {
            short8 b = *(const short8*)(A + (size_t)mr[t]*K + gq*8 + k0);
            acc[t] = __builtin_amdgcn_mfma_f32_16x16x32_bf16(a, b, acc[t], 0, 0, 0);
        }
    }

    int nb = n0 + gq*4;
    float bs[4];
    #pragma unroll
    for (int j = 0; j < 4; ++j) {
        int n = nb + j; int nc = (n > N-1) ? (N-1) : n;
        bs[j] = (bias ? bias[nc] : 0.f) + (bias2 ? bias2[nc] : 0.f);
    }
    #pragma unroll
    for (int t = 0; t < 4; ++t) {
        int m = m0 + t*16 + l15;
        if (m >= M) continue;
        size_t rowoff = XPOSE ? ((size_t)(m % 31)*32 + (m / 31))*(size_t)N : (size_t)m*N;
        #pragma unroll
        for (int j = 0; j < 4; ++j) {
            int n = nb + j;
            if (n < N) C[rowoff + n] = acc[t][j] + bs[j];
        }
    }
}

// ---------------- LSTM scan via MFMA: 4 blocks = (dir x batch-half), 1024 thr ----------------
__launch_bounds__(1024)
__global__ void lstm_scan_mfma(const float* __restrict__ xpT,
                               const unsigned short* __restrict__ wf,
                               unsigned short* __restrict__ hcat)
{
    const int d  = blockIdx.x >> 1;
    const int bh = blockIdx.x & 1;
    const int tid = threadIdx.x;
    const int u0 = tid >> 6;
    const int lane = tid & 63;
    const int l15 = lane & 15;
    const int q = lane >> 4;

    __shared__ unsigned short hbuf[2][4096];          // 16 KB
    __shared__ unsigned short wst[16][2][2048];       // 128 KB

    ((int4*)hbuf)[tid & 1023] = make_int4(0,0,0,0);

    const unsigned short* wfd = wf + (size_t)d*262144;
    const float* xpd = xpT + (size_t)d*992*1024 + (size_t)bh*16*1024;
    const unsigned short* wsrc = wfd + (size_t)u0*4096 + (size_t)lane*8;
    unsigned short* wl = &wst[u0][0][0];

#define STAGE(KC, PB) do { \
    unsigned short* dst_ = wl + (PB)*2048; \
    stage16(wsrc + 0*65536 + (KC)*512, dst_ + 0*512); \
    stage16(wsrc + 1*65536 + (KC)*512, dst_ + 1*512); \
    stage16(wsrc + 2*65536 + (KC)*512, dst_ + 2*512); \
    stage16(wsrc + 3*65536 + (KC)*512, dst_ + 3*512); \
} while(0)

    float c0=0.f, c1=0.f, c2=0.f, c3=0.f;
    const int ubase = u0*16 + q*4;
    const int rb = l15*512 + q*16;
    const int xr = (l15&7)<<4;

    STAGE(0, 0);
    float4 xi, xf, xg, xo;
    {
        const int t0 = d ? 30 : 0;
        const float* xb = xpd + (size_t)t0*32768 + (size_t)l15*1024;
        xi = *(const float4*)(xb + ubase);
        xf = *(const float4*)(xb + 256 + ubase);
        xg = *(const float4*)(xb + 512 + ubase);
        xo = *(const float4*)(xb + 768 + ubase);
    }
    asm volatile("s_waitcnt lgkmcnt(0)" ::: "memory");
    __builtin_amdgcn_s_barrier();

#define HRD(kc)   (*(const short8*)(hb + ((rb + (kc)*64) ^ xr)))
#define MF(w_,h_,a_) a_ = __builtin_amdgcn_mfma_f32_16x16x32_bf16(w_, h_, a_, 0, 0, 0)

    for (int s = 0; s < 31; ++s) {
        const int t = d ? (30 - s) : s;
        const int cur = s & 1, nxt = cur ^ 1;

        const char* hb = (const char*)hbuf[cur];
        f32x4 a0={0,0,0,0}, a1={0,0,0,0}, a2={0,0,0,0}, a3={0,0,0,0};

        #pragma unroll
        for (int kc = 0; kc < 8; ++kc) {
            if (kc < 7) STAGE(kc+1, (kc+1)&1);
            else        STAGE(0, 0);
            if (kc == 0) asm volatile("s_waitcnt vmcnt(8)" ::: "memory");
            else         asm volatile("s_waitcnt vmcnt(4)" ::: "memory");
            const unsigned short* wb = wl + (kc&1)*2048;
            short8 w0 = *(const short8*)(wb + 0*512 + lane*8);
            short8 w1 = *(const short8*)(wb + 1*512 + lane*8);
            short8 w2 = *(const short8*)(wb + 2*512 + lane*8);
            short8 w3 = *(const short8*)(wb + 3*512 + lane*8);
            short8 h = HRD(kc);
            MF(w0,h,a0); MF(w1,h,a1); MF(w2,h,a2); MF(w3,h,a3);
        }

        float4 nxi, nxf, nxg, nxo;
        {
            int s2 = (s < 30) ? s + 1 : s;
            int t2 = d ? (30 - s2) : s2;
            const float* xb = xpd + (size_t)t2*32768 + (size_t)l15*1024;
            nxi = *(const float4*)(xb + ubase);
            nxf = *(const float4*)(xb + 256 + ubase);
            nxg = *(const float4*)(xb + 512 + ubase);
            nxo = *(const float4*)(xb + 768 + ubase);
        }

        float hv0, hv1, hv2, hv3;
        { float gi=a0[0]+xi.x, gf=a1[0]+xf.x, gg=a2[0]+xg.x, go=a3[0]+xo.x;
          float cn = sigmoidf_(gf)*c0 + sigmoidf_(gi)*tanhf(gg); c0 = cn; hv0 = sigmoidf_(go)*tanhf(cn); }
        { float gi=a0[1]+xi.y, gf=a1[1]+xf.y, gg=a2[1]+xg.y, go=a3[1]+xo.y;
          float cn = sigmoidf_(gf)*c1 + sigmoidf_(gi)*tanhf(gg); c1 = cn; hv1 = sigmoidf_(go)*tanhf(cn); }
        { float gi=a0[2]+xi.z, gf=a1[2]+xf.z, gg=a2[2]+xg.z, go=a3[2]+xo.z;
          float cn = sigmoidf_(gf)*c2 + sigmoidf_(gi)*tanhf(gg); c2 = cn; hv2 = sigmoidf_(go)*tanhf(cn); }
        { float gi=a0[3]+xi.w, gf=a1[3]+xf.w, gg=a2[3]+xg.w, go=a3[3]+xo.w;
          float cn = sigmoidf_(gf)*c3 + sigmoidf_(gi)*tanhf(gg); c3 = cn; hv3 = sigmoidf_(go)*tanhf(cn); }

        short4 hp;
        hp.x = (short)f2bf(hv0); hp.y = (short)f2bf(hv1);
        hp.z = (short)f2bf(hv2); hp.w = (short)f2bf(hv3);
        *(short4*)((char*)hbuf[nxt] + ((l15*512 + ubase*2) ^ xr)) = hp;
        int bg = bh*16 + l15;
        *(short4*)(&hcat[((size_t)bg*31 + t)*512 + (size_t)d*256 + ubase]) = hp;

        asm volatile("s_waitcnt lgkmcnt(0)" ::: "memory");
        __builtin_amdgcn_s_barrier();

        xi = nxi; xf = nxf; xg = nxg; xo = nxo;
    }
#undef STAGE
#undef HRD
#undef MF
}

extern "C" void kernel_launch(void* const* d_in, const int* in_sizes, int n_in,
                              void* d_out, int out_size, void* d_ws, size_t ws_size,
                              hipStream_t stream)
{
    const float* x    = (const float*)d_in[0];
    const float* fW   = (const float*)d_in[1];
    const float* fB   = (const float*)d_in[2];
    const float* cbw1 = (const float*)d_in[3];
    const float* cbg  = (const float*)d_in[4];
    const float* cbb  = (const float*)d_in[5];
    const float* cbw2 = (const float*)d_in[6];
    const float* r1pg = (const float*)d_in[7];
    const float* r1pb = (const float*)d_in[8];
    const float* r1wA = (const float*)d_in[9];
    const float* r1g  = (const float*)d_in[10];
    const float* r1b  = (const float*)d_in[11];
    const float* r1wB = (const float*)d_in[12];
    const float* r1s  = (const float*)d_in[13];
    const float* r2pg = (const float*)d_in[14];
    const float* r2pb = (const float*)d_in[15];
    const float* r2wA = (const float*)d_in[16];
    const float* r2g  = (const float*)d_in[17];
    const float* r2b  = (const float*)d_in[18];
    const float* r2wB = (const float*)d_in[19];
    const float* r2s  = (const float*)d_in[20];
    const float* r3pg = (const float*)d_in[21];
    const float* r3pb = (const float*)d_in[22];
    const float* r3wA = (const float*)d_in[23];
    const float* r3g  = (const float*)d_in[24];
    const float* r3b  = (const float*)d_in[25];
    const float* r3wB = (const float*)d_in[26];
    const float* r3s  = (const float*)d_in[27];
    const float* pbg  = (const float*)d_in[28];
    const float* pbb  = (const float*)d_in[29];
    const float* wih_f = (const float*)d_in[30];
    const float* whh_f = (const float*)d_in[31];
    const float* bih_f = (const float*)d_in[32];
    const float* bhh_f = (const float*)d_in[33];
    const float* wih_b = (const float*)d_in[34];
    const float* whh_b = (const float*)d_in[35];
    const float* bih_b = (const float*)d_in[36];
    const float* bhh_b = (const float*)d_in[37];
    const float* clsw  = (const float*)d_in[38];
    const float* clsb  = (const float*)d_in[39];
    float* out = (float*)d_out;
    float* ws  = (float*)d_ws;

    // ---- workspace sizing (floats) ----
    const size_t FIXEDF = 5745088;
    const size_t PCS = 2422720;
    const size_t PCF = (PCS + 1)/2;
    int NC = 0;
    const int cands[6] = {32,16,8,4,2,1};
    for (int i = 0; i < 6; ++i) {
        if ((FIXEDF + (size_t)cands[i]*PCF + 64)*sizeof(float) <= ws_size) { NC = cands[i]; break; }
    }
    if (!NC) return;

    float* p = ws;
    unsigned short* WTR  = (unsigned short*)p; p += 962560;
    unsigned short* WIHT = (unsigned short*)p; p += 524288;   // 2 x 1024x512 bf16
    unsigned short* CLST = (unsigned short*)p; p += 184832;   // 722x512 bf16
    float* P   = p; p += 508896;
    float* XM  = p; p += 508896;
    unsigned short* XP4 = (unsigned short*)p; p += 253952;    // (unused, layout kept)
    unsigned short* FEb = (unsigned short*)p; p += 253952;
    unsigned short* WF  = (unsigned short*)p; p += 262144;
    float* XPT = p; p += 2031616;
    unsigned short* HCb = (unsigned short*)p; p += 253952;
    unsigned short* q = (unsigned short*)p;
    unsigned short* A1  = q; q += (size_t)NC*1087680;
    unsigned short* C1p = q; q += (size_t)NC*274560;
    unsigned short* A2  = q; q += (size_t)NC*549120;
    unsigned short* C2p = q; q += (size_t)NC*143616;
    unsigned short* A3  = q; q += (size_t)NC*215424;
    unsigned short* XP3 = q; q += (size_t)NC*65280;
    unsigned short* A4  = q; q += (size_t)NC*87040;
    (void)XP4;

    unsigned short* w2T  = WTR + 0;
    unsigned short* r1AT = WTR + 36864;
    unsigned short* r1BT = WTR + 110592;
    unsigned short* r1ST = WTR + 258048;
    unsigned short* r2AT = WTR + 266240;
    unsigned short* r2BT = WTR + 487424;
    unsigned short* r2ST = WTR + 819200;
    unsigned short* r3AT = WTR + 843776;
    unsigned short* r3BT = WTR + 1286144;
    unsigned short* r3ST = WTR + 1875968;

    auto cdiv = [](int a, int b){ return (a + b - 1) / b; };

    // ---- ALL weight transforms in one launch ----
    XJobs jobs;
    jobs.s[0] = cbw2;  jobs.d[0] = w2T;
    jobs.s[1] = r1wA;  jobs.d[1] = r1AT;
    jobs.s[2] = r1wB;  jobs.d[2] = r1BT;
    jobs.s[3] = r1s;   jobs.d[3] = r1ST;
    jobs.s[4] = r2wA;  jobs.d[4] = r2AT;
    jobs.s[5] = r2wB;  jobs.d[5] = r2BT;
    jobs.s[6] = r2s;   jobs.d[6] = r2ST;
    jobs.s[7] = r3wA;  jobs.d[7] = r3AT;
    jobs.s[8] = r3wB;  jobs.d[8] = r3BT;
    jobs.s[9] = r3s;   jobs.d[9] = r3ST;
    jobs.s[10] = whh_f; jobs.d[10] = WF;
    jobs.s[11] = whh_b; jobs.d[11] = WF + 262144;
    jobs.s[12] = wih_f; jobs.d[12] = WIHT;
    jobs.s[13] = wih_b; jobs.d[13] = WIHT + 524288;
    jobs.s[14] = clsw;  jobs.d[14] = CLST;
    wtrans_all_kernel<<<dim3(2304, 15), 256, 0, stream>>>(jobs);

    // ---- frontend mask ----
    mask_partial_kernel<<<dim3(63, 32), 256, 0, stream>>>(fW, fB, P);
    mask_finalize_apply<<<63, 256, 0, stream>>>(P, x, XM);

    // ---- zero padded staging region (all halos stay zero) ----
    hipMemsetAsync(A1, 0, (size_t)NC*PCS*sizeof(unsigned short), stream);

    // ---- conv stack, chunked over batch ----
    for (int c0 = 0; c0 < 32; c0 += NC) {
        const float* xmc = XM + (size_t)c0*15903;
        conv1_kernel<<<dim3(63, 1, NC), 256, 0, stream>>>(xmc, cbw1, cbg, cbb, A1);
        conv_lds_kernel<64,8,0,1><<<dim3(4*31, 1, NC), 256, 0, stream>>>(
            A1, w2T, nullptr, nullptr, C1p, 515, 4, 0, 33, 1, 130, 1, 64, r1pg, r1pb);
        conv_lds_kernel<64,8,0,0><<<dim3(31, 2, NC), 256, 0, stream>>>(
            C1p, r1AT, nullptr, nullptr, A2, 130, 1, 0, 33, 1, 130, 1, 128, r1g, r1b);
        conv_lds_kernel<128,8,64,1><<<dim3(31, 2, NC), 256, 0, stream>>>(
            A2, r1BT, C1p, r1ST, C2p, 130, 1, 130, 33, 1, 34, 1, 128, r2pg, r2pb);
        conv_lds_kernel<128,2,0,0><<<dim3(31, 3, NC), 256, 0, stream>>>(
            C2p, r2AT, nullptr, nullptr, A3, 34, 1, 0, 33, 1, 34, 1, 192, r2g, r2b);
        conv_lds_kernel<192,2,128,1><<<dim3(31, 3, NC), 256, 0, stream>>>(
            A3, r2BT, C2p, r2ST, XP3, 34, 1, 34, 34, 1, 10, 1, 192, r3pg, r3pb);
        conv_w8_kernel<192,0,0,0><<<dim3(16, 2, NC), 256, 0, stream>>>(
            XP3, r3AT, nullptr, nullptr, A4, 256, r3g, r3b);
        // r3B + shortcut + bn+lrelu+pool(8->2) -> FEb feats layout directly
        conv_w8_kernel<256,192,1,1><<<dim3(16, 2, NC), 256, 0, stream>>>(
            A4, r3BT, XP3, r3ST, FEb + (size_t)c0*15872, 256, pbg, pbb);
    }

    // LSTM input projections (MFMA) -> xpT [d][t][b][j] fp32
    gemm_mfma_kernel<1><<<dim3(16, 16), 256, 0, stream>>>(FEb, WIHT,          bih_f, bhh_f, XPT,           992, 1024, 512);
    gemm_mfma_kernel<1><<<dim3(16, 16), 256, 0, stream>>>(FEb, WIHT + 524288, bih_b, bhh_b, XPT + 1015808, 992, 1024, 512);

    // fused bidirectional scan (4 blocks: dir x batch-half), hcat bf16
    lstm_scan_mfma<<<4, 1024, 0, stream>>>(XPT, WF, HCb);

    // classifier (MFMA) -> d_out (32,31,722) fp32
    gemm_mfma_kernel<0><<<dim3(16, 12), 256, 0, stream>>>(HCb, CLST, clsb, nullptr, out, 992, 722, 512);
}

// Round 20
// 880.692 us; speedup vs baseline: 2.0471x; 1.0247x over previous
//
#include <hip/hip_runtime.h>
#include <hip/hip_bf16.h>
#include <math.h>

#define RSQ 0.99999500003749969f   // 1/sqrt(1+1e-5)
#define SLOPE 0.01f

typedef __attribute__((ext_vector_type(8))) short short8;
typedef __attribute__((ext_vector_type(4))) float f32x4;

__device__ __forceinline__ float sigmoidf_(float x){ return 1.0f/(1.0f+expf(-x)); }

__device__ __forceinline__ unsigned short f2bf(float f){
    unsigned u = __float_as_uint(f);
    u += 0x7fff + ((u >> 16) & 1);      // RNE
    return (unsigned short)(u >> 16);
}
__device__ __forceinline__ float bf2f(unsigned short s){
    return __uint_as_float(((unsigned)s) << 16);
}

// async global->LDS, 16B per lane; LDS dest is wave-uniform base + lane*16
__device__ __forceinline__ void stage16(const unsigned short* g, unsigned short* l) {
    __builtin_amdgcn_global_load_lds(
        (const __attribute__((address_space(1))) unsigned int*)g,
        (__attribute__((address_space(3))) unsigned int*)l, 16, 0, 0);
}

// ---------------- mask: prod_k cos(fW*rng + fB) ----------------
__global__ void mask_partial_kernel(const float* __restrict__ fW, const float* __restrict__ fB,
                                    float* __restrict__ partial)
{
    int p = blockIdx.x*256 + threadIdx.x;   // 0..15902
    if (p >= 15903) return;
    int w = p % 513;
    float r = (float)(w + 1);
    int k0 = blockIdx.y * 32;
    float prod = 1.0f;
    for (int k = k0; k < k0 + 32; ++k) {
        float a = fW[(size_t)k*15903 + p] * r + fB[(size_t)k*15903 + p];
        prod *= cosf(a);
    }
    partial[blockIdx.y*15903 + p] = prod;
}

__global__ void mask_finalize_apply(const float* __restrict__ partial, const float* __restrict__ x,
                                    float* __restrict__ xm)
{
    int p = blockIdx.x*256 + threadIdx.x;
    if (p >= 15903) return;
    float m = 1.0f;
    #pragma unroll
    for (int c = 0; c < 32; ++c) m *= partial[c*15903 + p];
    for (int n = 0; n < 32; ++n)
        xm[(size_t)n*15903 + p] = x[(size_t)n*15903 + p] * m;
}

// ---------------- ALL weight transforms in one launch (job table) ----------------
struct XJobs { const float* s[15]; unsigned short* d[15]; };

__global__ void wtrans_all_kernel(XJobs j)
{
    // type: 0 = OIHW->(tap,co,ci), 1 = flat bf16 cast, 2 = whh fragment pack
    constexpr int TYPE[15] = {0,0,0,1,0,0,1,0,0,1,2,2,1,1,1};
    constexpr int TOT[15]  = {36864,73728,147456,8192,221184,331776,24576,
                              442368,589824,49152,262144,262144,524288,524288,369664};
    constexpr int COUT[15] = {64,128,128,0,192,192,0,256,256,0,0,0,0,0,0};
    constexpr int CIN[15]  = {64,64,128,0,128,192,0,192,256,0,0,0,0,0,0};

    const int job = blockIdx.y;
    const int idx = blockIdx.x*256 + threadIdx.x;
    if (idx >= TOT[job]) return;
    const float* w = j.s[job];
    unsigned short* o = j.d[job];

    if (TYPE[job] == 0) {
        int cc = COUT[job]*CIN[job];
        int tap = idx / cc;
        int r = idx - tap*cc;
        int co = r / CIN[job], ci = r - co*CIN[job];
        int kh = tap/3, kw = tap - kh*3;
        o[idx] = f2bf(w[((size_t)(co*CIN[job] + ci)*3 + kh)*3 + kw]);
    } else if (TYPE[job] == 1) {
        o[idx] = f2bf(w[idx]);
    } else {
        int e    = idx & 7;
        int lane = (idx >> 3) & 63;
        int kc   = (idx >> 9) & 7;
        int u0   = (idx >> 12) & 15;
        int g    = idx >> 16;
        int jj = (g << 8) + (u0 << 4) + (lane & 15);
        int k  = (kc << 5) + ((lane >> 4) << 3) + e;
        o[idx] = f2bf(w[(size_t)jj*256 + k]);
    }
}

// ---------------- halo zeroing: only the padded border cells of the 7 staging buffers ----------------
// Interior cells are fully rewritten by producer kernels each call; halos stay zero.
struct HaloPtrs { unsigned short* b[7]; };

__global__ void halo_zero_kernel(HaloPtrs hp)
{
    // buffers: A1[33][515][64], C1p[33][130][64], A2[33][130][128], C2p[33][34][128],
    //          A3[33][34][192], XP3[34][10][192], A4[34][10][256]
    constexpr int WP[7]   = {515,130,130,34,34,10,10};
    constexpr int NRH[7]  = {2,2,2,2,2,3,3};          // halo rows: 0,32[,33]
    constexpr int CC8[7]  = {8,8,16,16,24,24,32};     // C/8 (uint4 units per px)
    constexpr int UNITS[7]= {8736,2576,5152,2080,3120,2208,2944};  // haloPx * CC8
    constexpr size_t IMG[7] = {1087680,274560,549120,143616,215424,65280,87040};

    const int j   = blockIdx.y;
    const int img = blockIdx.z;
    const int idx = blockIdx.x*256 + threadIdx.x;
    if (idx >= UNITS[j]) return;

    const int cc8 = CC8[j], wp = WP[j], nrh = NRH[j];
    int cq  = idx % cc8;
    int hpx = idx / cc8;
    int row, col;
    if (hpx < nrh*wp) {                         // full halo rows
        row = (hpx < wp) ? 0 : ((hpx < 2*wp) ? 32 : 33);
        col = hpx % wp;
    } else {                                    // side columns of rows 1..31
        int k = hpx - nrh*wp;
        row = 1 + (k >> 1);
        col = (k & 1) ? (wp - 1) : 0;
    }
    *(uint4*)(hp.b[j] + IMG[j]*img + ((size_t)row*wp + col)*(size_t)(cc8*8) + cq*8) =
        make_uint4(0,0,0,0);
}

// ---------------- conv1: Cin=1 direct, fp32 in -> bf16 NHWC (rows 1..31 of [33][515][64]) ----------------
__launch_bounds__(256)
__global__ void conv1_kernel(const float* __restrict__ xm, const float* __restrict__ w1,
                             const float* __restrict__ g, const float* __restrict__ b,
                             unsigned short* __restrict__ O)
{
    __shared__ float wl[576];
    __shared__ float sg[64], sb[64];
    int tid = threadIdx.x;
    if (tid < 64) { sg[tid] = g[tid]*RSQ; sb[tid] = b[tid]; }
    for (int i = tid; i < 576; i += 256) wl[i] = w1[i];
    __syncthreads();
    int px = blockIdx.x*256 + tid;
    int n = blockIdx.z;
    if (px >= 15903) return;
    int h = px / 513, w = px - h*513;
    const float* xp = xm + (size_t)n*15903;
    float v[9];
    #pragma unroll
    for (int dh = 0; dh < 3; ++dh)
      #pragma unroll
      for (int dw = 0; dw < 3; ++dw) {
        int hh = h+dh-1, ww = w+dw-1;
        bool ok = ((unsigned)hh < 31u) && ((unsigned)ww < 513u);
        v[dh*3+dw] = ok ? xp[hh*513 + ww] : 0.f;
      }
    unsigned short* op = O + (((size_t)(n*33 + h + 1))*515 + (w + 1))*64;
    #pragma unroll
    for (int c8 = 0; c8 < 8; ++c8) {
        unsigned tmp[8];
        #pragma unroll
        for (int j = 0; j < 8; ++j) {
            int co = c8*8 + j;
            const float* wr = &wl[co*9];
            float a = 0.f;
            #pragma unroll
            for (int t2 = 0; t2 < 9; ++t2) a += wr[t2]*v[t2];
            a = a*sg[co] + sb[co];
            a = (a >= 0.f) ? a : SLOPE*a;
            tmp[j] = f2bf(a);
        }
        uint4 pk;
        pk.x = tmp[0] | (tmp[1]<<16);
        pk.y = tmp[2] | (tmp[3]<<16);
        pk.z = tmp[4] | (tmp[5]<<16);
        pk.w = tmp[6] | (tmp[7]<<16);
        *(uint4*)(op + c8*8) = pk;
    }
}

// ---------------- LDS-staged implicit-GEMM 3x3 conv (+1x1 shortcut) via MFMA ----------------
template<int CIN, int TPX, int CS, int POOL>
__launch_bounds__(256, 2)
__global__ void conv_lds_kernel(const unsigned short* __restrict__ X,
                                const unsigned short* __restrict__ W9,
                                const unsigned short* __restrict__ Xs,
                                const unsigned short* __restrict__ Ws,
                                unsigned short* __restrict__ O,
                                int Wp, int WT, int WpS,
                                int HO, int HOFF, int WpO, int OOFF, int Cout,
                                const float* __restrict__ g, const float* __restrict__ b)
{
    constexpr int KQ  = CIN/8;
    constexpr int PXT = TPX*16 + 2;
    constexpr int UX  = 3*PXT*KQ;
    constexpr int KQS = (CS > 0) ? CS/8 : 8;
    constexpr int US  = (CS > 0) ? TPX*16*KQS : 0;
    constexpr int UT  = UX + US;
    constexpr int NU  = (UT + 255)/256;
    constexpr int NKC = CIN/32;
    __shared__ uint4 lds4[UT + 8];

    const int tid = threadIdx.x;
    const int lane = tid & 63;
    const int wave = tid >> 6;
    const int cob  = blockIdx.y*64 + wave*16;
    const int n  = blockIdx.z;
    const int wt = blockIdx.x % WT;
    const int h  = blockIdx.x / WT;
    const int w0 = wt*(TPX*16);
    const int l15 = lane & 15;
    const int gq  = lane >> 4;

    #pragma unroll
    for (int i = 0; i < NU; ++i) {
        int v = tid + i*256;
        unsigned short* ldst = (unsigned short*)lds4 + (size_t)(i*256 + wave*64)*8;
        if (v < UX) {
            int r   = v / (PXT*KQ);
            int rem = v - r*(PXT*KQ);
            int px  = rem / KQ;
            int kq  = rem - px*KQ;
            int kqs = kq ^ (px & 7);
            stage16(X + (((size_t)(n*33 + h + r))*Wp + w0 + px)*CIN + kqs*8, ldst);
        } else if (CS > 0 && v < UT) {
            int us = v - UX;
            int px = us / KQS;
            int kq = us - px*KQS;
            int kqs = kq ^ (px & 7);
            stage16(Xs + (((size_t)(n*33 + h + 1))*WpS + w0 + 1 + px)*CS + kqs*8, ldst);
        }
    }
    __syncthreads();

    f32x4 acc[TPX] = {};
    #pragma unroll
    for (int dh = 0; dh < 3; ++dh) {
        short8 aw[3*NKC];
        #pragma unroll
        for (int dw = 0; dw < 3; ++dw)
            #pragma unroll
            for (int kc = 0; kc < NKC; ++kc)
                aw[dw*NKC + kc] = *(const short8*)(W9 +
                    ((size_t)((dh*3 + dw)*Cout + cob + l15))*CIN + kc*32 + gq*8);
        #pragma unroll
        for (int dw = 0; dw < 3; ++dw) {
            #pragma unroll
            for (int kc = 0; kc < NKC; ++kc) {
                short8 a = aw[dw*NKC + kc];
                #pragma unroll
                for (int t = 0; t < TPX; ++t) {
                    int px = dw + t*16 + l15;
                    int u  = (dh*PXT + px)*KQ + kc*4 + gq;
                    short8 bv = *(const short8*)((const char*)lds4 + ((u*16) ^ ((px & 7) << 4)));
                    acc[t] = __builtin_amdgcn_mfma_f32_16x16x32_bf16(a, bv, acc[t], 0, 0, 0);
                }
            }
        }
    }

    if (CS > 0) {
        #pragma unroll
        for (int kc = 0; kc < KQS/4; ++kc) {
            short8 a = *(const short8*)(Ws + (size_t)(cob + l15)*CS + kc*32 + gq*8);
            #pragma unroll
            for (int t = 0; t < TPX; ++t) {
                int px = t*16 + l15;
                int u  = UX + px*KQS + kc*4 + gq;
                short8 bv = *(const short8*)((const char*)lds4 + ((u*16) ^ ((px & 7) << 4)));
                acc[t] = __builtin_amdgcn_mfma_f32_16x16x32_bf16(a, bv, acc[t], 0, 0, 0);
            }
        }
    }

    int cb = cob + gq*4;
    float s0 = g[cb+0]*RSQ, s1 = g[cb+1]*RSQ, s2 = g[cb+2]*RSQ, s3 = g[cb+3]*RSQ;
    float o0 = b[cb+0], o1 = b[cb+1], o2 = b[cb+2], o3 = b[cb+3];
    #pragma unroll
    for (int t = 0; t < TPX; ++t) {
        float v0 = acc[t][0]*s0 + o0; v0 = (v0 >= 0.f) ? v0 : SLOPE*v0;
        float v1 = acc[t][1]*s1 + o1; v1 = (v1 >= 0.f) ? v1 : SLOPE*v1;
        float v2 = acc[t][2]*s2 + o2; v2 = (v2 >= 0.f) ? v2 : SLOPE*v2;
        float v3 = acc[t][3]*s3 + o3; v3 = (v3 >= 0.f) ? v3 : SLOPE*v3;
        if (POOL) {
            v0 = fmaxf(v0, __shfl_xor(v0, 1)); v0 = fmaxf(v0, __shfl_xor(v0, 2));
            v1 = fmaxf(v1, __shfl_xor(v1, 1)); v1 = fmaxf(v1, __shfl_xor(v1, 2));
            v2 = fmaxf(v2, __shfl_xor(v2, 1)); v2 = fmaxf(v2, __shfl_xor(v2, 2));
            v3 = fmaxf(v3, __shfl_xor(v3, 1)); v3 = fmaxf(v3, __shfl_xor(v3, 2));
            if ((l15 & 3) == 0) {
                int pw = (w0 + t*16 + l15) >> 2;
                uint2 pk;
                pk.x = (unsigned)f2bf(v0) | ((unsigned)f2bf(v1) << 16);
                pk.y = (unsigned)f2bf(v2) | ((unsigned)f2bf(v3) << 16);
                *(uint2*)(O + (((size_t)(n*HO + h + HOFF))*WpO + pw + OOFF)*Cout + cb) = pk;
            }
        } else {
            int w = w0 + t*16 + l15;
            uint2 pk;
            pk.x = (unsigned)f2bf(v0) | ((unsigned)f2bf(v1) << 16);
            pk.y = (unsigned)f2bf(v2) | ((unsigned)f2bf(v3) << 16);
            *(uint2*)(O + (((size_t)(n*HO + h + HOFF))*WpO + w + OOFF)*Cout + cb) = pk;
        }
    }
}

// ---------------- W=8 LDS-staged conv for r3 layers ----------------
// FEATS=1 (with POOL=1): write [n][31][512] feats layout directly (c*2 + pw).
template<int CIN, int CS, int POOL, int FEATS>
__launch_bounds__(256, 2)
__global__ void conv_w8_kernel(const unsigned short* __restrict__ X,
                               const unsigned short* __restrict__ W9,
                               const unsigned short* __restrict__ Xs,
                               const unsigned short* __restrict__ Ws,
                               unsigned short* __restrict__ O, int Cout,
                               const float* __restrict__ g, const float* __restrict__ b)
{
    constexpr int KQ  = CIN/8;
    constexpr int UX  = 4*10*KQ;
    constexpr int KQS = (CS > 0) ? CS/8 : 8;
    constexpr int US  = (CS > 0) ? 2*8*KQS : 0;
    constexpr int UT  = UX + US;
    constexpr int NU  = (UT + 255)/256;
    constexpr int NKC = CIN/32;
    __shared__ uint4 lds4[UT + 8];

    const int tid = threadIdx.x;
    const int lane = tid & 63;
    const int wave = tid >> 6;
    const int hp = blockIdx.x;          // 0..15
    const int n  = blockIdx.z;
    const int h0 = hp*2;
    const int l15 = lane & 15;
    const int gq  = lane >> 4;
    const int r = l15 >> 3;
    const int w = l15 & 7;
    const int cwb = blockIdx.y*128 + wave*32;

    #pragma unroll
    for (int i = 0; i < NU; ++i) {
        int v = tid + i*256;
        unsigned short* ldst = (unsigned short*)lds4 + (size_t)(i*256 + wave*64)*8;
        if (v < UX) {
            int row = v / (10*KQ);
            int rem = v - row*(10*KQ);
            int px  = rem / KQ;
            int kq  = rem - px*KQ;
            int kqs = kq ^ (px & 7);
            stage16(X + (((size_t)(n*34 + h0 + row))*10 + px)*CIN + kqs*8, ldst);
        } else if (CS > 0 && v < UT) {
            int us = v - UX;
            int rs = us / (8*KQS);
            int rem = us - rs*(8*KQS);
            int px8 = rem / KQS;
            int kq  = rem - px8*KQS;
            int kqs = kq ^ (px8 & 7);
            stage16(Xs + (((size_t)(n*34 + h0 + 1 + rs))*10 + px8 + 1)*CS + kqs*8, ldst);
        }
    }
    __syncthreads();

    f32x4 acc0 = {0,0,0,0}, acc1 = {0,0,0,0};
    #pragma unroll
    for (int dh = 0; dh < 3; ++dh) {
        #pragma unroll
        for (int dw = 0; dw < 3; ++dw) {
            short8 a0[NKC], a1[NKC];
            #pragma unroll
            for (int kc = 0; kc < NKC; ++kc) {
                a0[kc] = *(const short8*)(W9 + ((size_t)((dh*3+dw)*Cout + cwb + l15))*CIN + kc*32 + gq*8);
                a1[kc] = *(const short8*)(W9 + ((size_t)((dh*3+dw)*Cout + cwb + 16 + l15))*CIN + kc*32 + gq*8);
            }
            #pragma unroll
            for (int kc = 0; kc < NKC; ++kc) {
                int row_s = r + dh;
                int col = w + dw;
                int u = (row_s*10 + col)*KQ + kc*4 + gq;
                short8 bv = *(const short8*)((const char*)lds4 + ((u*16) ^ ((col & 7) << 4)));
                acc0 = __builtin_amdgcn_mfma_f32_16x16x32_bf16(a0[kc], bv, acc0, 0, 0, 0);
                acc1 = __builtin_amdgcn_mfma_f32_16x16x32_bf16(a1[kc], bv, acc1, 0, 0, 0);
            }
        }
    }

    if (CS > 0) {
        #pragma unroll
        for (int kc = 0; kc < KQS/4; ++kc) {
            short8 a0 = *(const short8*)(Ws + (size_t)(cwb + l15)*CS + kc*32 + gq*8);
            short8 a1 = *(const short8*)(Ws + (size_t)(cwb + 16 + l15)*CS + kc*32 + gq*8);
            int u = UX + (r*8 + w)*KQS + kc*4 + gq;
            short8 bv = *(const short8*)((const char*)lds4 + ((u*16) ^ ((w & 7) << 4)));
            acc0 = __builtin_amdgcn_mfma_f32_16x16x32_bf16(a0, bv, acc0, 0, 0, 0);
            acc1 = __builtin_amdgcn_mfma_f32_16x16x32_bf16(a1, bv, acc1, 0, 0, 0);
        }
    }

    const int hr = h0 + r;
    const bool valid = hr < 31;
#define EPIG8(ACC, G) do { \
    int cb = cwb + (G)*16 + gq*4; \
    float s0 = g[cb+0]*RSQ, s1 = g[cb+1]*RSQ, s2 = g[cb+2]*RSQ, s3 = g[cb+3]*RSQ; \
    float o0 = b[cb+0], o1 = b[cb+1], o2 = b[cb+2], o3 = b[cb+3]; \
    float v0 = ACC[0]*s0 + o0; v0 = (v0 >= 0.f) ? v0 : SLOPE*v0; \
    float v1 = ACC[1]*s1 + o1; v1 = (v1 >= 0.f) ? v1 : SLOPE*v1; \
    float v2 = ACC[2]*s2 + o2; v2 = (v2 >= 0.f) ? v2 : SLOPE*v2; \
    float v3 = ACC[3]*s3 + o3; v3 = (v3 >= 0.f) ? v3 : SLOPE*v3; \
    if (POOL) { \
        v0 = fmaxf(v0, __shfl_xor(v0, 1)); v0 = fmaxf(v0, __shfl_xor(v0, 2)); \
        v1 = fmaxf(v1, __shfl_xor(v1, 1)); v1 = fmaxf(v1, __shfl_xor(v1, 2)); \
        v2 = fmaxf(v2, __shfl_xor(v2, 1)); v2 = fmaxf(v2, __shfl_xor(v2, 2)); \
        v3 = fmaxf(v3, __shfl_xor(v3, 1)); v3 = fmaxf(v3, __shfl_xor(v3, 2)); \
        if (((l15 & 3) == 0) && valid) { \
            if (FEATS) { \
                int pw = w >> 2; \
                unsigned short* fp = O + ((size_t)(n*31 + hr))*512 + pw; \
                fp[(cb+0)*2] = f2bf(v0); \
                fp[(cb+1)*2] = f2bf(v1); \
                fp[(cb+2)*2] = f2bf(v2); \
                fp[(cb+3)*2] = f2bf(v3); \
            } else { \
                uint2 pk; \
                pk.x = (unsigned)f2bf(v0) | ((unsigned)f2bf(v1) << 16); \
                pk.y = (unsigned)f2bf(v2) | ((unsigned)f2bf(v3) << 16); \
                *(uint2*)(O + (((size_t)(n*31 + hr))*2 + (w >> 2))*Cout + cb) = pk; \
            } \
        } \
    } else if (valid) { \
        uint2 pk; \
        pk.x = (unsigned)f2bf(v0) | ((unsigned)f2bf(v1) << 16); \
        pk.y = (unsigned)f2bf(v2) | ((unsigned)f2bf(v3) << 16); \
        *(uint2*)(O + (((size_t)(n*34 + hr + 1))*10 + w + 1)*Cout + cb) = pk; \
    } \
} while(0)
    EPIG8(acc0, 0);
    EPIG8(acc1, 1);
#undef EPIG8
}

// ---------------- MFMA GEMM: C[M,N] = A[M,K](bf16) @ B[N,K]^T(bf16) + bias(+bias2), fp32 out ----------------
template<int XPOSE>
__launch_bounds__(256)
__global__ void gemm_mfma_kernel(const unsigned short* __restrict__ A,
                                 const unsigned short* __restrict__ B,
                                 const float* __restrict__ bias, const float* __restrict__ bias2,
                                 float* __restrict__ C, int M, int N, int K)
{
    const int lane = threadIdx.x & 63;
    const int wave = threadIdx.x >> 6;
    const int l15 = lane & 15;
    const int gq = lane >> 4;
    const int n0 = blockIdx.y*64 + wave*16;
    const int m0 = blockIdx.x*64;

    int nrow = n0 + l15; if (nrow > N-1) nrow = N-1;
    const unsigned short* bp = B + (size_t)nrow*K + gq*8;
    int mr[4];
    #pragma unroll
    for (int t = 0; t < 4; ++t) {
        int m = m0 + t*16 + l15;
        mr[t] = (m > M-1) ? (M-1) : m;
    }

    f32x4 acc[4] = {};
    for (int k0 = 0; k0 < K; k0 += 32) {
        short8 a = *(const short8*)(bp + k0);
        #pragma unroll
        for (int t = 0; t < 4; ++t) {
            short8 b = *(const short8*)(A + (size_t)mr[t]*K + gq*8 + k0);
            acc[t] = __builtin_amdgcn_mfma_f32_16x16x32_bf16(a, b, acc[t], 0, 0, 0);
        }
    }

    int nb = n0 + gq*4;
    float bs[4];
    #pragma unroll
    for (int j = 0; j < 4; ++j) {
        int n = nb + j; int nc = (n > N-1) ? (N-1) : n;
        bs[j] = (bias ? bias[nc] : 0.f) + (bias2 ? bias2[nc] : 0.f);
    }
    #pragma unroll
    for (int t = 0; t < 4; ++t) {
        int m = m0 + t*16 + l15;
        if (m >= M) continue;
        size_t rowoff = XPOSE ? ((size_t)(m % 31)*32 + (m / 31))*(size_t)N : (size_t)m*N;
        #pragma unroll
        for (int j = 0; j < 4; ++j) {
            int n = nb + j;
            if (n < N) C[rowoff + n] = acc[t][j] + bs[j];
        }
    }
}

// ---------------- LSTM scan via MFMA: 4 blocks = (dir x batch-half), 1024 thr ----------------
__launch_bounds__(1024)
__global__ void lstm_scan_mfma(const float* __restrict__ xpT,
                               const unsigned short* __restrict__ wf,
                               unsigned short* __restrict__ hcat)
{
    const int d  = blockIdx.x >> 1;
    const int bh = blockIdx.x & 1;
    const int tid = threadIdx.x;
    const int u0 = tid >> 6;
    const int lane = tid & 63;
    const int l15 = lane & 15;
    const int q = lane >> 4;

    __shared__ unsigned short hbuf[2][4096];          // 16 KB
    __shared__ unsigned short wst[16][2][2048];       // 128 KB

    ((int4*)hbuf)[tid & 1023] = make_int4(0,0,0,0);

    const unsigned short* wfd = wf + (size_t)d*262144;
    const float* xpd = xpT + (size_t)d*992*1024 + (size_t)bh*16*1024;
    const unsigned short* wsrc = wfd + (size_t)u0*4096 + (size_t)lane*8;
    unsigned short* wl = &wst[u0][0][0];

#define STAGE(KC, PB) do { \
    unsigned short* dst_ = wl + (PB)*2048; \
    stage16(wsrc + 0*65536 + (KC)*512, dst_ + 0*512); \
    stage16(wsrc + 1*65536 + (KC)*512, dst_ + 1*512); \
    stage16(wsrc + 2*65536 + (KC)*512, dst_ + 2*512); \
    stage16(wsrc + 3*65536 + (KC)*512, dst_ + 3*512); \
} while(0)

    float c0=0.f, c1=0.f, c2=0.f, c3=0.f;
    const int ubase = u0*16 + q*4;
    const int rb = l15*512 + q*16;
    const int xr = (l15&7)<<4;

    STAGE(0, 0);
    float4 xi, xf, xg, xo;
    {
        const int t0 = d ? 30 : 0;
        const float* xb = xpd + (size_t)t0*32768 + (size_t)l15*1024;
        xi = *(const float4*)(xb + ubase);
        xf = *(const float4*)(xb + 256 + ubase);
        xg = *(const float4*)(xb + 512 + ubase);
        xo = *(const float4*)(xb + 768 + ubase);
    }
    asm volatile("s_waitcnt lgkmcnt(0)" ::: "memory");
    __builtin_amdgcn_s_barrier();

#define HRD(kc)   (*(const short8*)(hb + ((rb + (kc)*64) ^ xr)))
#define MF(w_,h_,a_) a_ = __builtin_amdgcn_mfma_f32_16x16x32_bf16(w_, h_, a_, 0, 0, 0)

    for (int s = 0; s < 31; ++s) {
        const int t = d ? (30 - s) : s;
        const int cur = s & 1, nxt = cur ^ 1;

        const char* hb = (const char*)hbuf[cur];
        f32x4 a0={0,0,0,0}, a1={0,0,0,0}, a2={0,0,0,0}, a3={0,0,0,0};

        #pragma unroll
        for (int kc = 0; kc < 8; ++kc) {
            if (kc < 7) STAGE(kc+1, (kc+1)&1);
            else        STAGE(0, 0);
            if (kc == 0) asm volatile("s_waitcnt vmcnt(8)" ::: "memory");
            else         asm volatile("s_waitcnt vmcnt(4)" ::: "memory");
            const unsigned short* wb = wl + (kc&1)*2048;
            short8 w0 = *(const short8*)(wb + 0*512 + lane*8);
            short8 w1 = *(const short8*)(wb + 1*512 + lane*8);
            short8 w2 = *(const short8*)(wb + 2*512 + lane*8);
            short8 w3 = *(const short8*)(wb + 3*512 + lane*8);
            short8 h = HRD(kc);
            MF(w0,h,a0); MF(w1,h,a1); MF(w2,h,a2); MF(w3,h,a3);
        }

        float4 nxi, nxf, nxg, nxo;
        {
            int s2 = (s < 30) ? s + 1 : s;
            int t2 = d ? (30 - s2) : s2;
            const float* xb = xpd + (size_t)t2*32768 + (size_t)l15*1024;
            nxi = *(const float4*)(xb + ubase);
            nxf = *(const float4*)(xb + 256 + ubase);
            nxg = *(const float4*)(xb + 512 + ubase);
            nxo = *(const float4*)(xb + 768 + ubase);
        }

        float hv0, hv1, hv2, hv3;
        { float gi=a0[0]+xi.x, gf=a1[0]+xf.x, gg=a2[0]+xg.x, go=a3[0]+xo.x;
          float cn = sigmoidf_(gf)*c0 + sigmoidf_(gi)*tanhf(gg); c0 = cn; hv0 = sigmoidf_(go)*tanhf(cn); }
        { float gi=a0[1]+xi.y, gf=a1[1]+xf.y, gg=a2[1]+xg.y, go=a3[1]+xo.y;
          float cn = sigmoidf_(gf)*c1 + sigmoidf_(gi)*tanhf(gg); c1 = cn; hv1 = sigmoidf_(go)*tanhf(cn); }
        { float gi=a0[2]+xi.z, gf=a1[2]+xf.z, gg=a2[2]+xg.z, go=a3[2]+xo.z;
          float cn = sigmoidf_(gf)*c2 + sigmoidf_(gi)*tanhf(gg); c2 = cn; hv2 = sigmoidf_(go)*tanhf(cn); }
        { float gi=a0[3]+xi.w, gf=a1[3]+xf.w, gg=a2[3]+xg.w, go=a3[3]+xo.w;
          float cn = sigmoidf_(gf)*c3 + sigmoidf_(gi)*tanhf(gg); c3 = cn; hv3 = sigmoidf_(go)*tanhf(cn); }

        short4 hp;
        hp.x = (short)f2bf(hv0); hp.y = (short)f2bf(hv1);
        hp.z = (short)f2bf(hv2); hp.w = (short)f2bf(hv3);
        *(short4*)((char*)hbuf[nxt] + ((l15*512 + ubase*2) ^ xr)) = hp;
        int bg = bh*16 + l15;
        *(short4*)(&hcat[((size_t)bg*31 + t)*512 + (size_t)d*256 + ubase]) = hp;

        asm volatile("s_waitcnt lgkmcnt(0)" ::: "memory");
        __builtin_amdgcn_s_barrier();

        xi = nxi; xf = nxf; xg = nxg; xo = nxo;
    }
#undef STAGE
#undef HRD
#undef MF
}

extern "C" void kernel_launch(void* const* d_in, const int* in_sizes, int n_in,
                              void* d_out, int out_size, void* d_ws, size_t ws_size,
                              hipStream_t stream)
{
    const float* x    = (const float*)d_in[0];
    const float* fW   = (const float*)d_in[1];
    const float* fB   = (const float*)d_in[2];
    const float* cbw1 = (const float*)d_in[3];
    const float* cbg  = (const float*)d_in[4];
    const float* cbb  = (const float*)d_in[5];
    const float* cbw2 = (const float*)d_in[6];
    const float* r1pg = (const float*)d_in[7];
    const float* r1pb = (const float*)d_in[8];
    const float* r1wA = (const float*)d_in[9];
    const float* r1g  = (const float*)d_in[10];
    const float* r1b  = (const float*)d_in[11];
    const float* r1wB = (const float*)d_in[12];
    const float* r1s  = (const float*)d_in[13];
    const float* r2pg = (const float*)d_in[14];
    const float* r2pb = (const float*)d_in[15];
    const float* r2wA = (const float*)d_in[16];
    const float* r2g  = (const float*)d_in[17];
    const float* r2b  = (const float*)d_in[18];
    const float* r2wB = (const float*)d_in[19];
    const float* r2s  = (const float*)d_in[20];
    const float* r3pg = (const float*)d_in[21];
    const float* r3pb = (const float*)d_in[22];
    const float* r3wA = (const float*)d_in[23];
    const float* r3g  = (const float*)d_in[24];
    const float* r3b  = (const float*)d_in[25];
    const float* r3wB = (const float*)d_in[26];
    const float* r3s  = (const float*)d_in[27];
    const float* pbg  = (const float*)d_in[28];
    const float* pbb  = (const float*)d_in[29];
    const float* wih_f = (const float*)d_in[30];
    const float* whh_f = (const float*)d_in[31];
    const float* bih_f = (const float*)d_in[32];
    const float* bhh_f = (const float*)d_in[33];
    const float* wih_b = (const float*)d_in[34];
    const float* whh_b = (const float*)d_in[35];
    const float* bih_b = (const float*)d_in[36];
    const float* bhh_b = (const float*)d_in[37];
    const float* clsw  = (const float*)d_in[38];
    const float* clsb  = (const float*)d_in[39];
    float* out = (float*)d_out;
    float* ws  = (float*)d_ws;

    // ---- workspace sizing (floats) ----
    const size_t FIXEDF = 5745088;
    const size_t PCS = 2422720;
    const size_t PCF = (PCS + 1)/2;
    int NC = 0;
    const int cands[6] = {32,16,8,4,2,1};
    for (int i = 0; i < 6; ++i) {
        if ((FIXEDF + (size_t)cands[i]*PCF + 64)*sizeof(float) <= ws_size) { NC = cands[i]; break; }
    }
    if (!NC) return;

    float* p = ws;
    unsigned short* WTR  = (unsigned short*)p; p += 962560;
    unsigned short* WIHT = (unsigned short*)p; p += 524288;   // 2 x 1024x512 bf16
    unsigned short* CLST = (unsigned short*)p; p += 184832;   // 722x512 bf16
    float* P   = p; p += 508896;
    float* XM  = p; p += 508896;
    unsigned short* XP4 = (unsigned short*)p; p += 253952;    // (unused, layout kept)
    unsigned short* FEb = (unsigned short*)p; p += 253952;
    unsigned short* WF  = (unsigned short*)p; p += 262144;
    float* XPT = p; p += 2031616;
    unsigned short* HCb = (unsigned short*)p; p += 253952;
    unsigned short* q = (unsigned short*)p;
    unsigned short* A1  = q; q += (size_t)NC*1087680;
    unsigned short* C1p = q; q += (size_t)NC*274560;
    unsigned short* A2  = q; q += (size_t)NC*549120;
    unsigned short* C2p = q; q += (size_t)NC*143616;
    unsigned short* A3  = q; q += (size_t)NC*215424;
    unsigned short* XP3 = q; q += (size_t)NC*65280;
    unsigned short* A4  = q; q += (size_t)NC*87040;
    (void)XP4;

    unsigned short* w2T  = WTR + 0;
    unsigned short* r1AT = WTR + 36864;
    unsigned short* r1BT = WTR + 110592;
    unsigned short* r1ST = WTR + 258048;
    unsigned short* r2AT = WTR + 266240;
    unsigned short* r2BT = WTR + 487424;
    unsigned short* r2ST = WTR + 819200;
    unsigned short* r3AT = WTR + 843776;
    unsigned short* r3BT = WTR + 1286144;
    unsigned short* r3ST = WTR + 1875968;

    auto cdiv = [](int a, int b){ return (a + b - 1) / b; };

    // ---- ALL weight transforms in one launch ----
    XJobs jobs;
    jobs.s[0] = cbw2;  jobs.d[0] = w2T;
    jobs.s[1] = r1wA;  jobs.d[1] = r1AT;
    jobs.s[2] = r1wB;  jobs.d[2] = r1BT;
    jobs.s[3] = r1s;   jobs.d[3] = r1ST;
    jobs.s[4] = r2wA;  jobs.d[4] = r2AT;
    jobs.s[5] = r2wB;  jobs.d[5] = r2BT;
    jobs.s[6] = r2s;   jobs.d[6] = r2ST;
    jobs.s[7] = r3wA;  jobs.d[7] = r3AT;
    jobs.s[8] = r3wB;  jobs.d[8] = r3BT;
    jobs.s[9] = r3s;   jobs.d[9] = r3ST;
    jobs.s[10] = whh_f; jobs.d[10] = WF;
    jobs.s[11] = whh_b; jobs.d[11] = WF + 262144;
    jobs.s[12] = wih_f; jobs.d[12] = WIHT;
    jobs.s[13] = wih_b; jobs.d[13] = WIHT + 524288;
    jobs.s[14] = clsw;  jobs.d[14] = CLST;
    wtrans_all_kernel<<<dim3(2304, 15), 256, 0, stream>>>(jobs);

    // ---- frontend mask ----
    mask_partial_kernel<<<dim3(63, 32), 256, 0, stream>>>(fW, fB, P);
    mask_finalize_apply<<<63, 256, 0, stream>>>(P, x, XM);

    // ---- zero ONLY the halo cells of the padded staging buffers ----
    HaloPtrs hps;
    hps.b[0] = A1;  hps.b[1] = C1p; hps.b[2] = A2; hps.b[3] = C2p;
    hps.b[4] = A3;  hps.b[5] = XP3; hps.b[6] = A4;
    halo_zero_kernel<<<dim3(35, 7, NC), 256, 0, stream>>>(hps);

    // ---- conv stack, chunked over batch ----
    for (int c0 = 0; c0 < 32; c0 += NC) {
        const float* xmc = XM + (size_t)c0*15903;
        conv1_kernel<<<dim3(63, 1, NC), 256, 0, stream>>>(xmc, cbw1, cbg, cbb, A1);
        conv_lds_kernel<64,8,0,1><<<dim3(4*31, 1, NC), 256, 0, stream>>>(
            A1, w2T, nullptr, nullptr, C1p, 515, 4, 0, 33, 1, 130, 1, 64, r1pg, r1pb);
        conv_lds_kernel<64,8,0,0><<<dim3(31, 2, NC), 256, 0, stream>>>(
            C1p, r1AT, nullptr, nullptr, A2, 130, 1, 0, 33, 1, 130, 1, 128, r1g, r1b);
        conv_lds_kernel<128,8,64,1><<<dim3(31, 2, NC), 256, 0, stream>>>(
            A2, r1BT, C1p, r1ST, C2p, 130, 1, 130, 33, 1, 34, 1, 128, r2pg, r2pb);
        conv_lds_kernel<128,2,0,0><<<dim3(31, 3, NC), 256, 0, stream>>>(
            C2p, r2AT, nullptr, nullptr, A3, 34, 1, 0, 33, 1, 34, 1, 192, r2g, r2b);
        conv_lds_kernel<192,2,128,1><<<dim3(31, 3, NC), 256, 0, stream>>>(
            A3, r2BT, C2p, r2ST, XP3, 34, 1, 34, 34, 1, 10, 1, 192, r3pg, r3pb);
        conv_w8_kernel<192,0,0,0><<<dim3(16, 2, NC), 256, 0, stream>>>(
            XP3, r3AT, nullptr, nullptr, A4, 256, r3g, r3b);
        // r3B + shortcut + bn+lrelu+pool(8->2) -> FEb feats layout directly
        conv_w8_kernel<256,192,1,1><<<dim3(16, 2, NC), 256, 0, stream>>>(
            A4, r3BT, XP3, r3ST, FEb + (size_t)c0*15872, 256, pbg, pbb);
    }

    // LSTM input projections (MFMA) -> xpT [d][t][b][j] fp32
    gemm_mfma_kernel<1><<<dim3(16, 16), 256, 0, stream>>>(FEb, WIHT,          bih_f, bhh_f, XPT,           992, 1024, 512);
    gemm_mfma_kernel<1><<<dim3(16, 16), 256, 0, stream>>>(FEb, WIHT + 524288, bih_b, bhh_b, XPT + 1015808, 992, 1024, 512);

    // fused bidirectional scan (4 blocks: dir x batch-half), hcat bf16
    lstm_scan_mfma<<<4, 1024, 0, stream>>>(XPT, WF, HCb);

    // classifier (MFMA) -> d_out (32,31,722) fp32
    gemm_mfma_kernel<0><<<dim3(16, 12), 256, 0, stream>>>(HCb, CLST, clsb, nullptr, out, 992, 722, 512);
}